// Round 1
// baseline (808.642 us; speedup 1.0000x reference)
//
#include <hip/hip_runtime.h>
#include <math.h>

// VMamba discriminator forward, fp32 throughout.
// B=2, C=256, IMG=128, P=4 -> H=W=32, L=1024, D_INNER=512, N=16, R=16, K=4

// ---------------- generic NT GEMM: C[m,n] = act(sum_k A[m,k]*B[n,k] + bias[n]) (+C) ----
// PATCH=true: A gathered on the fly from x (B,256,128,128) as im2col rows.
template<int ACT, bool PATCH>
__global__ __launch_bounds__(256) void gemm_nt(
    const float* __restrict__ Ag, const float* __restrict__ Bg,
    const float* __restrict__ biasg, float* Cg,
    int M, int N, int Kd, int lda, int ldb, int ldc,
    long sA, long sB, long sBias, long sC, int bmod, int accumulate)
{
  __shared__ __align__(16) float As[64 * 36];
  __shared__ float Bs[32 * 33];
  int z = blockIdx.z;
  int zb = (bmod > 1) ? (z % bmod) : 0;
  const float* A = Ag + (long)z * sA;
  const float* Bm = Bg + (long)zb * sB;
  const float* bias = biasg ? (biasg + (long)zb * sBias) : nullptr;
  float* C = Cg + (long)z * sC;
  int tid = threadIdx.x;
  int n0 = blockIdx.x * 32;
  int m0 = blockIdx.y * 64;
  int tn = tid & 7, tm = tid >> 3;
  float acc[2][4] = {};
  int nk = (Kd + 31) >> 5;
  for (int kt = 0; kt < nk; ++kt) {
    int k0 = kt << 5;
    if (PATCH) {
      #pragma unroll
      for (int i = 0; i < 2; ++i) {
        int idx = i * 256 + tid;
        int pos = idx & 63, kq = idx >> 6;
        int m = m0 + pos;
        int b = m >> 10, l = m & 1023;
        int h = l >> 5, w = l & 31;
        int kg = k0 + kq * 4;
        int ci = kg >> 4, ph = (kg >> 2) & 3;
        const float* src = Ag + ((((long)b * 256 + ci) * 128 + 4 * h + ph) * 128 + 4 * w);
        float4 v = *(const float4*)src;
        *(float4*)&As[pos * 36 + kq * 4] = v;
      }
    } else {
      #pragma unroll
      for (int i = 0; i < 2; ++i) {
        int idx = i * 256 + tid;
        int row = idx >> 3, c4 = idx & 7;
        int m = m0 + row, k = k0 + c4 * 4;
        float4 v = make_float4(0.f, 0.f, 0.f, 0.f);
        if (m < M && k < Kd) v = *(const float4*)(A + (long)m * lda + k);
        *(float4*)&As[row * 36 + c4 * 4] = v;
      }
    }
    {
      int row = tid >> 3, c4 = tid & 7;
      int n = n0 + row, k = k0 + c4 * 4;
      float4 v = make_float4(0.f, 0.f, 0.f, 0.f);
      if (n < N && k < Kd) v = *(const float4*)(Bm + (long)n * ldb + k);
      Bs[row * 33 + c4 * 4 + 0] = v.x;
      Bs[row * 33 + c4 * 4 + 1] = v.y;
      Bs[row * 33 + c4 * 4 + 2] = v.z;
      Bs[row * 33 + c4 * 4 + 3] = v.w;
    }
    __syncthreads();
    #pragma unroll
    for (int kk = 0; kk < 32; ++kk) {
      float a0 = As[(tm * 2 + 0) * 36 + kk];
      float a1 = As[(tm * 2 + 1) * 36 + kk];
      #pragma unroll
      for (int j = 0; j < 4; ++j) {
        float bv = Bs[(tn * 4 + j) * 33 + kk];
        acc[0][j] += a0 * bv;
        acc[1][j] += a1 * bv;
      }
    }
    __syncthreads();
  }
  bool fullN = (n0 + 32 <= N);
  #pragma unroll
  for (int i = 0; i < 2; ++i) {
    int m = m0 + tm * 2 + i;
    if (m >= M) continue;
    float r[4];
    #pragma unroll
    for (int j = 0; j < 4; ++j) {
      int n = n0 + tn * 4 + j;
      float v = acc[i][j];
      if (bias && n < N) v += bias[n];
      if (ACT == 1) v = (v > 20.f) ? v : log1pf(expf(v));  // softplus
      r[j] = v;
    }
    long base = (long)m * ldc + n0 + tn * 4;
    if (fullN) {
      float4 o = make_float4(r[0], r[1], r[2], r[3]);
      if (accumulate) {
        float4 old = *(float4*)(C + base);
        o.x += old.x; o.y += old.y; o.z += old.z; o.w += old.w;
      }
      *(float4*)(C + base) = o;
    } else {
      #pragma unroll
      for (int j = 0; j < 4; ++j) {
        int n = n0 + tn * 4 + j;
        if (n < N) {
          float v = r[j];
          if (accumulate) v += C[(long)m * ldc + n];
          C[(long)m * ldc + n] = v;
        }
      }
    }
  }
}

// ---------------- block reduce helper (256 threads) ----------------
__device__ __forceinline__ float blk_sum(float v, float* sm) {
  #pragma unroll
  for (int o = 32; o > 0; o >>= 1) v += __shfl_down(v, o);
  int wid = threadIdx.x >> 6, lane = threadIdx.x & 63;
  __syncthreads();
  if (lane == 0) sm[wid] = v;
  __syncthreads();
  int nw = blockDim.x >> 6;
  float r = 0.f;
  for (int i = 0; i < nw; ++i) r += sm[i];
  return r;
}

// ---------------- LN over C=256 ----------------
__global__ __launch_bounds__(256) void ln1_kernel(const float* __restrict__ t,
    float* __restrict__ u, const float* __restrict__ g, const float* __restrict__ b) {
  __shared__ float sm[8];
  int m = blockIdx.x, c = threadIdx.x;
  float v = t[(long)m * 256 + c];
  float s = blk_sum(v, sm);
  float s2 = blk_sum(v * v, sm);
  float mu = s * (1.f / 256.f);
  float var = s2 * (1.f / 256.f) - mu * mu;
  float rs = rsqrtf(var + 1e-5f);
  u[(long)m * 256 + c] = (v - mu) * rs * g[c] + b[c];
}

// ---------------- transpose xz[:, :512] -> xc (B,512,32,32) ----------------
__global__ __launch_bounds__(256) void repack_xc(const float* __restrict__ xz, float* __restrict__ xc) {
  __shared__ float tile[32][33];
  int b = blockIdx.z, l0 = blockIdx.x * 32, d0 = blockIdx.y * 32;
  int tid = threadIdx.x;
  int a = tid >> 5, q = tid & 31;
  #pragma unroll
  for (int i = 0; i < 4; ++i) {
    int li = a + i * 8;
    tile[li][q] = xz[((long)(b * 1024 + l0 + li)) * 1024 + d0 + q];
  }
  __syncthreads();
  #pragma unroll
  for (int i = 0; i < 4; ++i) {
    int dj = a + i * 8;
    xc[((long)(b * 512 + d0 + dj)) * 1024 + l0 + q] = tile[q][dj];
  }
}

// ---------------- depthwise 3x3 + bias + silu ----------------
__global__ __launch_bounds__(256) void dwconv_kernel(const float* __restrict__ xc,
    const float* __restrict__ cw, const float* __restrict__ cb, float* __restrict__ out) {
  __shared__ float plane[32][33];
  int d = blockIdx.x, b = blockIdx.y;
  long base = ((long)b * 512 + d) * 1024;
  int tid = threadIdx.x;
  float4 v = *(const float4*)(xc + base + tid * 4);
  int h0 = (tid * 4) >> 5, w0 = (tid * 4) & 31;
  plane[h0][w0 + 0] = v.x; plane[h0][w0 + 1] = v.y;
  plane[h0][w0 + 2] = v.z; plane[h0][w0 + 3] = v.w;
  float w9[9];
  #pragma unroll
  for (int i = 0; i < 9; ++i) w9[i] = cw[d * 9 + i];
  float bias = cb[d];
  __syncthreads();
  float4 o;
  float* op = &o.x;
  #pragma unroll
  for (int j = 0; j < 4; ++j) {
    int p = tid * 4 + j, h = p >> 5, w = p & 31;
    float acc = 0.f;
    #pragma unroll
    for (int dh = -1; dh <= 1; ++dh) {
      int hy = h + dh;
      if (hy < 0 || hy > 31) continue;
      #pragma unroll
      for (int dw = -1; dw <= 1; ++dw) {
        int wx = w + dw;
        if (wx < 0 || wx > 31) continue;
        acc += w9[(dh + 1) * 3 + (dw + 1)] * plane[hy][wx];
      }
    }
    acc += bias;
    op[j] = acc / (1.f + expf(-acc));  // silu
  }
  *(float4*)(out + base + tid * 4) = o;
}

// ---------------- build xsT (B,K,L,512) from xca (B,512,32,32) ----------------
__global__ __launch_bounds__(256) void build_xsT(const float* __restrict__ xca, float* __restrict__ xsT) {
  __shared__ float tile[32][33];
  int h = blockIdx.x;
  int d0 = blockIdx.y * 32;
  int z = blockIdx.z;          // z = b*4 + k
  int b = z >> 2, k = z & 3;
  int tid = threadIdx.x;
  int a = tid >> 5, q = tid & 31;
  #pragma unroll
  for (int i = 0; i < 4; ++i) {
    int di = a + i * 8;
    tile[di][q] = xca[((long)(b * 512 + d0 + di)) * 1024 + h * 32 + q];
  }
  __syncthreads();
  #pragma unroll
  for (int i = 0; i < 4; ++i) {
    int w = a + i * 8;
    int r;
    if (k == 0) r = h * 32 + w;
    else if (k == 1) r = w * 32 + h;
    else if (k == 2) r = 1023 - (h * 32 + w);
    else r = 1023 - (w * 32 + h);
    xsT[((long)z * 1024 + r) * 512 + d0 + q] = tile[q][w];
  }
}

// ---------------- selective scan; ys written in-place over xsT ----------------
__global__ __launch_bounds__(64) void scan_kernel(const float* __restrict__ dts,
    float* xsT_ys, const float* __restrict__ xdbl,
    const float* __restrict__ A_log, const float* __restrict__ Ds) {
  int bid = blockIdx.x;
  int z = bid >> 7;                       // 0..7 (b*4+k)
  int k = z & 3;
  int d = (bid & 127) * 4 + (threadIdx.x >> 4);
  int n = threadIdx.x & 15;
  float a = -expf(A_log[((long)k * 512 + d) * 16 + n]);
  float Dv = Ds[k * 512 + d];
  long rowD = (long)z * 1024 * 512 + d;
  long rowB = (long)z * 1024 * 48;
  float h = 0.f;
  #pragma unroll 2
  for (int l = 0; l < 1024; ++l) {
    float dt = dts[rowD + (long)l * 512];
    float xv = xsT_ys[rowD + (long)l * 512];
    float Bv = xdbl[rowB + l * 48 + 16 + n];
    float Cv = xdbl[rowB + l * 48 + 32 + n];
    float dA = expf(dt * a);
    h = dA * h + (dt * xv) * Bv;
    float p = h * Cv;
    #pragma unroll
    for (int o = 1; o < 16; o <<= 1) p += __shfl_xor(p, o);
    if (n == 0) xsT_ys[rowD + (long)l * 512] = p + Dv * xv;   // ys = scan_y + Ds*xs
  }
}

// ---------------- combine 4 directions ----------------
__global__ __launch_bounds__(256) void combine_kernel(const float* __restrict__ ys, float* __restrict__ yc) {
  int m = blockIdx.x;
  int b = m >> 10, l = m & 1023;
  int h = l >> 5, w = l & 31;
  int lw = w * 32 + h;
  long b4 = (long)b * 4;
  int tid = threadIdx.x;
  #pragma unroll
  for (int i = 0; i < 2; ++i) {
    int d = tid + i * 256;
    float v = ys[((b4 + 0) * 1024 + l) * 512 + d]
            + ys[((b4 + 2) * 1024 + (1023 - l)) * 512 + d]
            + ys[((b4 + 1) * 1024 + lw) * 512 + d]
            + ys[((b4 + 3) * 1024 + (1023 - lw)) * 512 + d];
    yc[(long)m * 512 + d] = v;
  }
}

// ---------------- LN over 512 + silu(z) gate ----------------
__global__ __launch_bounds__(256) void ln2gate_kernel(const float* __restrict__ y,
    const float* __restrict__ xz, float* __restrict__ out,
    const float* __restrict__ g, const float* __restrict__ b) {
  __shared__ float sm[8];
  int m = blockIdx.x, tid = threadIdx.x;
  float v0 = y[(long)m * 512 + tid];
  float v1 = y[(long)m * 512 + tid + 256];
  float s = blk_sum(v0 + v1, sm);
  float s2 = blk_sum(v0 * v0 + v1 * v1, sm);
  float mu = s * (1.f / 512.f);
  float var = s2 * (1.f / 512.f) - mu * mu;
  float rs = rsqrtf(var + 1e-5f);
  #pragma unroll
  for (int i = 0; i < 2; ++i) {
    int c = tid + i * 256;
    float v = i ? v1 : v0;
    float yn = (v - mu) * rs * g[c] + b[c];
    float zz = xz[(long)m * 1024 + 512 + c];
    out[(long)m * 512 + c] = yn * (zz / (1.f + expf(-zz)));
  }
}

// ---------------- pooled head ----------------
__global__ __launch_bounds__(256) void head_partial(const float* __restrict__ t,
    const float* __restrict__ hw, float* __restrict__ part) {
  __shared__ float sm[8];
  int j = blockIdx.x, b = blockIdx.y;
  int c = threadIdx.x;
  float s = 0.f;
  for (int l = j * 64; l < j * 64 + 64; ++l) s += t[((long)b * 1024 + l) * 256 + c];
  s *= hw[c];
  float tot = blk_sum(s, sm);
  if (c == 0) part[b * 16 + j] = tot;
}

__global__ void head_final(const float* __restrict__ part, const float* __restrict__ hb, float* __restrict__ out) {
  int tid = threadIdx.x;
  float v = (tid < 32) ? part[tid] : 0.f;
  #pragma unroll
  for (int o = 1; o < 16; o <<= 1) v += __shfl_xor(v, o);
  if (tid < 32 && (tid & 15) == 0) out[tid >> 4] = v * (1.f / 1024.f) + hb[0];
}

extern "C" void kernel_launch(void* const* d_in, const int* in_sizes, int n_in,
                              void* d_out, int out_size, void* d_ws, size_t ws_size,
                              hipStream_t stream) {
  const float* x       = (const float*)d_in[0];
  const float* patch_w = (const float*)d_in[1];
  const float* patch_b = (const float*)d_in[2];
  const float* ln_g    = (const float*)d_in[3];
  const float* ln_b    = (const float*)d_in[4];
  const float* in_w    = (const float*)d_in[5];
  const float* conv_w  = (const float*)d_in[6];
  const float* conv_b  = (const float*)d_in[7];
  const float* xproj_w = (const float*)d_in[8];
  const float* dt_w    = (const float*)d_in[9];
  const float* dt_b    = (const float*)d_in[10];
  const float* A_log   = (const float*)d_in[11];
  const float* Ds      = (const float*)d_in[12];
  const float* on_g    = (const float*)d_in[13];
  const float* on_b    = (const float*)d_in[14];
  const float* out_w   = (const float*)d_in[15];
  const float* head_w  = (const float*)d_in[16];
  const float* head_b  = (const float*)d_in[17];

  float* ws = (float*)d_ws;
  float* t_buf   = ws;                    // 2048*256
  float* u_buf   = t_buf + 524288;        // 2048*256
  float* xz_buf  = u_buf + 524288;        // 2048*1024
  float* xc_buf  = xz_buf + 2097152;      // 2*512*1024  (xc; later y_comb)
  float* xca_buf = xc_buf + 1048576;      // 2*512*1024  (xca; later y_gated)
  float* xsT_buf = xca_buf + 1048576;     // 8*1024*512  (xs; scan writes ys in-place)
  float* xdbl_buf= xsT_buf + 4194304;     // 8*1024*48
  float* dts_buf = xdbl_buf + 393216;     // 8*1024*512
  float* part_buf= dts_buf + 4194304;     // 32
  // total ~55 MB of d_ws

  // 1. patch embed (im2col fused GEMM): t (2048,256)
  gemm_nt<0, true><<<dim3(8, 32, 1), 256, 0, stream>>>(x, patch_w, patch_b, t_buf,
      2048, 256, 4096, 0, 4096, 256, 0, 0, 0, 0, 1, 0);
  // 2. LN1 -> u
  ln1_kernel<<<2048, 256, 0, stream>>>(t_buf, u_buf, ln_g, ln_b);
  // 3. xz = u @ in_w^T  (2048,1024)
  gemm_nt<0, false><<<dim3(32, 32, 1), 256, 0, stream>>>(u_buf, in_w, nullptr, xz_buf,
      2048, 1024, 256, 256, 256, 1024, 0, 0, 0, 0, 1, 0);
  // 4. repack xc -> (B,512,32,32)
  repack_xc<<<dim3(32, 16, 2), 256, 0, stream>>>(xz_buf, xc_buf);
  // 5. depthwise conv + silu
  dwconv_kernel<<<dim3(512, 2), 256, 0, stream>>>(xc_buf, conv_w, conv_b, xca_buf);
  // 6. build xsT (B,K,L,512)
  build_xsT<<<dim3(32, 16, 8), 256, 0, stream>>>(xca_buf, xsT_buf);
  // 7. x_dbl[z] (1024,48) = xsT[z] @ xproj_w[k]^T
  gemm_nt<0, false><<<dim3(2, 16, 8), 256, 0, stream>>>(xsT_buf, xproj_w, nullptr, xdbl_buf,
      1024, 48, 512, 512, 512, 48, 524288, 24576, 0, 49152, 4, 0);
  // 8. dts[z] (1024,512) = softplus(x_dbl[:, :16] @ dt_w[k]^T + dt_b[k])
  gemm_nt<1, false><<<dim3(16, 16, 8), 256, 0, stream>>>(xdbl_buf, dt_w, dt_b, dts_buf,
      1024, 512, 16, 48, 16, 512, 49152, 8192, 512, 524288, 4, 0);
  // 9. selective scan (ys overwrites xsT in place, + Ds*xs folded in)
  scan_kernel<<<1024, 64, 0, stream>>>(dts_buf, xsT_buf, xdbl_buf, A_log, Ds);
  // 10. combine 4 directions -> y_comb (reuse xc_buf)
  combine_kernel<<<2048, 256, 0, stream>>>(xsT_buf, xc_buf);
  // 11. LN2 * silu(z) -> y_gated (reuse xca_buf)
  ln2gate_kernel<<<2048, 256, 0, stream>>>(xc_buf, xz_buf, xca_buf, on_g, on_b);
  // 12. t += y_gated @ out_w^T
  gemm_nt<0, false><<<dim3(8, 32, 1), 256, 0, stream>>>(xca_buf, out_w, nullptr, t_buf,
      2048, 256, 512, 512, 512, 256, 0, 0, 0, 0, 1, 1);
  // 13. pooled head
  head_partial<<<dim3(16, 2), 256, 0, stream>>>(t_buf, head_w, part_buf);
  head_final<<<1, 64, 0, stream>>>(part_buf, head_b, (float*)d_out);
}

// Round 2
// 456.701 us; speedup vs baseline: 1.7706x; 1.7706x over previous
//
#include <hip/hip_runtime.h>
#include <math.h>

// VMamba discriminator forward, fp32 throughout.
// B=2, C=256, IMG=128, P=4 -> H=W=32, L=1024, D_INNER=512, N=16, R=16, K=4

// ---------------- generic NT GEMM: C[m,n] = act(sum_k A[m,k]*B[n,k] + bias[n]) (+C) ----
// PATCH=true: A gathered on the fly from x (B,256,128,128) as im2col rows.
template<int ACT, bool PATCH>
__global__ __launch_bounds__(256) void gemm_nt(
    const float* __restrict__ Ag, const float* __restrict__ Bg,
    const float* __restrict__ biasg, float* Cg,
    int M, int N, int Kd, int lda, int ldb, int ldc,
    long sA, long sB, long sBias, long sC, int bmod, int accumulate)
{
  __shared__ __align__(16) float As[64 * 36];
  __shared__ float Bs[32 * 33];
  int z = blockIdx.z;
  int zb = (bmod > 1) ? (z % bmod) : 0;
  const float* A = Ag + (long)z * sA;
  const float* Bm = Bg + (long)zb * sB;
  const float* bias = biasg ? (biasg + (long)zb * sBias) : nullptr;
  float* C = Cg + (long)z * sC;
  int tid = threadIdx.x;
  int n0 = blockIdx.x * 32;
  int m0 = blockIdx.y * 64;
  int tn = tid & 7, tm = tid >> 3;
  float acc[2][4] = {};
  int nk = (Kd + 31) >> 5;
  for (int kt = 0; kt < nk; ++kt) {
    int k0 = kt << 5;
    if (PATCH) {
      #pragma unroll
      for (int i = 0; i < 2; ++i) {
        int idx = i * 256 + tid;
        int pos = idx & 63, kq = idx >> 6;
        int m = m0 + pos;
        int b = m >> 10, l = m & 1023;
        int h = l >> 5, w = l & 31;
        int kg = k0 + kq * 4;
        int ci = kg >> 4, ph = (kg >> 2) & 3;
        const float* src = Ag + ((((long)b * 256 + ci) * 128 + 4 * h + ph) * 128 + 4 * w);
        float4 v = *(const float4*)src;
        *(float4*)&As[pos * 36 + kq * 4] = v;
      }
    } else {
      #pragma unroll
      for (int i = 0; i < 2; ++i) {
        int idx = i * 256 + tid;
        int row = idx >> 3, c4 = idx & 7;
        int m = m0 + row, k = k0 + c4 * 4;
        float4 v = make_float4(0.f, 0.f, 0.f, 0.f);
        if (m < M && k < Kd) v = *(const float4*)(A + (long)m * lda + k);
        *(float4*)&As[row * 36 + c4 * 4] = v;
      }
    }
    {
      int row = tid >> 3, c4 = tid & 7;
      int n = n0 + row, k = k0 + c4 * 4;
      float4 v = make_float4(0.f, 0.f, 0.f, 0.f);
      if (n < N && k < Kd) v = *(const float4*)(Bm + (long)n * ldb + k);
      Bs[row * 33 + c4 * 4 + 0] = v.x;
      Bs[row * 33 + c4 * 4 + 1] = v.y;
      Bs[row * 33 + c4 * 4 + 2] = v.z;
      Bs[row * 33 + c4 * 4 + 3] = v.w;
    }
    __syncthreads();
    #pragma unroll
    for (int kk = 0; kk < 32; ++kk) {
      float a0 = As[(tm * 2 + 0) * 36 + kk];
      float a1 = As[(tm * 2 + 1) * 36 + kk];
      #pragma unroll
      for (int j = 0; j < 4; ++j) {
        float bv = Bs[(tn * 4 + j) * 33 + kk];
        acc[0][j] += a0 * bv;
        acc[1][j] += a1 * bv;
      }
    }
    __syncthreads();
  }
  bool fullN = (n0 + 32 <= N);
  #pragma unroll
  for (int i = 0; i < 2; ++i) {
    int m = m0 + tm * 2 + i;
    if (m >= M) continue;
    float r[4];
    #pragma unroll
    for (int j = 0; j < 4; ++j) {
      int n = n0 + tn * 4 + j;
      float v = acc[i][j];
      if (bias && n < N) v += bias[n];
      if (ACT == 1) v = (v > 20.f) ? v : log1pf(expf(v));  // softplus
      r[j] = v;
    }
    long base = (long)m * ldc + n0 + tn * 4;
    if (fullN) {
      float4 o = make_float4(r[0], r[1], r[2], r[3]);
      if (accumulate) {
        float4 old = *(float4*)(C + base);
        o.x += old.x; o.y += old.y; o.z += old.z; o.w += old.w;
      }
      *(float4*)(C + base) = o;
    } else {
      #pragma unroll
      for (int j = 0; j < 4; ++j) {
        int n = n0 + tn * 4 + j;
        if (n < N) {
          float v = r[j];
          if (accumulate) v += C[(long)m * ldc + n];
          C[(long)m * ldc + n] = v;
        }
      }
    }
  }
}

// ---------------- block reduce helper (256 threads) ----------------
__device__ __forceinline__ float blk_sum(float v, float* sm) {
  #pragma unroll
  for (int o = 32; o > 0; o >>= 1) v += __shfl_down(v, o);
  int wid = threadIdx.x >> 6, lane = threadIdx.x & 63;
  __syncthreads();
  if (lane == 0) sm[wid] = v;
  __syncthreads();
  int nw = blockDim.x >> 6;
  float r = 0.f;
  for (int i = 0; i < nw; ++i) r += sm[i];
  return r;
}

// ---------------- LN over C=256 ----------------
__global__ __launch_bounds__(256) void ln1_kernel(const float* __restrict__ t,
    float* __restrict__ u, const float* __restrict__ g, const float* __restrict__ b) {
  __shared__ float sm[8];
  int m = blockIdx.x, c = threadIdx.x;
  float v = t[(long)m * 256 + c];
  float s = blk_sum(v, sm);
  float s2 = blk_sum(v * v, sm);
  float mu = s * (1.f / 256.f);
  float var = s2 * (1.f / 256.f) - mu * mu;
  float rs = rsqrtf(var + 1e-5f);
  u[(long)m * 256 + c] = (v - mu) * rs * g[c] + b[c];
}

// ---------------- transpose xz[:, :512] -> xc (B,512,32,32) ----------------
__global__ __launch_bounds__(256) void repack_xc(const float* __restrict__ xz, float* __restrict__ xc) {
  __shared__ float tile[32][33];
  int b = blockIdx.z, l0 = blockIdx.x * 32, d0 = blockIdx.y * 32;
  int tid = threadIdx.x;
  int a = tid >> 5, q = tid & 31;
  #pragma unroll
  for (int i = 0; i < 4; ++i) {
    int li = a + i * 8;
    tile[li][q] = xz[((long)(b * 1024 + l0 + li)) * 1024 + d0 + q];
  }
  __syncthreads();
  #pragma unroll
  for (int i = 0; i < 4; ++i) {
    int dj = a + i * 8;
    xc[((long)(b * 512 + d0 + dj)) * 1024 + l0 + q] = tile[q][dj];
  }
}

// ---------------- depthwise 3x3 + bias + silu ----------------
__global__ __launch_bounds__(256) void dwconv_kernel(const float* __restrict__ xc,
    const float* __restrict__ cw, const float* __restrict__ cb, float* __restrict__ out) {
  __shared__ float plane[32][33];
  int d = blockIdx.x, b = blockIdx.y;
  long base = ((long)b * 512 + d) * 1024;
  int tid = threadIdx.x;
  float4 v = *(const float4*)(xc + base + tid * 4);
  int h0 = (tid * 4) >> 5, w0 = (tid * 4) & 31;
  plane[h0][w0 + 0] = v.x; plane[h0][w0 + 1] = v.y;
  plane[h0][w0 + 2] = v.z; plane[h0][w0 + 3] = v.w;
  float w9[9];
  #pragma unroll
  for (int i = 0; i < 9; ++i) w9[i] = cw[d * 9 + i];
  float bias = cb[d];
  __syncthreads();
  float4 o;
  float* op = &o.x;
  #pragma unroll
  for (int j = 0; j < 4; ++j) {
    int p = tid * 4 + j, h = p >> 5, w = p & 31;
    float acc = 0.f;
    #pragma unroll
    for (int dh = -1; dh <= 1; ++dh) {
      int hy = h + dh;
      if (hy < 0 || hy > 31) continue;
      #pragma unroll
      for (int dw = -1; dw <= 1; ++dw) {
        int wx = w + dw;
        if (wx < 0 || wx > 31) continue;
        acc += w9[(dh + 1) * 3 + (dw + 1)] * plane[hy][wx];
      }
    }
    acc += bias;
    op[j] = acc / (1.f + expf(-acc));  // silu
  }
  *(float4*)(out + base + tid * 4) = o;
}

// ---------------- build xsT (B,K,L,512) from xca (B,512,32,32) ----------------
__global__ __launch_bounds__(256) void build_xsT(const float* __restrict__ xca, float* __restrict__ xsT) {
  __shared__ float tile[32][33];
  int h = blockIdx.x;
  int d0 = blockIdx.y * 32;
  int z = blockIdx.z;          // z = b*4 + k
  int b = z >> 2, k = z & 3;
  int tid = threadIdx.x;
  int a = tid >> 5, q = tid & 31;
  #pragma unroll
  for (int i = 0; i < 4; ++i) {
    int di = a + i * 8;
    tile[di][q] = xca[((long)(b * 512 + d0 + di)) * 1024 + h * 32 + q];
  }
  __syncthreads();
  #pragma unroll
  for (int i = 0; i < 4; ++i) {
    int w = a + i * 8;
    int r;
    if (k == 0) r = h * 32 + w;
    else if (k == 1) r = w * 32 + h;
    else if (k == 2) r = 1023 - (h * 32 + w);
    else r = 1023 - (w * 32 + h);
    xsT[((long)z * 1024 + r) * 512 + d0 + q] = tile[q][w];
  }
}

// ---------------- chunk-parallel selective scan ----------------
// L=1024 split into NC=8 chunks of 128. Phase 1 (FINAL=false): per-chunk
// running product P = prod(dA) and partial state hp (from h=0). Phase 3
// (FINAL=true): re-run from h_in, write ys in-place over xsT.
// Grid: (32 d-tiles, 8 chunks, 8 z). Block 256 = 16 d x 16 n.
template<bool FINAL>
__global__ __launch_bounds__(256) void scan_chunk(
    const float* __restrict__ dts, float* xsT_ys, const float* __restrict__ xdbl,
    const float* __restrict__ A_log, const float* __restrict__ Ds,
    float* __restrict__ Pb, float* __restrict__ hpb, const float* __restrict__ h_in)
{
  __shared__ float sdt[16][17], sxv[16][17], sB[16][17], sC[16][17], sy[16][17];
  int d0 = blockIdx.x * 16;
  int c  = blockIdx.y;
  int z  = blockIdx.z;
  int k  = z & 3;
  int tid = threadIdx.x;
  int di = tid >> 4, n = tid & 15;
  int d = d0 + di;
  int g = z * 8192 + d * 16 + n;
  float a = -expf(A_log[((long)k * 512 + d) * 16 + n]);
  long baseD = (long)z * 524288;
  long baseB = (long)z * 49152;
  int l0 = c * 128;
  float h = 0.f, P = 1.f, Dv = 0.f;
  if (FINAL) {
    h = h_in[c * 65536 + g];
    Dv = Ds[k * 512 + d];
  }
  for (int lt = 0; lt < 8; ++lt) {
    int lb = l0 + lt * 16;
    {
      int li = tid >> 4, dj = tid & 15;   // cooperative tile load
      long off = baseD + (long)(lb + li) * 512 + d0 + dj;
      sdt[li][dj] = dts[off];
      sxv[li][dj] = xsT_ys[off];
      sB[li][dj]  = xdbl[baseB + (lb + li) * 48 + 16 + dj];
      if (FINAL) sC[li][dj] = xdbl[baseB + (lb + li) * 48 + 32 + dj];
    }
    __syncthreads();
    #pragma unroll
    for (int li = 0; li < 16; ++li) {
      float dt = sdt[li][di];
      float xv = sxv[li][di];
      float dA = expf(dt * a);
      h = dA * h + (dt * xv) * sB[li][n];
      if (!FINAL) {
        P *= dA;
      } else {
        float p = h * sC[li][n];
        p += __shfl_xor(p, 1); p += __shfl_xor(p, 2);
        p += __shfl_xor(p, 4); p += __shfl_xor(p, 8);
        if (n == 0) sy[li][di] = p + Dv * xv;
      }
    }
    __syncthreads();
    if (FINAL) {
      int li = tid >> 4, dj = tid & 15;   // cooperative ys store (in-place)
      xsT_ys[baseD + (long)(lb + li) * 512 + d0 + dj] = sy[li][dj];
    }
  }
  if (!FINAL) {
    Pb[c * 65536 + g]  = P;
    hpb[c * 65536 + g] = h;
  }
}

// prefix across the 8 chunks per (z,d,n)
__global__ __launch_bounds__(256) void scan_prefix(const float* __restrict__ Pb,
    const float* __restrict__ hpb, float* __restrict__ h_in) {
  int g = blockIdx.x * 256 + threadIdx.x;
  float h = 0.f;
  #pragma unroll
  for (int c = 0; c < 8; ++c) {
    h_in[c * 65536 + g] = h;
    h = Pb[c * 65536 + g] * h + hpb[c * 65536 + g];
  }
}

// ---------------- combine 4 directions ----------------
__global__ __launch_bounds__(256) void combine_kernel(const float* __restrict__ ys, float* __restrict__ yc) {
  int m = blockIdx.x;
  int b = m >> 10, l = m & 1023;
  int h = l >> 5, w = l & 31;
  int lw = w * 32 + h;
  long b4 = (long)b * 4;
  int tid = threadIdx.x;
  #pragma unroll
  for (int i = 0; i < 2; ++i) {
    int d = tid + i * 256;
    float v = ys[((b4 + 0) * 1024 + l) * 512 + d]
            + ys[((b4 + 2) * 1024 + (1023 - l)) * 512 + d]
            + ys[((b4 + 1) * 1024 + lw) * 512 + d]
            + ys[((b4 + 3) * 1024 + (1023 - lw)) * 512 + d];
    yc[(long)m * 512 + d] = v;
  }
}

// ---------------- LN over 512 + silu(z) gate ----------------
__global__ __launch_bounds__(256) void ln2gate_kernel(const float* __restrict__ y,
    const float* __restrict__ xz, float* __restrict__ out,
    const float* __restrict__ g, const float* __restrict__ b) {
  __shared__ float sm[8];
  int m = blockIdx.x, tid = threadIdx.x;
  float v0 = y[(long)m * 512 + tid];
  float v1 = y[(long)m * 512 + tid + 256];
  float s = blk_sum(v0 + v1, sm);
  float s2 = blk_sum(v0 * v0 + v1 * v1, sm);
  float mu = s * (1.f / 512.f);
  float var = s2 * (1.f / 512.f) - mu * mu;
  float rs = rsqrtf(var + 1e-5f);
  #pragma unroll
  for (int i = 0; i < 2; ++i) {
    int c = tid + i * 256;
    float v = i ? v1 : v0;
    float yn = (v - mu) * rs * g[c] + b[c];
    float zz = xz[(long)m * 1024 + 512 + c];
    out[(long)m * 512 + c] = yn * (zz / (1.f + expf(-zz)));
  }
}

// ---------------- pooled head ----------------
__global__ __launch_bounds__(256) void head_partial(const float* __restrict__ t,
    const float* __restrict__ hw, float* __restrict__ part) {
  __shared__ float sm[8];
  int j = blockIdx.x, b = blockIdx.y;
  int c = threadIdx.x;
  float s = 0.f;
  for (int l = j * 64; l < j * 64 + 64; ++l) s += t[((long)b * 1024 + l) * 256 + c];
  s *= hw[c];
  float tot = blk_sum(s, sm);
  if (c == 0) part[b * 16 + j] = tot;
}

__global__ void head_final(const float* __restrict__ part, const float* __restrict__ hb, float* __restrict__ out) {
  int tid = threadIdx.x;
  float v = (tid < 32) ? part[tid] : 0.f;
  #pragma unroll
  for (int o = 1; o < 16; o <<= 1) v += __shfl_xor(v, o);
  if (tid < 32 && (tid & 15) == 0) out[tid >> 4] = v * (1.f / 1024.f) + hb[0];
}

extern "C" void kernel_launch(void* const* d_in, const int* in_sizes, int n_in,
                              void* d_out, int out_size, void* d_ws, size_t ws_size,
                              hipStream_t stream) {
  const float* x       = (const float*)d_in[0];
  const float* patch_w = (const float*)d_in[1];
  const float* patch_b = (const float*)d_in[2];
  const float* ln_g    = (const float*)d_in[3];
  const float* ln_b    = (const float*)d_in[4];
  const float* in_w    = (const float*)d_in[5];
  const float* conv_w  = (const float*)d_in[6];
  const float* conv_b  = (const float*)d_in[7];
  const float* xproj_w = (const float*)d_in[8];
  const float* dt_w    = (const float*)d_in[9];
  const float* dt_b    = (const float*)d_in[10];
  const float* A_log   = (const float*)d_in[11];
  const float* Ds      = (const float*)d_in[12];
  const float* on_g    = (const float*)d_in[13];
  const float* on_b    = (const float*)d_in[14];
  const float* out_w   = (const float*)d_in[15];
  const float* head_w  = (const float*)d_in[16];
  const float* head_b  = (const float*)d_in[17];

  float* ws = (float*)d_ws;
  float* t_buf   = ws;                    // 2048*256
  float* u_buf   = t_buf + 524288;        // 2048*256  (u; later h_in)
  float* xz_buf  = u_buf + 524288;        // 2048*1024
  float* xc_buf  = xz_buf + 2097152;      // 2*512*1024  (xc; later P; later y_comb)
  float* xca_buf = xc_buf + 1048576;      // 2*512*1024  (xca; later hp; later y_gated)
  float* xsT_buf = xca_buf + 1048576;     // 8*1024*512  (xs; scan writes ys in-place)
  float* xdbl_buf= xsT_buf + 4194304;     // 8*1024*48
  float* dts_buf = xdbl_buf + 393216;     // 8*1024*512
  float* part_buf= dts_buf + 4194304;     // 32
  // scan scratch (reusing dead regions):
  float* P_buf   = xc_buf;                // 8*65536 = 524288  (xc dead after dwconv)
  float* hp_buf  = xca_buf;               // 8*65536           (xca dead after build_xsT)
  float* hin_buf = u_buf;                 // 8*65536           (u dead after in-proj GEMM)

  // 1. patch embed (im2col fused GEMM): t (2048,256)
  gemm_nt<0, true><<<dim3(8, 32, 1), 256, 0, stream>>>(x, patch_w, patch_b, t_buf,
      2048, 256, 4096, 0, 4096, 256, 0, 0, 0, 0, 1, 0);
  // 2. LN1 -> u
  ln1_kernel<<<2048, 256, 0, stream>>>(t_buf, u_buf, ln_g, ln_b);
  // 3. xz = u @ in_w^T  (2048,1024)
  gemm_nt<0, false><<<dim3(32, 32, 1), 256, 0, stream>>>(u_buf, in_w, nullptr, xz_buf,
      2048, 1024, 256, 256, 256, 1024, 0, 0, 0, 0, 1, 0);
  // 4. repack xc -> (B,512,32,32)
  repack_xc<<<dim3(32, 16, 2), 256, 0, stream>>>(xz_buf, xc_buf);
  // 5. depthwise conv + silu
  dwconv_kernel<<<dim3(512, 2), 256, 0, stream>>>(xc_buf, conv_w, conv_b, xca_buf);
  // 6. build xsT (B,K,L,512)
  build_xsT<<<dim3(32, 16, 8), 256, 0, stream>>>(xca_buf, xsT_buf);
  // 7. x_dbl[z] (1024,48) = xsT[z] @ xproj_w[k]^T
  gemm_nt<0, false><<<dim3(2, 16, 8), 256, 0, stream>>>(xsT_buf, xproj_w, nullptr, xdbl_buf,
      1024, 48, 512, 512, 512, 48, 524288, 24576, 0, 49152, 4, 0);
  // 8. dts[z] (1024,512) = softplus(x_dbl[:, :16] @ dt_w[k]^T + dt_b[k])
  gemm_nt<1, false><<<dim3(16, 16, 8), 256, 0, stream>>>(xdbl_buf, dt_w, dt_b, dts_buf,
      1024, 512, 16, 48, 16, 512, 49152, 8192, 512, 524288, 4, 0);
  // 9. chunk-parallel selective scan (ys overwrites xsT in place, + Ds*xs folded in)
  scan_chunk<false><<<dim3(32, 8, 8), 256, 0, stream>>>(dts_buf, xsT_buf, xdbl_buf,
      A_log, Ds, P_buf, hp_buf, nullptr);
  scan_prefix<<<256, 256, 0, stream>>>(P_buf, hp_buf, hin_buf);
  scan_chunk<true><<<dim3(32, 8, 8), 256, 0, stream>>>(dts_buf, xsT_buf, xdbl_buf,
      A_log, Ds, nullptr, nullptr, hin_buf);
  // 10. combine 4 directions -> y_comb (reuse xc_buf)
  combine_kernel<<<2048, 256, 0, stream>>>(xsT_buf, xc_buf);
  // 11. LN2 * silu(z) -> y_gated (reuse xca_buf)
  ln2gate_kernel<<<2048, 256, 0, stream>>>(xc_buf, xz_buf, xca_buf, on_g, on_b);
  // 12. t += y_gated @ out_w^T
  gemm_nt<0, false><<<dim3(8, 32, 1), 256, 0, stream>>>(xca_buf, out_w, nullptr, t_buf,
      2048, 256, 512, 512, 512, 256, 0, 0, 0, 0, 1, 1);
  // 13. pooled head
  head_partial<<<dim3(16, 2), 256, 0, stream>>>(t_buf, head_w, part_buf);
  head_final<<<1, 64, 0, stream>>>(part_buf, head_b, (float*)d_out);
}

// Round 3
// 278.750 us; speedup vs baseline: 2.9010x; 1.6384x over previous
//
#include <hip/hip_runtime.h>
#include <math.h>

// VMamba discriminator forward. GEMMs: bf16 MFMA with weight hi/lo split
// (systematic weight-rounding error -> 2^-18); activations bf16-hi, fp32 accum.
// B=2, C=256, IMG=128, P=4 -> H=W=32, L=1024, D_INNER=512, N=16, R=16, K=4

typedef __attribute__((ext_vector_type(4))) float f32x4;
typedef __attribute__((ext_vector_type(8))) short bf16x8;

__device__ __forceinline__ ushort bf16_rn(float f) {
  uint u = __float_as_uint(f);
  return (ushort)((u + 0x7fffu + ((u >> 16) & 1u)) >> 16);
}

// ---------------- split f32 -> bf16 hi + lo ----------------
__global__ __launch_bounds__(256) void split_bf16(const float* __restrict__ src,
    ushort* __restrict__ hi, ushort* __restrict__ lo, int n) {
  int i = blockIdx.x * 256 + threadIdx.x;
  if (i >= n) return;
  float f = src[i];
  ushort h = bf16_rn(f);
  hi[i] = h;
  float fh = __uint_as_float(((uint)h) << 16);
  lo[i] = bf16_rn(f - fh);
}

// ---------------- MFMA NT GEMM: C[m,n] = sum_k A[m,k]*(Bhi+Blo)[n,k] ---------
// A: f32, converted to bf16-hi during LDS staging (PATCH: im2col gather from x).
// Block 64x64, BK=32, 4 waves (2m x 2n), each wave 32x32 via 2x2 16x16x32 MFMA.
// direct=1: store C directly (split must be 1). else store partials P[z][M][N].
template<bool PATCH>
__global__ __launch_bounds__(256) void mfma_nt(
    const float* __restrict__ Af, const ushort* __restrict__ Bhi,
    const ushort* __restrict__ Blo, float* __restrict__ Cout,
    int M, int N, int K, int lda, int kchunk, int direct)
{
  __shared__ ushort Ah[64 * 40];
  __shared__ ushort Bh[64 * 40];
  __shared__ ushort Bl[64 * 40];
  int tid = threadIdx.x;
  int n0 = blockIdx.x * 64;
  int m0 = blockIdx.y * 64;
  int k0 = blockIdx.z * kchunk;
  int wid = tid >> 6, lane = tid & 63;
  int wm = wid >> 1, wn = wid & 1;
  int lrow = lane & 15, lk = (lane >> 4) * 8;
  f32x4 acc[2][2] = {};
  int nkt = kchunk >> 5;
  for (int kt = 0; kt < nkt; ++kt) {
    int kb = k0 + (kt << 5);
    // --- stage A (f32 -> bf16 hi) ---
    #pragma unroll
    for (int i = 0; i < 2; ++i) {
      int idx = i * 256 + tid;
      int row = idx >> 3, kc = idx & 7;
      float4 v;
      if (PATCH) {
        int m = m0 + row;
        int b = m >> 10, l = m & 1023;
        int h = l >> 5, w = l & 31;
        int kg = kb + kc * 4;
        int ci = kg >> 4, ph = (kg >> 2) & 3;
        v = *(const float4*)(Af + ((((long)b * 256 + ci) * 128 + 4 * h + ph) * 128 + 4 * w));
      } else {
        v = *(const float4*)(Af + (long)(m0 + row) * lda + kb + kc * 4);
      }
      uint2 pk;
      pk.x = (uint)bf16_rn(v.x) | ((uint)bf16_rn(v.y) << 16);
      pk.y = (uint)bf16_rn(v.z) | ((uint)bf16_rn(v.w) << 16);
      *(uint2*)&Ah[row * 40 + kc * 4] = pk;
    }
    // --- stage B hi/lo (bf16 direct copy) ---
    {
      int row = tid >> 2, kc8 = (tid & 3) * 8;
      long goff = (long)(n0 + row) * K + kb + kc8;
      *(uint4*)&Bh[row * 40 + kc8] = *(const uint4*)&Bhi[goff];
      *(uint4*)&Bl[row * 40 + kc8] = *(const uint4*)&Blo[goff];
    }
    __syncthreads();
    // --- fragments + MFMA ---
    bf16x8 af[2], bhf[2], blf[2];
    #pragma unroll
    for (int mi = 0; mi < 2; ++mi)
      af[mi] = *(const bf16x8*)&Ah[(wm * 32 + mi * 16 + lrow) * 40 + lk];
    #pragma unroll
    for (int ni = 0; ni < 2; ++ni) {
      bhf[ni] = *(const bf16x8*)&Bh[(wn * 32 + ni * 16 + lrow) * 40 + lk];
      blf[ni] = *(const bf16x8*)&Bl[(wn * 32 + ni * 16 + lrow) * 40 + lk];
    }
    #pragma unroll
    for (int mi = 0; mi < 2; ++mi)
      #pragma unroll
      for (int ni = 0; ni < 2; ++ni) {
        acc[mi][ni] = __builtin_amdgcn_mfma_f32_16x16x32_bf16(af[mi], bhf[ni], acc[mi][ni], 0, 0, 0);
        acc[mi][ni] = __builtin_amdgcn_mfma_f32_16x16x32_bf16(af[mi], blf[ni], acc[mi][ni], 0, 0, 0);
      }
    __syncthreads();
  }
  // --- epilogue: C/D layout col=lane&15, row=(lane>>4)*4+r ---
  long zoff = direct ? 0 : (long)blockIdx.z * M * N;
  int r4 = lane >> 4;
  #pragma unroll
  for (int mi = 0; mi < 2; ++mi)
    #pragma unroll
    for (int ni = 0; ni < 2; ++ni) {
      int n = n0 + wn * 32 + ni * 16 + lrow;
      int mb = m0 + wm * 32 + mi * 16 + r4 * 4;
      #pragma unroll
      for (int r = 0; r < 4; ++r)
        Cout[zoff + (long)(mb + r) * N + n] = acc[mi][ni][r];
    }
}

// ---------------- reduce split-K partials: C (=/+=) sum_s P + bias ----------
__global__ __launch_bounds__(256) void reduce_split(const float* __restrict__ P,
    float* __restrict__ C, const float* __restrict__ bias,
    int MN, int N, int S, int accumulate) {
  int i = blockIdx.x * 256 + threadIdx.x;   // float4 index
  if (i * 4 >= MN) return;
  float4 v = make_float4(0.f, 0.f, 0.f, 0.f);
  for (int s = 0; s < S; ++s) {
    float4 p = *(const float4*)(P + (long)s * MN + i * 4);
    v.x += p.x; v.y += p.y; v.z += p.z; v.w += p.w;
  }
  if (bias) {
    float4 bv = *(const float4*)(bias + ((i * 4) & (N - 1)));
    v.x += bv.x; v.y += bv.y; v.z += bv.z; v.w += bv.w;
  }
  if (accumulate) {
    float4 o = *(const float4*)(C + (long)i * 4);
    v.x += o.x; v.y += o.y; v.z += o.z; v.w += o.w;
  }
  *(float4*)(C + (long)i * 4) = v;
}

// ---------------- generic NT GEMM (fp32 VALU) for small GEMMs ----------------
template<int ACT>
__global__ __launch_bounds__(256) void gemm_nt(
    const float* __restrict__ Ag, const float* __restrict__ Bg,
    const float* __restrict__ biasg, float* Cg,
    int M, int N, int Kd, int lda, int ldb, int ldc,
    long sA, long sB, long sBias, long sC, int bmod, int accumulate)
{
  __shared__ __align__(16) float As[64 * 36];
  __shared__ float Bs[32 * 33];
  int z = blockIdx.z;
  int zb = (bmod > 1) ? (z % bmod) : 0;
  const float* A = Ag + (long)z * sA;
  const float* Bm = Bg + (long)zb * sB;
  const float* bias = biasg ? (biasg + (long)zb * sBias) : nullptr;
  float* C = Cg + (long)z * sC;
  int tid = threadIdx.x;
  int n0 = blockIdx.x * 32;
  int m0 = blockIdx.y * 64;
  int tn = tid & 7, tm = tid >> 3;
  float acc[2][4] = {};
  int nk = (Kd + 31) >> 5;
  for (int kt = 0; kt < nk; ++kt) {
    int k0 = kt << 5;
    #pragma unroll
    for (int i = 0; i < 2; ++i) {
      int idx = i * 256 + tid;
      int row = idx >> 3, c4 = idx & 7;
      int m = m0 + row, k = k0 + c4 * 4;
      float4 v = make_float4(0.f, 0.f, 0.f, 0.f);
      if (m < M && k < Kd) v = *(const float4*)(A + (long)m * lda + k);
      *(float4*)&As[row * 36 + c4 * 4] = v;
    }
    {
      int row = tid >> 3, c4 = tid & 7;
      int n = n0 + row, k = k0 + c4 * 4;
      float4 v = make_float4(0.f, 0.f, 0.f, 0.f);
      if (n < N && k < Kd) v = *(const float4*)(Bm + (long)n * ldb + k);
      Bs[row * 33 + c4 * 4 + 0] = v.x;
      Bs[row * 33 + c4 * 4 + 1] = v.y;
      Bs[row * 33 + c4 * 4 + 2] = v.z;
      Bs[row * 33 + c4 * 4 + 3] = v.w;
    }
    __syncthreads();
    #pragma unroll
    for (int kk = 0; kk < 32; ++kk) {
      float a0 = As[(tm * 2 + 0) * 36 + kk];
      float a1 = As[(tm * 2 + 1) * 36 + kk];
      #pragma unroll
      for (int j = 0; j < 4; ++j) {
        float bv = Bs[(tn * 4 + j) * 33 + kk];
        acc[0][j] += a0 * bv;
        acc[1][j] += a1 * bv;
      }
    }
    __syncthreads();
  }
  bool fullN = (n0 + 32 <= N);
  #pragma unroll
  for (int i = 0; i < 2; ++i) {
    int m = m0 + tm * 2 + i;
    if (m >= M) continue;
    float r[4];
    #pragma unroll
    for (int j = 0; j < 4; ++j) {
      int n = n0 + tn * 4 + j;
      float v = acc[i][j];
      if (bias && n < N) v += bias[n];
      if (ACT == 1) v = (v > 20.f) ? v : log1pf(expf(v));  // softplus
      r[j] = v;
    }
    long base = (long)m * ldc + n0 + tn * 4;
    if (fullN) {
      float4 o = make_float4(r[0], r[1], r[2], r[3]);
      if (accumulate) {
        float4 old = *(float4*)(C + base);
        o.x += old.x; o.y += old.y; o.z += old.z; o.w += old.w;
      }
      *(float4*)(C + base) = o;
    } else {
      #pragma unroll
      for (int j = 0; j < 4; ++j) {
        int n = n0 + tn * 4 + j;
        if (n < N) {
          float v = r[j];
          if (accumulate) v += C[(long)m * ldc + n];
          C[(long)m * ldc + n] = v;
        }
      }
    }
  }
}

// ---------------- block reduce helper (256 threads) ----------------
__device__ __forceinline__ float blk_sum(float v, float* sm) {
  #pragma unroll
  for (int o = 32; o > 0; o >>= 1) v += __shfl_down(v, o);
  int wid = threadIdx.x >> 6, lane = threadIdx.x & 63;
  __syncthreads();
  if (lane == 0) sm[wid] = v;
  __syncthreads();
  int nw = blockDim.x >> 6;
  float r = 0.f;
  for (int i = 0; i < nw; ++i) r += sm[i];
  return r;
}

// ---------------- LN over C=256 ----------------
__global__ __launch_bounds__(256) void ln1_kernel(const float* __restrict__ t,
    float* __restrict__ u, const float* __restrict__ g, const float* __restrict__ b) {
  __shared__ float sm[8];
  int m = blockIdx.x, c = threadIdx.x;
  float v = t[(long)m * 256 + c];
  float s = blk_sum(v, sm);
  float s2 = blk_sum(v * v, sm);
  float mu = s * (1.f / 256.f);
  float var = s2 * (1.f / 256.f) - mu * mu;
  float rs = rsqrtf(var + 1e-5f);
  u[(long)m * 256 + c] = (v - mu) * rs * g[c] + b[c];
}

// ---------------- transpose xz[:, :512] -> xc (B,512,32,32) ----------------
__global__ __launch_bounds__(256) void repack_xc(const float* __restrict__ xz, float* __restrict__ xc) {
  __shared__ float tile[32][33];
  int b = blockIdx.z, l0 = blockIdx.x * 32, d0 = blockIdx.y * 32;
  int tid = threadIdx.x;
  int a = tid >> 5, q = tid & 31;
  #pragma unroll
  for (int i = 0; i < 4; ++i) {
    int li = a + i * 8;
    tile[li][q] = xz[((long)(b * 1024 + l0 + li)) * 1024 + d0 + q];
  }
  __syncthreads();
  #pragma unroll
  for (int i = 0; i < 4; ++i) {
    int dj = a + i * 8;
    xc[((long)(b * 512 + d0 + dj)) * 1024 + l0 + q] = tile[q][dj];
  }
}

// ---------------- depthwise 3x3 + bias + silu ----------------
__global__ __launch_bounds__(256) void dwconv_kernel(const float* __restrict__ xc,
    const float* __restrict__ cw, const float* __restrict__ cb, float* __restrict__ out) {
  __shared__ float plane[32][33];
  int d = blockIdx.x, b = blockIdx.y;
  long base = ((long)b * 512 + d) * 1024;
  int tid = threadIdx.x;
  float4 v = *(const float4*)(xc + base + tid * 4);
  int h0 = (tid * 4) >> 5, w0 = (tid * 4) & 31;
  plane[h0][w0 + 0] = v.x; plane[h0][w0 + 1] = v.y;
  plane[h0][w0 + 2] = v.z; plane[h0][w0 + 3] = v.w;
  float w9[9];
  #pragma unroll
  for (int i = 0; i < 9; ++i) w9[i] = cw[d * 9 + i];
  float bias = cb[d];
  __syncthreads();
  float4 o;
  float* op = &o.x;
  #pragma unroll
  for (int j = 0; j < 4; ++j) {
    int p = tid * 4 + j, h = p >> 5, w = p & 31;
    float acc = 0.f;
    #pragma unroll
    for (int dh = -1; dh <= 1; ++dh) {
      int hy = h + dh;
      if (hy < 0 || hy > 31) continue;
      #pragma unroll
      for (int dw = -1; dw <= 1; ++dw) {
        int wx = w + dw;
        if (wx < 0 || wx > 31) continue;
        acc += w9[(dh + 1) * 3 + (dw + 1)] * plane[hy][wx];
      }
    }
    acc += bias;
    op[j] = acc / (1.f + expf(-acc));  // silu
  }
  *(float4*)(out + base + tid * 4) = o;
}

// ---------------- build xsT (B,K,L,512) from xca (B,512,32,32) ----------------
__global__ __launch_bounds__(256) void build_xsT(const float* __restrict__ xca, float* __restrict__ xsT) {
  __shared__ float tile[32][33];
  int h = blockIdx.x;
  int d0 = blockIdx.y * 32;
  int z = blockIdx.z;          // z = b*4 + k
  int b = z >> 2, k = z & 3;
  int tid = threadIdx.x;
  int a = tid >> 5, q = tid & 31;
  #pragma unroll
  for (int i = 0; i < 4; ++i) {
    int di = a + i * 8;
    tile[di][q] = xca[((long)(b * 512 + d0 + di)) * 1024 + h * 32 + q];
  }
  __syncthreads();
  #pragma unroll
  for (int i = 0; i < 4; ++i) {
    int w = a + i * 8;
    int r;
    if (k == 0) r = h * 32 + w;
    else if (k == 1) r = w * 32 + h;
    else if (k == 2) r = 1023 - (h * 32 + w);
    else r = 1023 - (w * 32 + h);
    xsT[((long)z * 1024 + r) * 512 + d0 + q] = tile[q][w];
  }
}

// ---------------- chunk-parallel selective scan ----------------
template<bool FINAL>
__global__ __launch_bounds__(256) void scan_chunk(
    const float* __restrict__ dts, float* xsT_ys, const float* __restrict__ xdbl,
    const float* __restrict__ A_log, const float* __restrict__ Ds,
    float* __restrict__ Pb, float* __restrict__ hpb, const float* __restrict__ h_in)
{
  __shared__ float sdt[16][17], sxv[16][17], sB[16][17], sC[16][17], sy[16][17];
  int d0 = blockIdx.x * 16;
  int c  = blockIdx.y;
  int z  = blockIdx.z;
  int k  = z & 3;
  int tid = threadIdx.x;
  int di = tid >> 4, n = tid & 15;
  int d = d0 + di;
  int g = z * 8192 + d * 16 + n;
  float a = -expf(A_log[((long)k * 512 + d) * 16 + n]);
  long baseD = (long)z * 524288;
  long baseB = (long)z * 49152;
  int l0 = c * 128;
  float h = 0.f, P = 1.f, Dv = 0.f;
  if (FINAL) {
    h = h_in[c * 65536 + g];
    Dv = Ds[k * 512 + d];
  }
  for (int lt = 0; lt < 8; ++lt) {
    int lb = l0 + lt * 16;
    {
      int li = tid >> 4, dj = tid & 15;
      long off = baseD + (long)(lb + li) * 512 + d0 + dj;
      sdt[li][dj] = dts[off];
      sxv[li][dj] = xsT_ys[off];
      sB[li][dj]  = xdbl[baseB + (lb + li) * 48 + 16 + dj];
      if (FINAL) sC[li][dj] = xdbl[baseB + (lb + li) * 48 + 32 + dj];
    }
    __syncthreads();
    #pragma unroll
    for (int li = 0; li < 16; ++li) {
      float dt = sdt[li][di];
      float xv = sxv[li][di];
      float dA = expf(dt * a);
      h = dA * h + (dt * xv) * sB[li][n];
      if (!FINAL) {
        P *= dA;
      } else {
        float p = h * sC[li][n];
        p += __shfl_xor(p, 1); p += __shfl_xor(p, 2);
        p += __shfl_xor(p, 4); p += __shfl_xor(p, 8);
        if (n == 0) sy[li][di] = p + Dv * xv;
      }
    }
    __syncthreads();
    if (FINAL) {
      int li = tid >> 4, dj = tid & 15;
      xsT_ys[baseD + (long)(lb + li) * 512 + d0 + dj] = sy[li][dj];
    }
  }
  if (!FINAL) {
    Pb[c * 65536 + g]  = P;
    hpb[c * 65536 + g] = h;
  }
}

// prefix across the 8 chunks per (z,d,n)
__global__ __launch_bounds__(256) void scan_prefix(const float* __restrict__ Pb,
    const float* __restrict__ hpb, float* __restrict__ h_in) {
  int g = blockIdx.x * 256 + threadIdx.x;
  float h = 0.f;
  #pragma unroll
  for (int c = 0; c < 8; ++c) {
    h_in[c * 65536 + g] = h;
    h = Pb[c * 65536 + g] * h + hpb[c * 65536 + g];
  }
}

// ---------------- combine 4 directions ----------------
__global__ __launch_bounds__(256) void combine_kernel(const float* __restrict__ ys, float* __restrict__ yc) {
  int m = blockIdx.x;
  int b = m >> 10, l = m & 1023;
  int h = l >> 5, w = l & 31;
  int lw = w * 32 + h;
  long b4 = (long)b * 4;
  int tid = threadIdx.x;
  #pragma unroll
  for (int i = 0; i < 2; ++i) {
    int d = tid + i * 256;
    float v = ys[((b4 + 0) * 1024 + l) * 512 + d]
            + ys[((b4 + 2) * 1024 + (1023 - l)) * 512 + d]
            + ys[((b4 + 1) * 1024 + lw) * 512 + d]
            + ys[((b4 + 3) * 1024 + (1023 - lw)) * 512 + d];
    yc[(long)m * 512 + d] = v;
  }
}

// ---------------- LN over 512 + silu(z) gate ----------------
__global__ __launch_bounds__(256) void ln2gate_kernel(const float* __restrict__ y,
    const float* __restrict__ xz, float* __restrict__ out,
    const float* __restrict__ g, const float* __restrict__ b) {
  __shared__ float sm[8];
  int m = blockIdx.x, tid = threadIdx.x;
  float v0 = y[(long)m * 512 + tid];
  float v1 = y[(long)m * 512 + tid + 256];
  float s = blk_sum(v0 + v1, sm);
  float s2 = blk_sum(v0 * v0 + v1 * v1, sm);
  float mu = s * (1.f / 512.f);
  float var = s2 * (1.f / 512.f) - mu * mu;
  float rs = rsqrtf(var + 1e-5f);
  #pragma unroll
  for (int i = 0; i < 2; ++i) {
    int c = tid + i * 256;
    float v = i ? v1 : v0;
    float yn = (v - mu) * rs * g[c] + b[c];
    float zz = xz[(long)m * 1024 + 512 + c];
    out[(long)m * 512 + c] = yn * (zz / (1.f + expf(-zz)));
  }
}

// ---------------- pooled head ----------------
__global__ __launch_bounds__(256) void head_partial(const float* __restrict__ t,
    const float* __restrict__ hw, float* __restrict__ part) {
  __shared__ float sm[8];
  int j = blockIdx.x, b = blockIdx.y;
  int c = threadIdx.x;
  float s = 0.f;
  for (int l = j * 64; l < j * 64 + 64; ++l) s += t[((long)b * 1024 + l) * 256 + c];
  s *= hw[c];
  float tot = blk_sum(s, sm);
  if (c == 0) part[b * 16 + j] = tot;
}

__global__ void head_final(const float* __restrict__ part, const float* __restrict__ hb, float* __restrict__ out) {
  int tid = threadIdx.x;
  float v = (tid < 32) ? part[tid] : 0.f;
  #pragma unroll
  for (int o = 1; o < 16; o <<= 1) v += __shfl_xor(v, o);
  if (tid < 32 && (tid & 15) == 0) out[tid >> 4] = v * (1.f / 1024.f) + hb[0];
}

extern "C" void kernel_launch(void* const* d_in, const int* in_sizes, int n_in,
                              void* d_out, int out_size, void* d_ws, size_t ws_size,
                              hipStream_t stream) {
  const float* x       = (const float*)d_in[0];
  const float* patch_w = (const float*)d_in[1];
  const float* patch_b = (const float*)d_in[2];
  const float* ln_g    = (const float*)d_in[3];
  const float* ln_b    = (const float*)d_in[4];
  const float* in_w    = (const float*)d_in[5];
  const float* conv_w  = (const float*)d_in[6];
  const float* conv_b  = (const float*)d_in[7];
  const float* xproj_w = (const float*)d_in[8];
  const float* dt_w    = (const float*)d_in[9];
  const float* dt_b    = (const float*)d_in[10];
  const float* A_log   = (const float*)d_in[11];
  const float* Ds      = (const float*)d_in[12];
  const float* on_g    = (const float*)d_in[13];
  const float* on_b    = (const float*)d_in[14];
  const float* out_w   = (const float*)d_in[15];
  const float* head_w  = (const float*)d_in[16];
  const float* head_b  = (const float*)d_in[17];

  float* ws = (float*)d_ws;
  float* t_buf   = ws;                    // 2048*256
  float* u_buf   = t_buf + 524288;        // 2048*256  (u; later h_in)
  float* xz_buf  = u_buf + 524288;        // 2048*1024
  float* xc_buf  = xz_buf + 2097152;      // 2*512*1024  (xc; P_scan; y_comb)
  float* xca_buf = xc_buf + 1048576;      // 2*512*1024  (xca; hp; y_gated)
  float* xsT_buf = xca_buf + 1048576;     // 8*1024*512  (P_patch+patchW splits; xs/ys)
  float* xdbl_buf= xsT_buf + 4194304;     // 8*1024*48
  float* dts_buf = xdbl_buf + 393216;     // 8*1024*512  (dts; later P_out)
  float* part_buf= dts_buf + 4194304;     // 32
  float* tail    = part_buf + 32;
  // scan scratch (dead-region reuse):
  float* P_buf   = xc_buf;
  float* hp_buf  = xca_buf;
  float* hin_buf = u_buf;
  // MFMA weight splits + split-K partials:
  float* P_patch = xsT_buf;                         // 4*2048*256 = 2097152 f
  ushort* pw_hi  = (ushort*)(xsT_buf + 2097152);    // 1048576 us (512K f)
  ushort* pw_lo  = (ushort*)(xsT_buf + 2621440);    // 1048576 us
  float* P_out   = dts_buf;                         // 4*2048*256
  ushort* iw_hi  = (ushort*)tail;                   // 262144 us (128K f)
  ushort* iw_lo  = (ushort*)(tail + 131072);
  ushort* ow_hi  = (ushort*)(tail + 262144);        // 131072 us
  ushort* ow_lo  = (ushort*)(tail + 327680);
  // high-water ~ tail + 393216 floats ~ 57.7 MB

  // 0. weight hi/lo splits
  split_bf16<<<4096, 256, 0, stream>>>(patch_w, pw_hi, pw_lo, 1048576);
  split_bf16<<<1024, 256, 0, stream>>>(in_w, iw_hi, iw_lo, 262144);
  split_bf16<<<512, 256, 0, stream>>>(out_w, ow_hi, ow_lo, 131072);
  // 1. patch embed (im2col MFMA, split-K=4): t (2048,256)
  mfma_nt<true><<<dim3(4, 32, 4), 256, 0, stream>>>(x, pw_hi, pw_lo, P_patch,
      2048, 256, 4096, 0, 1024, 0);
  reduce_split<<<512, 256, 0, stream>>>(P_patch, t_buf, patch_b, 524288, 256, 4, 0);
  // 2. LN1 -> u
  ln1_kernel<<<2048, 256, 0, stream>>>(t_buf, u_buf, ln_g, ln_b);
  // 3. xz = u @ in_w^T  (2048,1024), direct
  mfma_nt<false><<<dim3(16, 32, 1), 256, 0, stream>>>(u_buf, iw_hi, iw_lo, xz_buf,
      2048, 1024, 256, 256, 256, 1);
  // 4. repack xc -> (B,512,32,32)
  repack_xc<<<dim3(32, 16, 2), 256, 0, stream>>>(xz_buf, xc_buf);
  // 5. depthwise conv + silu
  dwconv_kernel<<<dim3(512, 2), 256, 0, stream>>>(xc_buf, conv_w, conv_b, xca_buf);
  // 6. build xsT (B,K,L,512)
  build_xsT<<<dim3(32, 16, 8), 256, 0, stream>>>(xca_buf, xsT_buf);
  // 7. x_dbl[z] (1024,48) = xsT[z] @ xproj_w[k]^T
  gemm_nt<0><<<dim3(2, 16, 8), 256, 0, stream>>>(xsT_buf, xproj_w, nullptr, xdbl_buf,
      1024, 48, 512, 512, 512, 48, 524288, 24576, 0, 49152, 4, 0);
  // 8. dts[z] (1024,512) = softplus(x_dbl[:, :16] @ dt_w[k]^T + dt_b[k])
  gemm_nt<1><<<dim3(16, 16, 8), 256, 0, stream>>>(xdbl_buf, dt_w, dt_b, dts_buf,
      1024, 512, 16, 48, 16, 512, 49152, 8192, 512, 524288, 4, 0);
  // 9. chunk-parallel selective scan (ys overwrites xsT in place)
  scan_chunk<false><<<dim3(32, 8, 8), 256, 0, stream>>>(dts_buf, xsT_buf, xdbl_buf,
      A_log, Ds, P_buf, hp_buf, nullptr);
  scan_prefix<<<256, 256, 0, stream>>>(P_buf, hp_buf, hin_buf);
  scan_chunk<true><<<dim3(32, 8, 8), 256, 0, stream>>>(dts_buf, xsT_buf, xdbl_buf,
      A_log, Ds, nullptr, nullptr, hin_buf);
  // 10. combine 4 directions -> y_comb (reuse xc_buf)
  combine_kernel<<<2048, 256, 0, stream>>>(xsT_buf, xc_buf);
  // 11. LN2 * silu(z) -> y_gated (reuse xca_buf)
  ln2gate_kernel<<<2048, 256, 0, stream>>>(xc_buf, xz_buf, xca_buf, on_g, on_b);
  // 12. t += y_gated @ out_w^T (MFMA split-K=4)
  mfma_nt<false><<<dim3(4, 32, 4), 256, 0, stream>>>(xca_buf, ow_hi, ow_lo, P_out,
      2048, 256, 512, 512, 128, 0);
  reduce_split<<<512, 256, 0, stream>>>(P_out, t_buf, nullptr, 524288, 256, 4, 1);
  // 13. pooled head
  head_partial<<<dim3(16, 2), 256, 0, stream>>>(t_buf, head_w, part_buf);
  head_final<<<1, 64, 0, stream>>>(part_buf, head_b, (float*)d_out);
}

// Round 4
// 220.165 us; speedup vs baseline: 3.6729x; 1.2661x over previous
//
#include <hip/hip_runtime.h>
#include <math.h>

// VMamba discriminator forward. GEMMs: bf16 MFMA with weight hi/lo split
// (systematic weight-rounding error -> 2^-18); activations bf16-hi, fp32 accum.
// Scan: chunk-parallel, n-states in registers (8 per thread, lane-pair split).
// B=2, C=256, IMG=128, P=4 -> H=W=32, L=1024, D_INNER=512, N=16, R=16, K=4

typedef __attribute__((ext_vector_type(4))) float f32x4;
typedef __attribute__((ext_vector_type(8))) short bf16x8;

__device__ __forceinline__ ushort bf16_rn(float f) {
  uint u = __float_as_uint(f);
  return (ushort)((u + 0x7fffu + ((u >> 16) & 1u)) >> 16);
}

// ---------------- split f32 -> bf16 hi + lo ----------------
__global__ __launch_bounds__(256) void split_bf16(const float* __restrict__ src,
    ushort* __restrict__ hi, ushort* __restrict__ lo, int n) {
  int i = blockIdx.x * 256 + threadIdx.x;
  if (i >= n) return;
  float f = src[i];
  ushort h = bf16_rn(f);
  hi[i] = h;
  float fh = __uint_as_float(((uint)h) << 16);
  lo[i] = bf16_rn(f - fh);
}

// ---------------- MFMA NT GEMM: C[m,n] = sum_k A[m,k]*(Bhi+Blo)[n,k] ---------
template<bool PATCH>
__global__ __launch_bounds__(256) void mfma_nt(
    const float* __restrict__ Af, const ushort* __restrict__ Bhi,
    const ushort* __restrict__ Blo, float* __restrict__ Cout,
    int M, int N, int K, int lda, int kchunk, int direct)
{
  __shared__ ushort Ah[64 * 40];
  __shared__ ushort Bh[64 * 40];
  __shared__ ushort Bl[64 * 40];
  int tid = threadIdx.x;
  int n0 = blockIdx.x * 64;
  int m0 = blockIdx.y * 64;
  int k0 = blockIdx.z * kchunk;
  int wid = tid >> 6, lane = tid & 63;
  int wm = wid >> 1, wn = wid & 1;
  int lrow = lane & 15, lk = (lane >> 4) * 8;
  f32x4 acc[2][2] = {};
  int nkt = kchunk >> 5;
  for (int kt = 0; kt < nkt; ++kt) {
    int kb = k0 + (kt << 5);
    #pragma unroll
    for (int i = 0; i < 2; ++i) {
      int idx = i * 256 + tid;
      int row = idx >> 3, kc = idx & 7;
      float4 v;
      if (PATCH) {
        int m = m0 + row;
        int b = m >> 10, l = m & 1023;
        int h = l >> 5, w = l & 31;
        int kg = kb + kc * 4;
        int ci = kg >> 4, ph = (kg >> 2) & 3;
        v = *(const float4*)(Af + ((((long)b * 256 + ci) * 128 + 4 * h + ph) * 128 + 4 * w));
      } else {
        v = *(const float4*)(Af + (long)(m0 + row) * lda + kb + kc * 4);
      }
      uint2 pk;
      pk.x = (uint)bf16_rn(v.x) | ((uint)bf16_rn(v.y) << 16);
      pk.y = (uint)bf16_rn(v.z) | ((uint)bf16_rn(v.w) << 16);
      *(uint2*)&Ah[row * 40 + kc * 4] = pk;
    }
    {
      int row = tid >> 2, kc8 = (tid & 3) * 8;
      long goff = (long)(n0 + row) * K + kb + kc8;
      *(uint4*)&Bh[row * 40 + kc8] = *(const uint4*)&Bhi[goff];
      *(uint4*)&Bl[row * 40 + kc8] = *(const uint4*)&Blo[goff];
    }
    __syncthreads();
    bf16x8 af[2], bhf[2], blf[2];
    #pragma unroll
    for (int mi = 0; mi < 2; ++mi)
      af[mi] = *(const bf16x8*)&Ah[(wm * 32 + mi * 16 + lrow) * 40 + lk];
    #pragma unroll
    for (int ni = 0; ni < 2; ++ni) {
      bhf[ni] = *(const bf16x8*)&Bh[(wn * 32 + ni * 16 + lrow) * 40 + lk];
      blf[ni] = *(const bf16x8*)&Bl[(wn * 32 + ni * 16 + lrow) * 40 + lk];
    }
    #pragma unroll
    for (int mi = 0; mi < 2; ++mi)
      #pragma unroll
      for (int ni = 0; ni < 2; ++ni) {
        acc[mi][ni] = __builtin_amdgcn_mfma_f32_16x16x32_bf16(af[mi], bhf[ni], acc[mi][ni], 0, 0, 0);
        acc[mi][ni] = __builtin_amdgcn_mfma_f32_16x16x32_bf16(af[mi], blf[ni], acc[mi][ni], 0, 0, 0);
      }
    __syncthreads();
  }
  long zoff = direct ? 0 : (long)blockIdx.z * M * N;
  int r4 = lane >> 4;
  #pragma unroll
  for (int mi = 0; mi < 2; ++mi)
    #pragma unroll
    for (int ni = 0; ni < 2; ++ni) {
      int n = n0 + wn * 32 + ni * 16 + lrow;
      int mb = m0 + wm * 32 + mi * 16 + r4 * 4;
      #pragma unroll
      for (int r = 0; r < 4; ++r)
        Cout[zoff + (long)(mb + r) * N + n] = acc[mi][ni][r];
    }
}

// ---------------- reduce split-K partials: C (=/+=) sum_s P + bias ----------
__global__ __launch_bounds__(256) void reduce_split(const float* __restrict__ P,
    float* __restrict__ C, const float* __restrict__ bias,
    int MN, int N, int S, int accumulate) {
  int i = blockIdx.x * 256 + threadIdx.x;
  if (i * 4 >= MN) return;
  float4 v = make_float4(0.f, 0.f, 0.f, 0.f);
  for (int s = 0; s < S; ++s) {
    float4 p = *(const float4*)(P + (long)s * MN + i * 4);
    v.x += p.x; v.y += p.y; v.z += p.z; v.w += p.w;
  }
  if (bias) {
    float4 bv = *(const float4*)(bias + ((i * 4) & (N - 1)));
    v.x += bv.x; v.y += bv.y; v.z += bv.z; v.w += bv.w;
  }
  if (accumulate) {
    float4 o = *(const float4*)(C + (long)i * 4);
    v.x += o.x; v.y += o.y; v.z += o.z; v.w += o.w;
  }
  *(float4*)(C + (long)i * 4) = v;
}

// ---------------- generic NT GEMM (fp32 VALU) for small GEMMs ----------------
template<int ACT>
__global__ __launch_bounds__(256) void gemm_nt(
    const float* __restrict__ Ag, const float* __restrict__ Bg,
    const float* __restrict__ biasg, float* Cg,
    int M, int N, int Kd, int lda, int ldb, int ldc,
    long sA, long sB, long sBias, long sC, int bmod, int accumulate)
{
  __shared__ __align__(16) float As[64 * 36];
  __shared__ float Bs[32 * 33];
  int z = blockIdx.z;
  int zb = (bmod > 1) ? (z % bmod) : 0;
  const float* A = Ag + (long)z * sA;
  const float* Bm = Bg + (long)zb * sB;
  const float* bias = biasg ? (biasg + (long)zb * sBias) : nullptr;
  float* C = Cg + (long)z * sC;
  int tid = threadIdx.x;
  int n0 = blockIdx.x * 32;
  int m0 = blockIdx.y * 64;
  int tn = tid & 7, tm = tid >> 3;
  float acc[2][4] = {};
  int nk = (Kd + 31) >> 5;
  for (int kt = 0; kt < nk; ++kt) {
    int k0 = kt << 5;
    #pragma unroll
    for (int i = 0; i < 2; ++i) {
      int idx = i * 256 + tid;
      int row = idx >> 3, c4 = idx & 7;
      int m = m0 + row, k = k0 + c4 * 4;
      float4 v = make_float4(0.f, 0.f, 0.f, 0.f);
      if (m < M && k < Kd) v = *(const float4*)(A + (long)m * lda + k);
      *(float4*)&As[row * 36 + c4 * 4] = v;
    }
    {
      int row = tid >> 3, c4 = tid & 7;
      int n = n0 + row, k = k0 + c4 * 4;
      float4 v = make_float4(0.f, 0.f, 0.f, 0.f);
      if (n < N && k < Kd) v = *(const float4*)(Bm + (long)n * ldb + k);
      Bs[row * 33 + c4 * 4 + 0] = v.x;
      Bs[row * 33 + c4 * 4 + 1] = v.y;
      Bs[row * 33 + c4 * 4 + 2] = v.z;
      Bs[row * 33 + c4 * 4 + 3] = v.w;
    }
    __syncthreads();
    #pragma unroll
    for (int kk = 0; kk < 32; ++kk) {
      float a0 = As[(tm * 2 + 0) * 36 + kk];
      float a1 = As[(tm * 2 + 1) * 36 + kk];
      #pragma unroll
      for (int j = 0; j < 4; ++j) {
        float bv = Bs[(tn * 4 + j) * 33 + kk];
        acc[0][j] += a0 * bv;
        acc[1][j] += a1 * bv;
      }
    }
    __syncthreads();
  }
  bool fullN = (n0 + 32 <= N);
  #pragma unroll
  for (int i = 0; i < 2; ++i) {
    int m = m0 + tm * 2 + i;
    if (m >= M) continue;
    float r[4];
    #pragma unroll
    for (int j = 0; j < 4; ++j) {
      int n = n0 + tn * 4 + j;
      float v = acc[i][j];
      if (bias && n < N) v += bias[n];
      if (ACT == 1) v = (v > 20.f) ? v : __logf(1.f + __expf(v));  // softplus
      r[j] = v;
    }
    long base = (long)m * ldc + n0 + tn * 4;
    if (fullN) {
      float4 o = make_float4(r[0], r[1], r[2], r[3]);
      if (accumulate) {
        float4 old = *(float4*)(C + base);
        o.x += old.x; o.y += old.y; o.z += old.z; o.w += old.w;
      }
      *(float4*)(C + base) = o;
    } else {
      #pragma unroll
      for (int j = 0; j < 4; ++j) {
        int n = n0 + tn * 4 + j;
        if (n < N) {
          float v = r[j];
          if (accumulate) v += C[(long)m * ldc + n];
          C[(long)m * ldc + n] = v;
        }
      }
    }
  }
}

// ---------------- block reduce helper (256 threads) ----------------
__device__ __forceinline__ float blk_sum(float v, float* sm) {
  #pragma unroll
  for (int o = 32; o > 0; o >>= 1) v += __shfl_down(v, o);
  int wid = threadIdx.x >> 6, lane = threadIdx.x & 63;
  __syncthreads();
  if (lane == 0) sm[wid] = v;
  __syncthreads();
  int nw = blockDim.x >> 6;
  float r = 0.f;
  for (int i = 0; i < nw; ++i) r += sm[i];
  return r;
}

// ---------------- LN over C=256 ----------------
__global__ __launch_bounds__(256) void ln1_kernel(const float* __restrict__ t,
    float* __restrict__ u, const float* __restrict__ g, const float* __restrict__ b) {
  __shared__ float sm[8];
  int m = blockIdx.x, c = threadIdx.x;
  float v = t[(long)m * 256 + c];
  float s = blk_sum(v, sm);
  float s2 = blk_sum(v * v, sm);
  float mu = s * (1.f / 256.f);
  float var = s2 * (1.f / 256.f) - mu * mu;
  float rs = rsqrtf(var + 1e-5f);
  u[(long)m * 256 + c] = (v - mu) * rs * g[c] + b[c];
}

// ---------------- transpose xz[:, :512] -> xc (B,512,32,32) ----------------
__global__ __launch_bounds__(256) void repack_xc(const float* __restrict__ xz, float* __restrict__ xc) {
  __shared__ float tile[32][33];
  int b = blockIdx.z, l0 = blockIdx.x * 32, d0 = blockIdx.y * 32;
  int tid = threadIdx.x;
  int a = tid >> 5, q = tid & 31;
  #pragma unroll
  for (int i = 0; i < 4; ++i) {
    int li = a + i * 8;
    tile[li][q] = xz[((long)(b * 1024 + l0 + li)) * 1024 + d0 + q];
  }
  __syncthreads();
  #pragma unroll
  for (int i = 0; i < 4; ++i) {
    int dj = a + i * 8;
    xc[((long)(b * 512 + d0 + dj)) * 1024 + l0 + q] = tile[q][dj];
  }
}

// ---------------- depthwise 3x3 + bias + silu ----------------
__global__ __launch_bounds__(256) void dwconv_kernel(const float* __restrict__ xc,
    const float* __restrict__ cw, const float* __restrict__ cb, float* __restrict__ out) {
  __shared__ float plane[32][33];
  int d = blockIdx.x, b = blockIdx.y;
  long base = ((long)b * 512 + d) * 1024;
  int tid = threadIdx.x;
  float4 v = *(const float4*)(xc + base + tid * 4);
  int h0 = (tid * 4) >> 5, w0 = (tid * 4) & 31;
  plane[h0][w0 + 0] = v.x; plane[h0][w0 + 1] = v.y;
  plane[h0][w0 + 2] = v.z; plane[h0][w0 + 3] = v.w;
  float w9[9];
  #pragma unroll
  for (int i = 0; i < 9; ++i) w9[i] = cw[d * 9 + i];
  float bias = cb[d];
  __syncthreads();
  float4 o;
  float* op = &o.x;
  #pragma unroll
  for (int j = 0; j < 4; ++j) {
    int p = tid * 4 + j, h = p >> 5, w = p & 31;
    float acc = 0.f;
    #pragma unroll
    for (int dh = -1; dh <= 1; ++dh) {
      int hy = h + dh;
      if (hy < 0 || hy > 31) continue;
      #pragma unroll
      for (int dw = -1; dw <= 1; ++dw) {
        int wx = w + dw;
        if (wx < 0 || wx > 31) continue;
        acc += w9[(dh + 1) * 3 + (dw + 1)] * plane[hy][wx];
      }
    }
    acc += bias;
    op[j] = acc / (1.f + __expf(-acc));  // silu
  }
  *(float4*)(out + base + tid * 4) = o;
}

// ---------------- build xsT (B,K,L,512) from xca (B,512,32,32) ----------------
__global__ __launch_bounds__(256) void build_xsT(const float* __restrict__ xca, float* __restrict__ xsT) {
  __shared__ float tile[32][33];
  int h = blockIdx.x;
  int d0 = blockIdx.y * 32;
  int z = blockIdx.z;          // z = b*4 + k
  int b = z >> 2, k = z & 3;
  int tid = threadIdx.x;
  int a = tid >> 5, q = tid & 31;
  #pragma unroll
  for (int i = 0; i < 4; ++i) {
    int di = a + i * 8;
    tile[di][q] = xca[((long)(b * 512 + d0 + di)) * 1024 + h * 32 + q];
  }
  __syncthreads();
  #pragma unroll
  for (int i = 0; i < 4; ++i) {
    int w = a + i * 8;
    int r;
    if (k == 0) r = h * 32 + w;
    else if (k == 1) r = w * 32 + h;
    else if (k == 2) r = 1023 - (h * 32 + w);
    else r = 1023 - (w * 32 + h);
    xsT[((long)z * 1024 + r) * 512 + d0 + q] = tile[q][w];
  }
}

// ---------------- chunk-parallel selective scan, states-in-registers ---------
// NC=8 chunks x LC=128. Block = 128 threads = 64 d x 2 n-halves; each thread
// owns h[8] in VGPRs. Phase1 (!FINAL): store P=exp(a*sum dt) and partial h.
// Phase3 (FINAL): start from h_in (in hpb, rewritten by prefix), write ys
// in-place over xsT. Grid (8 d-tiles, 8 chunks, 8 z).
template<bool FINAL>
__global__ __launch_bounds__(128) void scan_chunk2(
    const float* __restrict__ dts, float* xsT_ys, const float* __restrict__ xdbl,
    const float* __restrict__ A_log, const float* __restrict__ Ds,
    float* __restrict__ Pb, float* __restrict__ hpb)
{
  __shared__ float sdt[16][64], sxv[16][64], sy[16][64];
  __shared__ float sBC[128][32];     // [l][n]: n<16 -> B, n>=16 -> C
  int tid = threadIdx.x;
  int dl = tid >> 1, ng = tid & 1;
  int d0 = blockIdx.x * 64;
  int d = d0 + dl;
  int c = blockIdx.y;
  int z = blockIdx.z;
  int k = z & 3;
  long baseD = (long)z * 524288;
  long baseB = (long)z * 49152 + (long)c * 128 * 48;
  int l0 = c * 128;
  float a[8], h[8];
  #pragma unroll
  for (int j = 0; j < 8; ++j) {
    a[j] = -__expf(A_log[((long)k * 512 + d) * 16 + ng * 8 + j]);
    h[j] = 0.f;
  }
  int gbase = (c * 8 + z) * 8192 + d * 16 + ng * 8;
  float Dv = 0.f;
  if (FINAL) {
    #pragma unroll
    for (int j = 0; j < 8; ++j) h[j] = hpb[gbase + j];   // h_in (prefix in-place)
    Dv = Ds[k * 512 + d];
  }
  // stage B/C for the whole chunk
  #pragma unroll
  for (int i = 0; i < 2; ++i) {
    int idx = i * 128 + tid;
    int l = idx >> 1, half = idx & 1;
    const float* src = xdbl + baseB + l * 48 + 16 + half * 16;
    #pragma unroll
    for (int j = 0; j < 4; ++j)
      *(float4*)&sBC[l][half * 16 + j * 4] = *(const float4*)(src + j * 4);
  }
  float dtsum = 0.f;
  for (int t = 0; t < 8; ++t) {
    int lb = l0 + t * 16;
    __syncthreads();                     // sy of prev tile fully stored
    {
      int li = tid >> 4, dj = (tid & 15) * 4;
      #pragma unroll
      for (int i = 0; i < 2; ++i) {
        int lr = li + i * 8;
        long off = baseD + (long)(lb + lr) * 512 + d0 + dj;
        *(float4*)&sdt[lr][dj] = *(const float4*)(dts + off);
        *(float4*)&sxv[lr][dj] = *(const float4*)(xsT_ys + off);
      }
    }
    __syncthreads();
    #pragma unroll
    for (int li = 0; li < 16; ++li) {
      float dt = sdt[li][dl];
      float xv = sxv[li][dl];
      float w = dt * xv;
      int lr = t * 16 + li;
      if (!FINAL) {
        dtsum += dt;
        #pragma unroll
        for (int j = 0; j < 8; ++j)
          h[j] = __expf(dt * a[j]) * h[j] + w * sBC[lr][ng * 8 + j];
      } else {
        float p = 0.f;
        #pragma unroll
        for (int j = 0; j < 8; ++j) {
          h[j] = __expf(dt * a[j]) * h[j] + w * sBC[lr][ng * 8 + j];
          p += h[j] * sBC[lr][16 + ng * 8 + j];
        }
        p += __shfl_xor(p, 1);
        if (ng == 0) sy[li][dl] = p + Dv * xv;
      }
    }
    if (FINAL) {
      __syncthreads();
      int li = tid >> 4, dj = (tid & 15) * 4;
      #pragma unroll
      for (int i = 0; i < 2; ++i) {
        int lr = li + i * 8;
        long off = baseD + (long)(lb + lr) * 512 + d0 + dj;
        *(float4*)(xsT_ys + off) = *(float4*)&sy[lr][dj];
      }
    }
  }
  if (!FINAL) {
    float4 pv;
    #pragma unroll
    for (int i = 0; i < 2; ++i) {
      pv.x = __expf(dtsum * a[i * 4 + 0]);
      pv.y = __expf(dtsum * a[i * 4 + 1]);
      pv.z = __expf(dtsum * a[i * 4 + 2]);
      pv.w = __expf(dtsum * a[i * 4 + 3]);
      *(float4*)(Pb + gbase + i * 4) = pv;
      *(float4*)(hpb + gbase + i * 4) = make_float4(h[i*4+0], h[i*4+1], h[i*4+2], h[i*4+3]);
    }
  }
}

// prefix across the 8 chunks per (z,d,n); writes h_in in-place over hp
__global__ __launch_bounds__(256) void scan_prefix(const float* __restrict__ Pb,
    float* __restrict__ hpb) {
  int g = blockIdx.x * 256 + threadIdx.x;
  float h = 0.f;
  #pragma unroll
  for (int c = 0; c < 8; ++c) {
    float P = Pb[c * 65536 + g];
    float hp = hpb[c * 65536 + g];
    hpb[c * 65536 + g] = h;
    h = P * h + hp;
  }
}

// ---------------- combine 4 directions ----------------
__global__ __launch_bounds__(256) void combine_kernel(const float* __restrict__ ys, float* __restrict__ yc) {
  int m = blockIdx.x;
  int b = m >> 10, l = m & 1023;
  int h = l >> 5, w = l & 31;
  int lw = w * 32 + h;
  long b4 = (long)b * 4;
  int tid = threadIdx.x;
  #pragma unroll
  for (int i = 0; i < 2; ++i) {
    int d = tid + i * 256;
    float v = ys[((b4 + 0) * 1024 + l) * 512 + d]
            + ys[((b4 + 2) * 1024 + (1023 - l)) * 512 + d]
            + ys[((b4 + 1) * 1024 + lw) * 512 + d]
            + ys[((b4 + 3) * 1024 + (1023 - lw)) * 512 + d];
    yc[(long)m * 512 + d] = v;
  }
}

// ---------------- LN over 512 + silu(z) gate ----------------
__global__ __launch_bounds__(256) void ln2gate_kernel(const float* __restrict__ y,
    const float* __restrict__ xz, float* __restrict__ out,
    const float* __restrict__ g, const float* __restrict__ b) {
  __shared__ float sm[8];
  int m = blockIdx.x, tid = threadIdx.x;
  float v0 = y[(long)m * 512 + tid];
  float v1 = y[(long)m * 512 + tid + 256];
  float s = blk_sum(v0 + v1, sm);
  float s2 = blk_sum(v0 * v0 + v1 * v1, sm);
  float mu = s * (1.f / 512.f);
  float var = s2 * (1.f / 512.f) - mu * mu;
  float rs = rsqrtf(var + 1e-5f);
  #pragma unroll
  for (int i = 0; i < 2; ++i) {
    int c = tid + i * 256;
    float v = i ? v1 : v0;
    float yn = (v - mu) * rs * g[c] + b[c];
    float zz = xz[(long)m * 1024 + 512 + c];
    out[(long)m * 512 + c] = yn * (zz / (1.f + __expf(-zz)));
  }
}

// ---------------- pooled head ----------------
__global__ __launch_bounds__(256) void head_partial(const float* __restrict__ t,
    const float* __restrict__ hw, float* __restrict__ part) {
  __shared__ float sm[8];
  int j = blockIdx.x, b = blockIdx.y;
  int c = threadIdx.x;
  float s = 0.f;
  for (int l = j * 64; l < j * 64 + 64; ++l) s += t[((long)b * 1024 + l) * 256 + c];
  s *= hw[c];
  float tot = blk_sum(s, sm);
  if (c == 0) part[b * 16 + j] = tot;
}

__global__ void head_final(const float* __restrict__ part, const float* __restrict__ hb, float* __restrict__ out) {
  int tid = threadIdx.x;
  float v = (tid < 32) ? part[tid] : 0.f;
  #pragma unroll
  for (int o = 1; o < 16; o <<= 1) v += __shfl_xor(v, o);
  if (tid < 32 && (tid & 15) == 0) out[tid >> 4] = v * (1.f / 1024.f) + hb[0];
}

extern "C" void kernel_launch(void* const* d_in, const int* in_sizes, int n_in,
                              void* d_out, int out_size, void* d_ws, size_t ws_size,
                              hipStream_t stream) {
  const float* x       = (const float*)d_in[0];
  const float* patch_w = (const float*)d_in[1];
  const float* patch_b = (const float*)d_in[2];
  const float* ln_g    = (const float*)d_in[3];
  const float* ln_b    = (const float*)d_in[4];
  const float* in_w    = (const float*)d_in[5];
  const float* conv_w  = (const float*)d_in[6];
  const float* conv_b  = (const float*)d_in[7];
  const float* xproj_w = (const float*)d_in[8];
  const float* dt_w    = (const float*)d_in[9];
  const float* dt_b    = (const float*)d_in[10];
  const float* A_log   = (const float*)d_in[11];
  const float* Ds      = (const float*)d_in[12];
  const float* on_g    = (const float*)d_in[13];
  const float* on_b    = (const float*)d_in[14];
  const float* out_w   = (const float*)d_in[15];
  const float* head_w  = (const float*)d_in[16];
  const float* head_b  = (const float*)d_in[17];

  float* ws = (float*)d_ws;
  float* t_buf   = ws;                    // 2048*256
  float* u_buf   = t_buf + 524288;        // 2048*256
  float* xz_buf  = u_buf + 524288;        // 2048*1024
  float* xc_buf  = xz_buf + 2097152;      // 2*512*1024  (xc; P_scan; y_comb)
  float* xca_buf = xc_buf + 1048576;      // 2*512*1024  (xca; hp/h_in; y_gated)
  float* xsT_buf = xca_buf + 1048576;     // 8*1024*512  (P_patch+patchW splits; xs/ys)
  float* xdbl_buf= xsT_buf + 4194304;     // 8*1024*48
  float* dts_buf = xdbl_buf + 393216;     // 8*1024*512  (dts; later P_out)
  float* part_buf= dts_buf + 4194304;     // 32
  float* tail    = part_buf + 32;
  // scan scratch (dead-region reuse): P/hp each 8c*8z*512d*16n = 524288 f
  float* P_buf   = xc_buf;
  float* hp_buf  = xca_buf;
  // MFMA weight splits + split-K partials:
  float* P_patch = xsT_buf;                         // 4*2048*256 = 2097152 f
  ushort* pw_hi  = (ushort*)(xsT_buf + 2097152);
  ushort* pw_lo  = (ushort*)(xsT_buf + 2621440);
  float* P_out   = dts_buf;                         // 4*2048*256
  ushort* iw_hi  = (ushort*)tail;
  ushort* iw_lo  = (ushort*)(tail + 131072);
  ushort* ow_hi  = (ushort*)(tail + 262144);
  ushort* ow_lo  = (ushort*)(tail + 327680);

  // 0. weight hi/lo splits
  split_bf16<<<4096, 256, 0, stream>>>(patch_w, pw_hi, pw_lo, 1048576);
  split_bf16<<<1024, 256, 0, stream>>>(in_w, iw_hi, iw_lo, 262144);
  split_bf16<<<512, 256, 0, stream>>>(out_w, ow_hi, ow_lo, 131072);
  // 1. patch embed (im2col MFMA, split-K=4): t (2048,256)
  mfma_nt<true><<<dim3(4, 32, 4), 256, 0, stream>>>(x, pw_hi, pw_lo, P_patch,
      2048, 256, 4096, 0, 1024, 0);
  reduce_split<<<512, 256, 0, stream>>>(P_patch, t_buf, patch_b, 524288, 256, 4, 0);
  // 2. LN1 -> u
  ln1_kernel<<<2048, 256, 0, stream>>>(t_buf, u_buf, ln_g, ln_b);
  // 3. xz = u @ in_w^T  (2048,1024), direct
  mfma_nt<false><<<dim3(16, 32, 1), 256, 0, stream>>>(u_buf, iw_hi, iw_lo, xz_buf,
      2048, 1024, 256, 256, 256, 1);
  // 4. repack xc -> (B,512,32,32)
  repack_xc<<<dim3(32, 16, 2), 256, 0, stream>>>(xz_buf, xc_buf);
  // 5. depthwise conv + silu
  dwconv_kernel<<<dim3(512, 2), 256, 0, stream>>>(xc_buf, conv_w, conv_b, xca_buf);
  // 6. build xsT (B,K,L,512)
  build_xsT<<<dim3(32, 16, 8), 256, 0, stream>>>(xca_buf, xsT_buf);
  // 7. x_dbl[z] (1024,48) = xsT[z] @ xproj_w[k]^T
  gemm_nt<0><<<dim3(2, 16, 8), 256, 0, stream>>>(xsT_buf, xproj_w, nullptr, xdbl_buf,
      1024, 48, 512, 512, 512, 48, 524288, 24576, 0, 49152, 4, 0);
  // 8. dts[z] (1024,512) = softplus(x_dbl[:, :16] @ dt_w[k]^T + dt_b[k])
  gemm_nt<1><<<dim3(16, 16, 8), 256, 0, stream>>>(xdbl_buf, dt_w, dt_b, dts_buf,
      1024, 512, 16, 48, 16, 512, 49152, 8192, 512, 524288, 4, 0);
  // 9. chunk-parallel selective scan (states in registers)
  scan_chunk2<false><<<dim3(8, 8, 8), 128, 0, stream>>>(dts_buf, xsT_buf, xdbl_buf,
      A_log, Ds, P_buf, hp_buf);
  scan_prefix<<<256, 256, 0, stream>>>(P_buf, hp_buf);
  scan_chunk2<true><<<dim3(8, 8, 8), 128, 0, stream>>>(dts_buf, xsT_buf, xdbl_buf,
      A_log, Ds, nullptr, hp_buf);
  // 10. combine 4 directions -> y_comb (reuse xc_buf)
  combine_kernel<<<2048, 256, 0, stream>>>(xsT_buf, xc_buf);
  // 11. LN2 * silu(z) -> y_gated (reuse xca_buf)
  ln2gate_kernel<<<2048, 256, 0, stream>>>(xc_buf, xz_buf, xca_buf, on_g, on_b);
  // 12. t += y_gated @ out_w^T (MFMA split-K=4)
  mfma_nt<false><<<dim3(4, 32, 4), 256, 0, stream>>>(xca_buf, ow_hi, ow_lo, P_out,
      2048, 256, 512, 512, 128, 0);
  reduce_split<<<512, 256, 0, stream>>>(P_out, t_buf, nullptr, 524288, 256, 4, 1);
  // 13. pooled head
  head_partial<<<dim3(16, 2), 256, 0, stream>>>(t_buf, head_w, part_buf);
  head_final<<<1, 64, 0, stream>>>(part_buf, head_b, (float*)d_out);
}

// Round 5
// 206.916 us; speedup vs baseline: 3.9081x; 1.0640x over previous
//
#include <hip/hip_runtime.h>
#include <math.h>

// VMamba discriminator forward. GEMMs: bf16 MFMA with weight hi/lo split
// (systematic weight-rounding error -> 2^-18); activations pre-converted to
// bf16 (im2col for patch), fp32 accum. Scan: chunk-parallel, states in regs.
// B=2, C=256, IMG=128, P=4 -> H=W=32, L=1024, D_INNER=512, N=16, R=16, K=4

typedef __attribute__((ext_vector_type(4))) float f32x4;
typedef __attribute__((ext_vector_type(8))) short bf16x8;

__device__ __forceinline__ ushort bf16_rn(float f) {
  uint u = __float_as_uint(f);
  return (ushort)((u + 0x7fffu + ((u >> 16) & 1u)) >> 16);
}

// ---------------- split f32 -> bf16 hi + lo ----------------
__global__ __launch_bounds__(256) void split_bf16(const float* __restrict__ src,
    ushort* __restrict__ hi, ushort* __restrict__ lo, int n) {
  int i = blockIdx.x * 256 + threadIdx.x;
  if (i >= n) return;
  float f = src[i];
  ushort h = bf16_rn(f);
  hi[i] = h;
  float fh = __uint_as_float(((uint)h) << 16);
  lo[i] = bf16_rn(f - fh);
}

// ---------------- im2col + f32->bf16: x (B,256,128,128) -> A_p (2048,4096) ----
// kg = ci*16 + ph*4 + pw ; m = b*1024 + h*32 + w. Block: (8 ci) x (1 h) x (1 b).
__global__ __launch_bounds__(256) void im2col_bf16(const float* __restrict__ x,
    ushort* __restrict__ Ap) {
  __shared__ __align__(16) ushort tile[32][136];   // [w][ci8*16+ph*4+pw]
  int c0 = blockIdx.x * 8, hh = blockIdx.y, b = blockIdx.z;
  int tid = threadIdx.x;
  int ci = tid >> 5, ph = (tid >> 3) & 3, w4 = tid & 7;
  const float* src = x + (((long)(b * 256 + c0 + ci) * 128 + 4 * hh + ph) * 128 + 16 * w4);
  #pragma unroll
  for (int j = 0; j < 4; ++j) {
    float4 v = *(const float4*)(src + 4 * j);
    uint2 pk;
    pk.x = (uint)bf16_rn(v.x) | ((uint)bf16_rn(v.y) << 16);
    pk.y = (uint)bf16_rn(v.z) | ((uint)bf16_rn(v.w) << 16);
    *(uint2*)&tile[w4 * 4 + j][ci * 16 + ph * 4] = pk;
  }
  __syncthreads();
  int w = tid >> 3;
  long rowbase = ((long)(b * 1024 + hh * 32 + w)) * 4096 + c0 * 16;
  #pragma unroll
  for (int i = 0; i < 2; ++i) {
    int gr = (tid & 7) + 8 * i;
    *(uint4*)&Ap[rowbase + gr * 8] = *(const uint4*)&tile[w][gr * 8];
  }
}

// ---------------- MFMA NT GEMM (bf16 A, hi/lo bf16 B, fp32 out) --------------
// C[m,n] = sum_k A[m,k]*(Bhi+Blo)[n,k]. Tile 128M x 64N, BK=64, 512 thr
// (8 waves = 4m x 2n, each wave 32x32 via 2x2 16x16x32 MFMA frags).
// LDS rows 64 bf16 = 128B, XOR swizzle on 16B granules: gr ^= (row&7).
__global__ __launch_bounds__(512) void mfma_bf(
    const ushort* __restrict__ A, const ushort* __restrict__ Bhi,
    const ushort* __restrict__ Blo, float* __restrict__ Cout,
    int M, int N, int K, int kchunk, int direct)
{
  __shared__ __align__(16) ushort Ah[128 * 64];
  __shared__ __align__(16) ushort Bh[64 * 64];
  __shared__ __align__(16) ushort Bl[64 * 64];
  int tid = threadIdx.x;
  int n0 = blockIdx.x * 64;
  int m0 = blockIdx.y * 128;
  int k0 = blockIdx.z * kchunk;
  int wid = tid >> 6, lane = tid & 63;
  int wm = wid >> 1, wn = wid & 1;
  int lrow = lane & 15, g = lane >> 4;
  f32x4 acc[2][2] = {};
  int nkt = kchunk >> 6;
  for (int kt = 0; kt < nkt; ++kt) {
    int kb = k0 + (kt << 6);
    // stage A: 128 rows x 8 granules(16B); thread -> (row, gi), 2 passes
    {
      int gi = tid & 7;
      #pragma unroll
      for (int i = 0; i < 2; ++i) {
        int row = (tid >> 3) + (i << 6);
        uint4 v = *(const uint4*)&A[(long)(m0 + row) * K + kb + gi * 8];
        *(uint4*)&Ah[row * 64 + ((gi ^ (row & 7)) << 3)] = v;
      }
      // stage B hi/lo: 64 rows x 8 granules each
      int row = tid >> 3;
      long off = (long)(n0 + row) * K + kb + gi * 8;
      int la = row * 64 + ((gi ^ (row & 7)) << 3);
      *(uint4*)&Bh[la] = *(const uint4*)&Bhi[off];
      *(uint4*)&Bl[la] = *(const uint4*)&Blo[off];
    }
    __syncthreads();
    #pragma unroll
    for (int kk = 0; kk < 2; ++kk) {
      bf16x8 af[2], bhf[2], blf[2];
      #pragma unroll
      for (int mi = 0; mi < 2; ++mi) {
        int row = wm * 32 + mi * 16 + lrow;
        af[mi] = *(const bf16x8*)&Ah[row * 64 + ((((kk << 2) + g) ^ (row & 7)) << 3)];
      }
      #pragma unroll
      for (int ni = 0; ni < 2; ++ni) {
        int row = wn * 32 + ni * 16 + lrow;
        int col = (((kk << 2) + g) ^ (row & 7)) << 3;
        bhf[ni] = *(const bf16x8*)&Bh[row * 64 + col];
        blf[ni] = *(const bf16x8*)&Bl[row * 64 + col];
      }
      #pragma unroll
      for (int mi = 0; mi < 2; ++mi)
        #pragma unroll
        for (int ni = 0; ni < 2; ++ni) {
          acc[mi][ni] = __builtin_amdgcn_mfma_f32_16x16x32_bf16(af[mi], bhf[ni], acc[mi][ni], 0, 0, 0);
          acc[mi][ni] = __builtin_amdgcn_mfma_f32_16x16x32_bf16(af[mi], blf[ni], acc[mi][ni], 0, 0, 0);
        }
    }
    __syncthreads();
  }
  long zoff = direct ? 0 : (long)blockIdx.z * M * N;
  int r4 = lane >> 4;
  #pragma unroll
  for (int mi = 0; mi < 2; ++mi)
    #pragma unroll
    for (int ni = 0; ni < 2; ++ni) {
      int n = n0 + wn * 32 + ni * 16 + lrow;
      int mb = m0 + wm * 32 + mi * 16 + r4 * 4;
      #pragma unroll
      for (int r = 0; r < 4; ++r)
        Cout[zoff + (long)(mb + r) * N + n] = acc[mi][ni][r];
    }
}

// ---------------- reduce split-K partials: C (=/+=) sum_s P + bias ----------
__global__ __launch_bounds__(256) void reduce_split(const float* __restrict__ P,
    float* __restrict__ C, const float* __restrict__ bias,
    int MN, int N, int S, int accumulate) {
  int i = blockIdx.x * 256 + threadIdx.x;
  if (i * 4 >= MN) return;
  float4 v = make_float4(0.f, 0.f, 0.f, 0.f);
  for (int s = 0; s < S; ++s) {
    float4 p = *(const float4*)(P + (long)s * MN + i * 4);
    v.x += p.x; v.y += p.y; v.z += p.z; v.w += p.w;
  }
  if (bias) {
    float4 bv = *(const float4*)(bias + ((i * 4) & (N - 1)));
    v.x += bv.x; v.y += bv.y; v.z += bv.z; v.w += bv.w;
  }
  if (accumulate) {
    float4 o = *(const float4*)(C + (long)i * 4);
    v.x += o.x; v.y += o.y; v.z += o.z; v.w += o.w;
  }
  *(float4*)(C + (long)i * 4) = v;
}

// ---------------- generic NT GEMM (fp32 VALU) for small GEMMs ----------------
template<int ACT>
__global__ __launch_bounds__(256) void gemm_nt(
    const float* __restrict__ Ag, const float* __restrict__ Bg,
    const float* __restrict__ biasg, float* Cg,
    int M, int N, int Kd, int lda, int ldb, int ldc,
    long sA, long sB, long sBias, long sC, int bmod, int accumulate)
{
  __shared__ __align__(16) float As[64 * 36];
  __shared__ float Bs[32 * 33];
  int z = blockIdx.z;
  int zb = (bmod > 1) ? (z % bmod) : 0;
  const float* A = Ag + (long)z * sA;
  const float* Bm = Bg + (long)zb * sB;
  const float* bias = biasg ? (biasg + (long)zb * sBias) : nullptr;
  float* C = Cg + (long)z * sC;
  int tid = threadIdx.x;
  int n0 = blockIdx.x * 32;
  int m0 = blockIdx.y * 64;
  int tn = tid & 7, tm = tid >> 3;
  float acc[2][4] = {};
  int nk = (Kd + 31) >> 5;
  for (int kt = 0; kt < nk; ++kt) {
    int k0 = kt << 5;
    #pragma unroll
    for (int i = 0; i < 2; ++i) {
      int idx = i * 256 + tid;
      int row = idx >> 3, c4 = idx & 7;
      int m = m0 + row, k = k0 + c4 * 4;
      float4 v = make_float4(0.f, 0.f, 0.f, 0.f);
      if (m < M && k < Kd) v = *(const float4*)(A + (long)m * lda + k);
      *(float4*)&As[row * 36 + c4 * 4] = v;
    }
    {
      int row = tid >> 3, c4 = tid & 7;
      int n = n0 + row, k = k0 + c4 * 4;
      float4 v = make_float4(0.f, 0.f, 0.f, 0.f);
      if (n < N && k < Kd) v = *(const float4*)(Bm + (long)n * ldb + k);
      Bs[row * 33 + c4 * 4 + 0] = v.x;
      Bs[row * 33 + c4 * 4 + 1] = v.y;
      Bs[row * 33 + c4 * 4 + 2] = v.z;
      Bs[row * 33 + c4 * 4 + 3] = v.w;
    }
    __syncthreads();
    #pragma unroll
    for (int kk = 0; kk < 32; ++kk) {
      float a0 = As[(tm * 2 + 0) * 36 + kk];
      float a1 = As[(tm * 2 + 1) * 36 + kk];
      #pragma unroll
      for (int j = 0; j < 4; ++j) {
        float bv = Bs[(tn * 4 + j) * 33 + kk];
        acc[0][j] += a0 * bv;
        acc[1][j] += a1 * bv;
      }
    }
    __syncthreads();
  }
  bool fullN = (n0 + 32 <= N);
  #pragma unroll
  for (int i = 0; i < 2; ++i) {
    int m = m0 + tm * 2 + i;
    if (m >= M) continue;
    float r[4];
    #pragma unroll
    for (int j = 0; j < 4; ++j) {
      int n = n0 + tn * 4 + j;
      float v = acc[i][j];
      if (bias && n < N) v += bias[n];
      if (ACT == 1) v = (v > 20.f) ? v : __logf(1.f + __expf(v));  // softplus
      r[j] = v;
    }
    long base = (long)m * ldc + n0 + tn * 4;
    if (fullN) {
      float4 o = make_float4(r[0], r[1], r[2], r[3]);
      if (accumulate) {
        float4 old = *(float4*)(C + base);
        o.x += old.x; o.y += old.y; o.z += old.z; o.w += old.w;
      }
      *(float4*)(C + base) = o;
    } else {
      #pragma unroll
      for (int j = 0; j < 4; ++j) {
        int n = n0 + tn * 4 + j;
        if (n < N) {
          float v = r[j];
          if (accumulate) v += C[(long)m * ldc + n];
          C[(long)m * ldc + n] = v;
        }
      }
    }
  }
}

// ---------------- block reduce helper (256 threads) ----------------
__device__ __forceinline__ float blk_sum(float v, float* sm) {
  #pragma unroll
  for (int o = 32; o > 0; o >>= 1) v += __shfl_down(v, o);
  int wid = threadIdx.x >> 6, lane = threadIdx.x & 63;
  __syncthreads();
  if (lane == 0) sm[wid] = v;
  __syncthreads();
  int nw = blockDim.x >> 6;
  float r = 0.f;
  for (int i = 0; i < nw; ++i) r += sm[i];
  return r;
}

// ---------------- LN over C=256 (bf16 output for MFMA GEMM) ----------------
__global__ __launch_bounds__(256) void ln1_kernel(const float* __restrict__ t,
    ushort* __restrict__ u, const float* __restrict__ g, const float* __restrict__ b) {
  __shared__ float sm[8];
  int m = blockIdx.x, c = threadIdx.x;
  float v = t[(long)m * 256 + c];
  float s = blk_sum(v, sm);
  float s2 = blk_sum(v * v, sm);
  float mu = s * (1.f / 256.f);
  float var = s2 * (1.f / 256.f) - mu * mu;
  float rs = rsqrtf(var + 1e-5f);
  u[(long)m * 256 + c] = bf16_rn((v - mu) * rs * g[c] + b[c]);
}

// ---------------- transpose xz[:, :512] -> xc (B,512,32,32) ----------------
__global__ __launch_bounds__(256) void repack_xc(const float* __restrict__ xz, float* __restrict__ xc) {
  __shared__ float tile[32][33];
  int b = blockIdx.z, l0 = blockIdx.x * 32, d0 = blockIdx.y * 32;
  int tid = threadIdx.x;
  int a = tid >> 5, q = tid & 31;
  #pragma unroll
  for (int i = 0; i < 4; ++i) {
    int li = a + i * 8;
    tile[li][q] = xz[((long)(b * 1024 + l0 + li)) * 1024 + d0 + q];
  }
  __syncthreads();
  #pragma unroll
  for (int i = 0; i < 4; ++i) {
    int dj = a + i * 8;
    xc[((long)(b * 512 + d0 + dj)) * 1024 + l0 + q] = tile[q][dj];
  }
}

// ---------------- depthwise 3x3 + bias + silu ----------------
__global__ __launch_bounds__(256) void dwconv_kernel(const float* __restrict__ xc,
    const float* __restrict__ cw, const float* __restrict__ cb, float* __restrict__ out) {
  __shared__ float plane[32][33];
  int d = blockIdx.x, b = blockIdx.y;
  long base = ((long)b * 512 + d) * 1024;
  int tid = threadIdx.x;
  float4 v = *(const float4*)(xc + base + tid * 4);
  int h0 = (tid * 4) >> 5, w0 = (tid * 4) & 31;
  plane[h0][w0 + 0] = v.x; plane[h0][w0 + 1] = v.y;
  plane[h0][w0 + 2] = v.z; plane[h0][w0 + 3] = v.w;
  float w9[9];
  #pragma unroll
  for (int i = 0; i < 9; ++i) w9[i] = cw[d * 9 + i];
  float bias = cb[d];
  __syncthreads();
  float4 o;
  float* op = &o.x;
  #pragma unroll
  for (int j = 0; j < 4; ++j) {
    int p = tid * 4 + j, h = p >> 5, w = p & 31;
    float acc = 0.f;
    #pragma unroll
    for (int dh = -1; dh <= 1; ++dh) {
      int hy = h + dh;
      if (hy < 0 || hy > 31) continue;
      #pragma unroll
      for (int dw = -1; dw <= 1; ++dw) {
        int wx = w + dw;
        if (wx < 0 || wx > 31) continue;
        acc += w9[(dh + 1) * 3 + (dw + 1)] * plane[hy][wx];
      }
    }
    acc += bias;
    op[j] = acc / (1.f + __expf(-acc));  // silu
  }
  *(float4*)(out + base + tid * 4) = o;
}

// ---------------- build xsT (B,K,L,512) from xca (B,512,32,32) ----------------
__global__ __launch_bounds__(256) void build_xsT(const float* __restrict__ xca, float* __restrict__ xsT) {
  __shared__ float tile[32][33];
  int h = blockIdx.x;
  int d0 = blockIdx.y * 32;
  int z = blockIdx.z;          // z = b*4 + k
  int b = z >> 2, k = z & 3;
  int tid = threadIdx.x;
  int a = tid >> 5, q = tid & 31;
  #pragma unroll
  for (int i = 0; i < 4; ++i) {
    int di = a + i * 8;
    tile[di][q] = xca[((long)(b * 512 + d0 + di)) * 1024 + h * 32 + q];
  }
  __syncthreads();
  #pragma unroll
  for (int i = 0; i < 4; ++i) {
    int w = a + i * 8;
    int r;
    if (k == 0) r = h * 32 + w;
    else if (k == 1) r = w * 32 + h;
    else if (k == 2) r = 1023 - (h * 32 + w);
    else r = 1023 - (w * 32 + h);
    xsT[((long)z * 1024 + r) * 512 + d0 + q] = tile[q][w];
  }
}

// ---------------- chunk-parallel selective scan, states-in-registers ---------
template<bool FINAL>
__global__ __launch_bounds__(128) void scan_chunk2(
    const float* __restrict__ dts, float* xsT_ys, const float* __restrict__ xdbl,
    const float* __restrict__ A_log, const float* __restrict__ Ds,
    float* __restrict__ Pb, float* __restrict__ hpb)
{
  __shared__ float sdt[16][64], sxv[16][64], sy[16][64];
  __shared__ float sBC[128][32];     // [l][n]: n<16 -> B, n>=16 -> C
  int tid = threadIdx.x;
  int dl = tid >> 1, ng = tid & 1;
  int d0 = blockIdx.x * 64;
  int d = d0 + dl;
  int c = blockIdx.y;
  int z = blockIdx.z;
  int k = z & 3;
  long baseD = (long)z * 524288;
  long baseB = (long)z * 49152 + (long)c * 128 * 48;
  int l0 = c * 128;
  float a[8], h[8];
  #pragma unroll
  for (int j = 0; j < 8; ++j) {
    a[j] = -__expf(A_log[((long)k * 512 + d) * 16 + ng * 8 + j]);
    h[j] = 0.f;
  }
  int gbase = (c * 8 + z) * 8192 + d * 16 + ng * 8;
  float Dv = 0.f;
  if (FINAL) {
    #pragma unroll
    for (int j = 0; j < 8; ++j) h[j] = hpb[gbase + j];   // h_in (prefix in-place)
    Dv = Ds[k * 512 + d];
  }
  #pragma unroll
  for (int i = 0; i < 2; ++i) {
    int idx = i * 128 + tid;
    int l = idx >> 1, half = idx & 1;
    const float* src = xdbl + baseB + l * 48 + 16 + half * 16;
    #pragma unroll
    for (int j = 0; j < 4; ++j)
      *(float4*)&sBC[l][half * 16 + j * 4] = *(const float4*)(src + j * 4);
  }
  float dtsum = 0.f;
  for (int t = 0; t < 8; ++t) {
    int lb = l0 + t * 16;
    __syncthreads();
    {
      int li = tid >> 4, dj = (tid & 15) * 4;
      #pragma unroll
      for (int i = 0; i < 2; ++i) {
        int lr = li + i * 8;
        long off = baseD + (long)(lb + lr) * 512 + d0 + dj;
        *(float4*)&sdt[lr][dj] = *(const float4*)(dts + off);
        *(float4*)&sxv[lr][dj] = *(const float4*)(xsT_ys + off);
      }
    }
    __syncthreads();
    #pragma unroll
    for (int li = 0; li < 16; ++li) {
      float dt = sdt[li][dl];
      float xv = sxv[li][dl];
      float w = dt * xv;
      int lr = t * 16 + li;
      if (!FINAL) {
        dtsum += dt;
        #pragma unroll
        for (int j = 0; j < 8; ++j)
          h[j] = __expf(dt * a[j]) * h[j] + w * sBC[lr][ng * 8 + j];
      } else {
        float p = 0.f;
        #pragma unroll
        for (int j = 0; j < 8; ++j) {
          h[j] = __expf(dt * a[j]) * h[j] + w * sBC[lr][ng * 8 + j];
          p += h[j] * sBC[lr][16 + ng * 8 + j];
        }
        p += __shfl_xor(p, 1);
        if (ng == 0) sy[li][dl] = p + Dv * xv;
      }
    }
    if (FINAL) {
      __syncthreads();
      int li = tid >> 4, dj = (tid & 15) * 4;
      #pragma unroll
      for (int i = 0; i < 2; ++i) {
        int lr = li + i * 8;
        long off = baseD + (long)(lb + lr) * 512 + d0 + dj;
        *(float4*)(xsT_ys + off) = *(float4*)&sy[lr][dj];
      }
    }
  }
  if (!FINAL) {
    float4 pv;
    #pragma unroll
    for (int i = 0; i < 2; ++i) {
      pv.x = __expf(dtsum * a[i * 4 + 0]);
      pv.y = __expf(dtsum * a[i * 4 + 1]);
      pv.z = __expf(dtsum * a[i * 4 + 2]);
      pv.w = __expf(dtsum * a[i * 4 + 3]);
      *(float4*)(Pb + gbase + i * 4) = pv;
      *(float4*)(hpb + gbase + i * 4) = make_float4(h[i*4+0], h[i*4+1], h[i*4+2], h[i*4+3]);
    }
  }
}

// prefix across the 8 chunks per (z,d,n); writes h_in in-place over hp
__global__ __launch_bounds__(256) void scan_prefix(const float* __restrict__ Pb,
    float* __restrict__ hpb) {
  int g = blockIdx.x * 256 + threadIdx.x;
  float h = 0.f;
  #pragma unroll
  for (int c = 0; c < 8; ++c) {
    float P = Pb[c * 65536 + g];
    float hp = hpb[c * 65536 + g];
    hpb[c * 65536 + g] = h;
    h = P * h + hp;
  }
}

// ---------------- combine 4 directions ----------------
__global__ __launch_bounds__(256) void combine_kernel(const float* __restrict__ ys, float* __restrict__ yc) {
  int m = blockIdx.x;
  int b = m >> 10, l = m & 1023;
  int h = l >> 5, w = l & 31;
  int lw = w * 32 + h;
  long b4 = (long)b * 4;
  int tid = threadIdx.x;
  #pragma unroll
  for (int i = 0; i < 2; ++i) {
    int d = tid + i * 256;
    float v = ys[((b4 + 0) * 1024 + l) * 512 + d]
            + ys[((b4 + 2) * 1024 + (1023 - l)) * 512 + d]
            + ys[((b4 + 1) * 1024 + lw) * 512 + d]
            + ys[((b4 + 3) * 1024 + (1023 - lw)) * 512 + d];
    yc[(long)m * 512 + d] = v;
  }
}

// ---------------- LN over 512 + silu(z) gate (bf16 output) ----------------
__global__ __launch_bounds__(256) void ln2gate_kernel(const float* __restrict__ y,
    const float* __restrict__ xz, ushort* __restrict__ out,
    const float* __restrict__ g, const float* __restrict__ b) {
  __shared__ float sm[8];
  int m = blockIdx.x, tid = threadIdx.x;
  float v0 = y[(long)m * 512 + tid];
  float v1 = y[(long)m * 512 + tid + 256];
  float s = blk_sum(v0 + v1, sm);
  float s2 = blk_sum(v0 * v0 + v1 * v1, sm);
  float mu = s * (1.f / 512.f);
  float var = s2 * (1.f / 512.f) - mu * mu;
  float rs = rsqrtf(var + 1e-5f);
  #pragma unroll
  for (int i = 0; i < 2; ++i) {
    int c = tid + i * 256;
    float v = i ? v1 : v0;
    float yn = (v - mu) * rs * g[c] + b[c];
    float zz = xz[(long)m * 1024 + 512 + c];
    out[(long)m * 512 + c] = bf16_rn(yn * (zz / (1.f + __expf(-zz))));
  }
}

// ---------------- pooled head ----------------
__global__ __launch_bounds__(256) void head_partial(const float* __restrict__ t,
    const float* __restrict__ hw, float* __restrict__ part) {
  __shared__ float sm[8];
  int j = blockIdx.x, b = blockIdx.y;
  int c = threadIdx.x;
  float s = 0.f;
  for (int l = j * 64; l < j * 64 + 64; ++l) s += t[((long)b * 1024 + l) * 256 + c];
  s *= hw[c];
  float tot = blk_sum(s, sm);
  if (c == 0) part[b * 16 + j] = tot;
}

__global__ void head_final(const float* __restrict__ part, const float* __restrict__ hb, float* __restrict__ out) {
  int tid = threadIdx.x;
  float v = (tid < 32) ? part[tid] : 0.f;
  #pragma unroll
  for (int o = 1; o < 16; o <<= 1) v += __shfl_xor(v, o);
  if (tid < 32 && (tid & 15) == 0) out[tid >> 4] = v * (1.f / 1024.f) + hb[0];
}

extern "C" void kernel_launch(void* const* d_in, const int* in_sizes, int n_in,
                              void* d_out, int out_size, void* d_ws, size_t ws_size,
                              hipStream_t stream) {
  const float* x       = (const float*)d_in[0];
  const float* patch_w = (const float*)d_in[1];
  const float* patch_b = (const float*)d_in[2];
  const float* ln_g    = (const float*)d_in[3];
  const float* ln_b    = (const float*)d_in[4];
  const float* in_w    = (const float*)d_in[5];
  const float* conv_w  = (const float*)d_in[6];
  const float* conv_b  = (const float*)d_in[7];
  const float* xproj_w = (const float*)d_in[8];
  const float* dt_w    = (const float*)d_in[9];
  const float* dt_b    = (const float*)d_in[10];
  const float* A_log   = (const float*)d_in[11];
  const float* Ds      = (const float*)d_in[12];
  const float* on_g    = (const float*)d_in[13];
  const float* on_b    = (const float*)d_in[14];
  const float* out_w   = (const float*)d_in[15];
  const float* head_w  = (const float*)d_in[16];
  const float* head_b  = (const float*)d_in[17];

  float* ws = (float*)d_ws;
  float* t_buf   = ws;                    // 2048*256
  float* u_buf   = t_buf + 524288;        // 2048*256   (u_bf16 overlay)
  float* xz_buf  = u_buf + 524288;        // 2048*1024  (pw splits overlay; xz)
  float* xc_buf  = xz_buf + 2097152;      // 2*512*1024 (xc; P_scan; y_comb)
  float* xca_buf = xc_buf + 1048576;      // 2*512*1024 (xca; hp/h_in; y_bf16)
  float* xsT_buf = xca_buf + 1048576;     // 8*1024*512 (A_p overlay; xs/ys)
  float* xdbl_buf= xsT_buf + 4194304;     // 8*1024*48
  float* dts_buf = xdbl_buf + 393216;     // 8*1024*512 (P_patch overlay; dts; P_out)
  float* part_buf= dts_buf + 4194304;     // 32
  float* tail    = part_buf + 32;
  // scan scratch (dead-region reuse): P/hp each 524288 f
  float* P_buf   = xc_buf;
  float* hp_buf  = xca_buf;
  // bf16 overlays + split-K partials:
  ushort* A_p    = (ushort*)xsT_buf;                // 2048*4096 us = 16 MB
  ushort* pw_hi  = (ushort*)xz_buf;                 // 1048576 us
  ushort* pw_lo  = (ushort*)(xz_buf + 524288);      // 1048576 us
  float*  P_patch= dts_buf;                         // 8*524288 f = 16 MB
  float*  P_out  = dts_buf;                         // 4*524288 f
  ushort* u_bf   = (ushort*)u_buf;                  // 2048*256 us
  ushort* y_bf   = (ushort*)xca_buf;                // 2048*512 us
  ushort* iw_hi  = (ushort*)tail;
  ushort* iw_lo  = (ushort*)(tail + 131072);
  ushort* ow_hi  = (ushort*)(tail + 262144);
  ushort* ow_lo  = (ushort*)(tail + 327680);

  // 0. weight hi/lo splits + im2col A
  split_bf16<<<4096, 256, 0, stream>>>(patch_w, pw_hi, pw_lo, 1048576);
  split_bf16<<<1024, 256, 0, stream>>>(in_w, iw_hi, iw_lo, 262144);
  split_bf16<<<512, 256, 0, stream>>>(out_w, ow_hi, ow_lo, 131072);
  im2col_bf16<<<dim3(32, 32, 2), 256, 0, stream>>>(x, A_p);
  // 1. patch embed MFMA, split-K=8: t (2048,256)
  mfma_bf<<<dim3(4, 16, 8), 512, 0, stream>>>(A_p, pw_hi, pw_lo, P_patch,
      2048, 256, 4096, 512, 0);
  reduce_split<<<512, 256, 0, stream>>>(P_patch, t_buf, patch_b, 524288, 256, 8, 0);
  // 2. LN1 -> u (bf16)
  ln1_kernel<<<2048, 256, 0, stream>>>(t_buf, u_bf, ln_g, ln_b);
  // 3. xz = u @ in_w^T  (2048,1024), direct
  mfma_bf<<<dim3(16, 16, 1), 512, 0, stream>>>(u_bf, iw_hi, iw_lo, xz_buf,
      2048, 1024, 256, 256, 1);
  // 4. repack xc -> (B,512,32,32)
  repack_xc<<<dim3(32, 16, 2), 256, 0, stream>>>(xz_buf, xc_buf);
  // 5. depthwise conv + silu
  dwconv_kernel<<<dim3(512, 2), 256, 0, stream>>>(xc_buf, conv_w, conv_b, xca_buf);
  // 6. build xsT (B,K,L,512)  (clobbers A_p - dead)
  build_xsT<<<dim3(32, 16, 8), 256, 0, stream>>>(xca_buf, xsT_buf);
  // 7. x_dbl[z] (1024,48) = xsT[z] @ xproj_w[k]^T
  gemm_nt<0><<<dim3(2, 16, 8), 256, 0, stream>>>(xsT_buf, xproj_w, nullptr, xdbl_buf,
      1024, 48, 512, 512, 512, 48, 524288, 24576, 0, 49152, 4, 0);
  // 8. dts[z] (1024,512) = softplus(...)  (clobbers P_patch - dead)
  gemm_nt<1><<<dim3(16, 16, 8), 256, 0, stream>>>(xdbl_buf, dt_w, dt_b, dts_buf,
      1024, 512, 16, 48, 16, 512, 49152, 8192, 512, 524288, 4, 0);
  // 9. chunk-parallel selective scan (states in registers)
  scan_chunk2<false><<<dim3(8, 8, 8), 128, 0, stream>>>(dts_buf, xsT_buf, xdbl_buf,
      A_log, Ds, P_buf, hp_buf);
  scan_prefix<<<256, 256, 0, stream>>>(P_buf, hp_buf);
  scan_chunk2<true><<<dim3(8, 8, 8), 128, 0, stream>>>(dts_buf, xsT_buf, xdbl_buf,
      A_log, Ds, nullptr, hp_buf);
  // 10. combine 4 directions -> y_comb (reuse xc_buf)
  combine_kernel<<<2048, 256, 0, stream>>>(xsT_buf, xc_buf);
  // 11. LN2 * silu(z) -> y_bf16 (reuse xca_buf)
  ln2gate_kernel<<<2048, 256, 0, stream>>>(xc_buf, xz_buf, y_bf, on_g, on_b);
  // 12. t += y @ out_w^T (MFMA split-K=4; P_out over dead dts)
  mfma_bf<<<dim3(4, 16, 4), 512, 0, stream>>>(y_bf, ow_hi, ow_lo, P_out,
      2048, 256, 512, 128, 0);
  reduce_split<<<512, 256, 0, stream>>>(P_out, t_buf, nullptr, 524288, 256, 4, 1);
  // 13. pooled head
  head_partial<<<dim3(16, 2), 256, 0, stream>>>(t_buf, head_w, part_buf);
  head_final<<<1, 64, 0, stream>>>(part_buf, head_b, (float*)d_out);
}

// Round 6
// 189.929 us; speedup vs baseline: 4.2576x; 1.0894x over previous
//
#include <hip/hip_runtime.h>
#include <math.h>

// VMamba discriminator forward. GEMMs: bf16 MFMA with weight hi/lo split
// (systematic weight-rounding error -> 2^-18); activations pre-converted to
// bf16 (im2col for patch), fp32 accum. Scan: chunk-parallel (NC=16), states
// in registers, float4 LDS reads, register-prefetched staging.
// B=2, C=256, IMG=128, P=4 -> H=W=32, L=1024, D_INNER=512, N=16, R=16, K=4

typedef __attribute__((ext_vector_type(4))) float f32x4;
typedef __attribute__((ext_vector_type(8))) short bf16x8;

__device__ __forceinline__ ushort bf16_rn(float f) {
  uint u = __float_as_uint(f);
  return (ushort)((u + 0x7fffu + ((u >> 16) & 1u)) >> 16);
}

// ---------------- split f32 -> bf16 hi + lo ----------------
__global__ __launch_bounds__(256) void split_bf16(const float* __restrict__ src,
    ushort* __restrict__ hi, ushort* __restrict__ lo, int n) {
  int i = blockIdx.x * 256 + threadIdx.x;
  if (i >= n) return;
  float f = src[i];
  ushort h = bf16_rn(f);
  hi[i] = h;
  float fh = __uint_as_float(((uint)h) << 16);
  lo[i] = bf16_rn(f - fh);
}

// ---------------- im2col + f32->bf16: x (B,256,128,128) -> A_p (2048,4096) ----
__global__ __launch_bounds__(256) void im2col_bf16(const float* __restrict__ x,
    ushort* __restrict__ Ap) {
  __shared__ __align__(16) ushort tile[32][136];
  int c0 = blockIdx.x * 8, hh = blockIdx.y, b = blockIdx.z;
  int tid = threadIdx.x;
  int ci = tid >> 5, ph = (tid >> 3) & 3, w4 = tid & 7;
  const float* src = x + (((long)(b * 256 + c0 + ci) * 128 + 4 * hh + ph) * 128 + 16 * w4);
  #pragma unroll
  for (int j = 0; j < 4; ++j) {
    float4 v = *(const float4*)(src + 4 * j);
    uint2 pk;
    pk.x = (uint)bf16_rn(v.x) | ((uint)bf16_rn(v.y) << 16);
    pk.y = (uint)bf16_rn(v.z) | ((uint)bf16_rn(v.w) << 16);
    *(uint2*)&tile[w4 * 4 + j][ci * 16 + ph * 4] = pk;
  }
  __syncthreads();
  int w = tid >> 3;
  long rowbase = ((long)(b * 1024 + hh * 32 + w)) * 4096 + c0 * 16;
  #pragma unroll
  for (int i = 0; i < 2; ++i) {
    int gr = (tid & 7) + 8 * i;
    *(uint4*)&Ap[rowbase + gr * 8] = *(const uint4*)&tile[w][gr * 8];
  }
}

// ---------------- MFMA NT GEMM (bf16 A, hi/lo bf16 B, fp32 out) --------------
__global__ __launch_bounds__(512) void mfma_bf(
    const ushort* __restrict__ A, const ushort* __restrict__ Bhi,
    const ushort* __restrict__ Blo, float* __restrict__ Cout,
    int M, int N, int K, int kchunk, int direct)
{
  __shared__ __align__(16) ushort Ah[128 * 64];
  __shared__ __align__(16) ushort Bh[64 * 64];
  __shared__ __align__(16) ushort Bl[64 * 64];
  int tid = threadIdx.x;
  int n0 = blockIdx.x * 64;
  int m0 = blockIdx.y * 128;
  int k0 = blockIdx.z * kchunk;
  int wid = tid >> 6, lane = tid & 63;
  int wm = wid >> 1, wn = wid & 1;
  int lrow = lane & 15, g = lane >> 4;
  f32x4 acc[2][2] = {};
  int nkt = kchunk >> 6;
  for (int kt = 0; kt < nkt; ++kt) {
    int kb = k0 + (kt << 6);
    {
      int gi = tid & 7;
      #pragma unroll
      for (int i = 0; i < 2; ++i) {
        int row = (tid >> 3) + (i << 6);
        uint4 v = *(const uint4*)&A[(long)(m0 + row) * K + kb + gi * 8];
        *(uint4*)&Ah[row * 64 + ((gi ^ (row & 7)) << 3)] = v;
      }
      int row = tid >> 3;
      long off = (long)(n0 + row) * K + kb + gi * 8;
      int la = row * 64 + ((gi ^ (row & 7)) << 3);
      *(uint4*)&Bh[la] = *(const uint4*)&Bhi[off];
      *(uint4*)&Bl[la] = *(const uint4*)&Blo[off];
    }
    __syncthreads();
    #pragma unroll
    for (int kk = 0; kk < 2; ++kk) {
      bf16x8 af[2], bhf[2], blf[2];
      #pragma unroll
      for (int mi = 0; mi < 2; ++mi) {
        int row = wm * 32 + mi * 16 + lrow;
        af[mi] = *(const bf16x8*)&Ah[row * 64 + ((((kk << 2) + g) ^ (row & 7)) << 3)];
      }
      #pragma unroll
      for (int ni = 0; ni < 2; ++ni) {
        int row = wn * 32 + ni * 16 + lrow;
        int col = (((kk << 2) + g) ^ (row & 7)) << 3;
        bhf[ni] = *(const bf16x8*)&Bh[row * 64 + col];
        blf[ni] = *(const bf16x8*)&Bl[row * 64 + col];
      }
      #pragma unroll
      for (int mi = 0; mi < 2; ++mi)
        #pragma unroll
        for (int ni = 0; ni < 2; ++ni) {
          acc[mi][ni] = __builtin_amdgcn_mfma_f32_16x16x32_bf16(af[mi], bhf[ni], acc[mi][ni], 0, 0, 0);
          acc[mi][ni] = __builtin_amdgcn_mfma_f32_16x16x32_bf16(af[mi], blf[ni], acc[mi][ni], 0, 0, 0);
        }
    }
    __syncthreads();
  }
  long zoff = direct ? 0 : (long)blockIdx.z * M * N;
  int r4 = lane >> 4;
  #pragma unroll
  for (int mi = 0; mi < 2; ++mi)
    #pragma unroll
    for (int ni = 0; ni < 2; ++ni) {
      int n = n0 + wn * 32 + ni * 16 + lrow;
      int mb = m0 + wm * 32 + mi * 16 + r4 * 4;
      #pragma unroll
      for (int r = 0; r < 4; ++r)
        Cout[zoff + (long)(mb + r) * N + n] = acc[mi][ni][r];
    }
}

// ---------------- reduce split-K partials: C (=/+=) sum_s P + bias ----------
__global__ __launch_bounds__(256) void reduce_split(const float* __restrict__ P,
    float* __restrict__ C, const float* __restrict__ bias,
    int MN, int N, int S, int accumulate) {
  int i = blockIdx.x * 256 + threadIdx.x;
  if (i * 4 >= MN) return;
  float4 v = make_float4(0.f, 0.f, 0.f, 0.f);
  for (int s = 0; s < S; ++s) {
    float4 p = *(const float4*)(P + (long)s * MN + i * 4);
    v.x += p.x; v.y += p.y; v.z += p.z; v.w += p.w;
  }
  if (bias) {
    float4 bv = *(const float4*)(bias + ((i * 4) & (N - 1)));
    v.x += bv.x; v.y += bv.y; v.z += bv.z; v.w += bv.w;
  }
  if (accumulate) {
    float4 o = *(const float4*)(C + (long)i * 4);
    v.x += o.x; v.y += o.y; v.z += o.z; v.w += o.w;
  }
  *(float4*)(C + (long)i * 4) = v;
}

// ---------------- generic NT GEMM (fp32 VALU) for small GEMMs ----------------
template<int ACT>
__global__ __launch_bounds__(256) void gemm_nt(
    const float* __restrict__ Ag, const float* __restrict__ Bg,
    const float* __restrict__ biasg, float* Cg,
    int M, int N, int Kd, int lda, int ldb, int ldc,
    long sA, long sB, long sBias, long sC, int bmod, int accumulate)
{
  __shared__ __align__(16) float As[64 * 36];
  __shared__ float Bs[32 * 33];
  int z = blockIdx.z;
  int zb = (bmod > 1) ? (z % bmod) : 0;
  const float* A = Ag + (long)z * sA;
  const float* Bm = Bg + (long)zb * sB;
  const float* bias = biasg ? (biasg + (long)zb * sBias) : nullptr;
  float* C = Cg + (long)z * sC;
  int tid = threadIdx.x;
  int n0 = blockIdx.x * 32;
  int m0 = blockIdx.y * 64;
  int tn = tid & 7, tm = tid >> 3;
  float acc[2][4] = {};
  int nk = (Kd + 31) >> 5;
  for (int kt = 0; kt < nk; ++kt) {
    int k0 = kt << 5;
    #pragma unroll
    for (int i = 0; i < 2; ++i) {
      int idx = i * 256 + tid;
      int row = idx >> 3, c4 = idx & 7;
      int m = m0 + row, k = k0 + c4 * 4;
      float4 v = make_float4(0.f, 0.f, 0.f, 0.f);
      if (m < M && k < Kd) v = *(const float4*)(A + (long)m * lda + k);
      *(float4*)&As[row * 36 + c4 * 4] = v;
    }
    {
      int row = tid >> 3, c4 = tid & 7;
      int n = n0 + row, k = k0 + c4 * 4;
      float4 v = make_float4(0.f, 0.f, 0.f, 0.f);
      if (n < N && k < Kd) v = *(const float4*)(Bm + (long)n * ldb + k);
      Bs[row * 33 + c4 * 4 + 0] = v.x;
      Bs[row * 33 + c4 * 4 + 1] = v.y;
      Bs[row * 33 + c4 * 4 + 2] = v.z;
      Bs[row * 33 + c4 * 4 + 3] = v.w;
    }
    __syncthreads();
    #pragma unroll
    for (int kk = 0; kk < 32; ++kk) {
      float a0 = As[(tm * 2 + 0) * 36 + kk];
      float a1 = As[(tm * 2 + 1) * 36 + kk];
      #pragma unroll
      for (int j = 0; j < 4; ++j) {
        float bv = Bs[(tn * 4 + j) * 33 + kk];
        acc[0][j] += a0 * bv;
        acc[1][j] += a1 * bv;
      }
    }
    __syncthreads();
  }
  bool fullN = (n0 + 32 <= N);
  #pragma unroll
  for (int i = 0; i < 2; ++i) {
    int m = m0 + tm * 2 + i;
    if (m >= M) continue;
    float r[4];
    #pragma unroll
    for (int j = 0; j < 4; ++j) {
      int n = n0 + tn * 4 + j;
      float v = acc[i][j];
      if (bias && n < N) v += bias[n];
      if (ACT == 1) v = (v > 20.f) ? v : __logf(1.f + __expf(v));  // softplus
      r[j] = v;
    }
    long base = (long)m * ldc + n0 + tn * 4;
    if (fullN) {
      float4 o = make_float4(r[0], r[1], r[2], r[3]);
      if (accumulate) {
        float4 old = *(float4*)(C + base);
        o.x += old.x; o.y += old.y; o.z += old.z; o.w += old.w;
      }
      *(float4*)(C + base) = o;
    } else {
      #pragma unroll
      for (int j = 0; j < 4; ++j) {
        int n = n0 + tn * 4 + j;
        if (n < N) {
          float v = r[j];
          if (accumulate) v += C[(long)m * ldc + n];
          C[(long)m * ldc + n] = v;
        }
      }
    }
  }
}

// ---------------- block reduce helper (256 threads) ----------------
__device__ __forceinline__ float blk_sum(float v, float* sm) {
  #pragma unroll
  for (int o = 32; o > 0; o >>= 1) v += __shfl_down(v, o);
  int wid = threadIdx.x >> 6, lane = threadIdx.x & 63;
  __syncthreads();
  if (lane == 0) sm[wid] = v;
  __syncthreads();
  int nw = blockDim.x >> 6;
  float r = 0.f;
  for (int i = 0; i < nw; ++i) r += sm[i];
  return r;
}

// ---------------- LN over C=256 (bf16 output for MFMA GEMM) ----------------
__global__ __launch_bounds__(256) void ln1_kernel(const float* __restrict__ t,
    ushort* __restrict__ u, const float* __restrict__ g, const float* __restrict__ b) {
  __shared__ float sm[8];
  int m = blockIdx.x, c = threadIdx.x;
  float v = t[(long)m * 256 + c];
  float s = blk_sum(v, sm);
  float s2 = blk_sum(v * v, sm);
  float mu = s * (1.f / 256.f);
  float var = s2 * (1.f / 256.f) - mu * mu;
  float rs = rsqrtf(var + 1e-5f);
  u[(long)m * 256 + c] = bf16_rn((v - mu) * rs * g[c] + b[c]);
}

// ---------------- transpose xz[:, :512] -> xc (B,512,32,32) ----------------
__global__ __launch_bounds__(256) void repack_xc(const float* __restrict__ xz, float* __restrict__ xc) {
  __shared__ float tile[32][33];
  int b = blockIdx.z, l0 = blockIdx.x * 32, d0 = blockIdx.y * 32;
  int tid = threadIdx.x;
  int a = tid >> 5, q = tid & 31;
  #pragma unroll
  for (int i = 0; i < 4; ++i) {
    int li = a + i * 8;
    tile[li][q] = xz[((long)(b * 1024 + l0 + li)) * 1024 + d0 + q];
  }
  __syncthreads();
  #pragma unroll
  for (int i = 0; i < 4; ++i) {
    int dj = a + i * 8;
    xc[((long)(b * 512 + d0 + dj)) * 1024 + l0 + q] = tile[q][dj];
  }
}

// ---------------- depthwise 3x3 + bias + silu ----------------
__global__ __launch_bounds__(256) void dwconv_kernel(const float* __restrict__ xc,
    const float* __restrict__ cw, const float* __restrict__ cb, float* __restrict__ out) {
  __shared__ float plane[32][33];
  int d = blockIdx.x, b = blockIdx.y;
  long base = ((long)b * 512 + d) * 1024;
  int tid = threadIdx.x;
  float4 v = *(const float4*)(xc + base + tid * 4);
  int h0 = (tid * 4) >> 5, w0 = (tid * 4) & 31;
  plane[h0][w0 + 0] = v.x; plane[h0][w0 + 1] = v.y;
  plane[h0][w0 + 2] = v.z; plane[h0][w0 + 3] = v.w;
  float w9[9];
  #pragma unroll
  for (int i = 0; i < 9; ++i) w9[i] = cw[d * 9 + i];
  float bias = cb[d];
  __syncthreads();
  float4 o;
  float* op = &o.x;
  #pragma unroll
  for (int j = 0; j < 4; ++j) {
    int p = tid * 4 + j, h = p >> 5, w = p & 31;
    float acc = 0.f;
    #pragma unroll
    for (int dh = -1; dh <= 1; ++dh) {
      int hy = h + dh;
      if (hy < 0 || hy > 31) continue;
      #pragma unroll
      for (int dw = -1; dw <= 1; ++dw) {
        int wx = w + dw;
        if (wx < 0 || wx > 31) continue;
        acc += w9[(dh + 1) * 3 + (dw + 1)] * plane[hy][wx];
      }
    }
    acc += bias;
    op[j] = acc / (1.f + __expf(-acc));  // silu
  }
  *(float4*)(out + base + tid * 4) = o;
}

// ---------------- build xsT (B,K,L,512) from xca (B,512,32,32) ----------------
__global__ __launch_bounds__(256) void build_xsT(const float* __restrict__ xca, float* __restrict__ xsT) {
  __shared__ float tile[32][33];
  int h = blockIdx.x;
  int d0 = blockIdx.y * 32;
  int z = blockIdx.z;          // z = b*4 + k
  int b = z >> 2, k = z & 3;
  int tid = threadIdx.x;
  int a = tid >> 5, q = tid & 31;
  #pragma unroll
  for (int i = 0; i < 4; ++i) {
    int di = a + i * 8;
    tile[di][q] = xca[((long)(b * 512 + d0 + di)) * 1024 + h * 32 + q];
  }
  __syncthreads();
  #pragma unroll
  for (int i = 0; i < 4; ++i) {
    int w = a + i * 8;
    int r;
    if (k == 0) r = h * 32 + w;
    else if (k == 1) r = w * 32 + h;
    else if (k == 2) r = 1023 - (h * 32 + w);
    else r = 1023 - (w * 32 + h);
    xsT[((long)z * 1024 + r) * 512 + d0 + q] = tile[q][w];
  }
}

// ---------------- chunk-parallel selective scan, NC=16, prefetch ------------
// LC=64, 4 l-tiles of 16. Block 128 thr = 64 d x 2 n-halves, h[8] in VGPRs.
// Grid (8 d-tiles, 16 chunks, 8 z). Phase1 (!FINAL): P=exp(a*sum dt), partial h.
// Phase3 (FINAL): start from h_in (in hpb after prefix), ys in-place over xsT.
template<bool FINAL>
__global__ __launch_bounds__(128) void scan_chunk3(
    const float* __restrict__ dts, float* xsT_ys, const float* __restrict__ xdbl,
    const float* __restrict__ A_log, const float* __restrict__ Ds,
    float* __restrict__ Pb, float* __restrict__ hpb)
{
  __shared__ float sdt[16][64], sxv[16][64], sy[16][64];
  __shared__ float sBC[64][32];     // [l][n]: n<16 -> B, n>=16 -> C
  int tid = threadIdx.x;
  int dl = tid >> 1, ng = tid & 1;
  int d0 = blockIdx.x * 64;
  int d = d0 + dl;
  int c = blockIdx.y;
  int z = blockIdx.z;
  int k = z & 3;
  long baseD = (long)z * 524288;
  int l0 = c * 64;
  const float* bptr = xdbl + (long)z * 49152 + (long)l0 * 48;
  float a[8], h[8];
  #pragma unroll
  for (int j = 0; j < 8; ++j) {
    a[j] = -__expf(A_log[((long)k * 512 + d) * 16 + ng * 8 + j]);
    h[j] = 0.f;
  }
  int gbase = (c * 8 + z) * 8192 + d * 16 + ng * 8;
  float Dv = 0.f;
  if (FINAL) {
    #pragma unroll
    for (int j = 0; j < 8; ++j) h[j] = hpb[gbase + j];   // h_in (prefix in-place)
    Dv = Ds[k * 512 + d];
  }
  // stage B/C for whole chunk: 64 l x 32
  #pragma unroll
  for (int i = 0; i < 2; ++i) {
    int idx = i * 128 + tid;
    int l = idx >> 1, half = idx & 1;
    const float* src = bptr + l * 48 + 16 + half * 16;
    *(float4*)&sBC[l][half * 16]     = *(const float4*)(src);
    *(float4*)&sBC[l][half * 16 + 4] = *(const float4*)(src + 4);
  }
  int sli = tid >> 4;              // 0..7
  int sdj = (tid & 15) * 4;
  float4 rdt[2], rxv[2];
  #pragma unroll
  for (int i = 0; i < 2; ++i) {    // prefetch tile 0
    long off = baseD + (long)(l0 + sli + i * 8) * 512 + d0 + sdj;
    rdt[i] = *(const float4*)(dts + off);
    rxv[i] = *(const float4*)(xsT_ys + off);
  }
  float dtsum = 0.f;
  for (int t = 0; t < 4; ++t) {
    #pragma unroll
    for (int i = 0; i < 2; ++i) {
      *(float4*)&sdt[sli + i * 8][sdj] = rdt[i];
      *(float4*)&sxv[sli + i * 8][sdj] = rxv[i];
    }
    __syncthreads();
    if (t < 3) {
      #pragma unroll
      for (int i = 0; i < 2; ++i) {  // prefetch next tile (hides under compute)
        long off = baseD + (long)(l0 + (t + 1) * 16 + sli + i * 8) * 512 + d0 + sdj;
        rdt[i] = *(const float4*)(dts + off);
        rxv[i] = *(const float4*)(xsT_ys + off);
      }
    }
    #pragma unroll
    for (int li = 0; li < 16; ++li) {
      float dt = sdt[li][dl];
      float xv = sxv[li][dl];
      float w = dt * xv;
      int lr = t * 16 + li;
      float4 B0 = *(const float4*)&sBC[lr][ng * 8];
      float4 B1 = *(const float4*)&sBC[lr][ng * 8 + 4];
      if (!FINAL) {
        dtsum += dt;
        h[0] = __expf(dt * a[0]) * h[0] + w * B0.x;
        h[1] = __expf(dt * a[1]) * h[1] + w * B0.y;
        h[2] = __expf(dt * a[2]) * h[2] + w * B0.z;
        h[3] = __expf(dt * a[3]) * h[3] + w * B0.w;
        h[4] = __expf(dt * a[4]) * h[4] + w * B1.x;
        h[5] = __expf(dt * a[5]) * h[5] + w * B1.y;
        h[6] = __expf(dt * a[6]) * h[6] + w * B1.z;
        h[7] = __expf(dt * a[7]) * h[7] + w * B1.w;
      } else {
        float4 C0 = *(const float4*)&sBC[lr][16 + ng * 8];
        float4 C1 = *(const float4*)&sBC[lr][16 + ng * 8 + 4];
        float p;
        h[0] = __expf(dt * a[0]) * h[0] + w * B0.x; p  = h[0] * C0.x;
        h[1] = __expf(dt * a[1]) * h[1] + w * B0.y; p += h[1] * C0.y;
        h[2] = __expf(dt * a[2]) * h[2] + w * B0.z; p += h[2] * C0.z;
        h[3] = __expf(dt * a[3]) * h[3] + w * B0.w; p += h[3] * C0.w;
        h[4] = __expf(dt * a[4]) * h[4] + w * B1.x; p += h[4] * C1.x;
        h[5] = __expf(dt * a[5]) * h[5] + w * B1.y; p += h[5] * C1.y;
        h[6] = __expf(dt * a[6]) * h[6] + w * B1.z; p += h[6] * C1.z;
        h[7] = __expf(dt * a[7]) * h[7] + w * B1.w; p += h[7] * C1.w;
        p += __shfl_xor(p, 1);
        if (ng == 0) sy[li][dl] = p + Dv * xv;
      }
    }
    __syncthreads();
    if (FINAL) {
      #pragma unroll
      for (int i = 0; i < 2; ++i) {
        long off = baseD + (long)(l0 + t * 16 + sli + i * 8) * 512 + d0 + sdj;
        *(float4*)(xsT_ys + off) = *(float4*)&sy[sli + i * 8][sdj];
      }
    }
  }
  if (!FINAL) {
    float4 pv;
    #pragma unroll
    for (int i = 0; i < 2; ++i) {
      pv.x = __expf(dtsum * a[i * 4 + 0]);
      pv.y = __expf(dtsum * a[i * 4 + 1]);
      pv.z = __expf(dtsum * a[i * 4 + 2]);
      pv.w = __expf(dtsum * a[i * 4 + 3]);
      *(float4*)(Pb + gbase + i * 4) = pv;
      *(float4*)(hpb + gbase + i * 4) = make_float4(h[i*4+0], h[i*4+1], h[i*4+2], h[i*4+3]);
    }
  }
}

// prefix across the 16 chunks per (z,d,n); writes h_in in-place over hp
__global__ __launch_bounds__(256) void scan_prefix(const float* __restrict__ Pb,
    float* __restrict__ hpb) {
  int g = blockIdx.x * 256 + threadIdx.x;
  float h = 0.f;
  #pragma unroll
  for (int c = 0; c < 16; ++c) {
    float P = Pb[c * 65536 + g];
    float hp = hpb[c * 65536 + g];
    hpb[c * 65536 + g] = h;
    h = P * h + hp;
  }
}

// ---------------- combine 4 directions ----------------
__global__ __launch_bounds__(256) void combine_kernel(const float* __restrict__ ys, float* __restrict__ yc) {
  int m = blockIdx.x;
  int b = m >> 10, l = m & 1023;
  int h = l >> 5, w = l & 31;
  int lw = w * 32 + h;
  long b4 = (long)b * 4;
  int tid = threadIdx.x;
  #pragma unroll
  for (int i = 0; i < 2; ++i) {
    int d = tid + i * 256;
    float v = ys[((b4 + 0) * 1024 + l) * 512 + d]
            + ys[((b4 + 2) * 1024 + (1023 - l)) * 512 + d]
            + ys[((b4 + 1) * 1024 + lw) * 512 + d]
            + ys[((b4 + 3) * 1024 + (1023 - lw)) * 512 + d];
    yc[(long)m * 512 + d] = v;
  }
}

// ---------------- LN over 512 + silu(z) gate (bf16 output) ----------------
__global__ __launch_bounds__(256) void ln2gate_kernel(const float* __restrict__ y,
    const float* __restrict__ xz, ushort* __restrict__ out,
    const float* __restrict__ g, const float* __restrict__ b) {
  __shared__ float sm[8];
  int m = blockIdx.x, tid = threadIdx.x;
  float v0 = y[(long)m * 512 + tid];
  float v1 = y[(long)m * 512 + tid + 256];
  float s = blk_sum(v0 + v1, sm);
  float s2 = blk_sum(v0 * v0 + v1 * v1, sm);
  float mu = s * (1.f / 512.f);
  float var = s2 * (1.f / 512.f) - mu * mu;
  float rs = rsqrtf(var + 1e-5f);
  #pragma unroll
  for (int i = 0; i < 2; ++i) {
    int c = tid + i * 256;
    float v = i ? v1 : v0;
    float yn = (v - mu) * rs * g[c] + b[c];
    float zz = xz[(long)m * 1024 + 512 + c];
    out[(long)m * 512 + c] = bf16_rn(yn * (zz / (1.f + __expf(-zz))));
  }
}

// ---------------- pooled head ----------------
__global__ __launch_bounds__(256) void head_partial(const float* __restrict__ t,
    const float* __restrict__ hw, float* __restrict__ part) {
  __shared__ float sm[8];
  int j = blockIdx.x, b = blockIdx.y;
  int c = threadIdx.x;
  float s = 0.f;
  for (int l = j * 64; l < j * 64 + 64; ++l) s += t[((long)b * 1024 + l) * 256 + c];
  s *= hw[c];
  float tot = blk_sum(s, sm);
  if (c == 0) part[b * 16 + j] = tot;
}

__global__ void head_final(const float* __restrict__ part, const float* __restrict__ hb, float* __restrict__ out) {
  int tid = threadIdx.x;
  float v = (tid < 32) ? part[tid] : 0.f;
  #pragma unroll
  for (int o = 1; o < 16; o <<= 1) v += __shfl_xor(v, o);
  if (tid < 32 && (tid & 15) == 0) out[tid >> 4] = v * (1.f / 1024.f) + hb[0];
}

extern "C" void kernel_launch(void* const* d_in, const int* in_sizes, int n_in,
                              void* d_out, int out_size, void* d_ws, size_t ws_size,
                              hipStream_t stream) {
  const float* x       = (const float*)d_in[0];
  const float* patch_w = (const float*)d_in[1];
  const float* patch_b = (const float*)d_in[2];
  const float* ln_g    = (const float*)d_in[3];
  const float* ln_b    = (const float*)d_in[4];
  const float* in_w    = (const float*)d_in[5];
  const float* conv_w  = (const float*)d_in[6];
  const float* conv_b  = (const float*)d_in[7];
  const float* xproj_w = (const float*)d_in[8];
  const float* dt_w    = (const float*)d_in[9];
  const float* dt_b    = (const float*)d_in[10];
  const float* A_log   = (const float*)d_in[11];
  const float* Ds      = (const float*)d_in[12];
  const float* on_g    = (const float*)d_in[13];
  const float* on_b    = (const float*)d_in[14];
  const float* out_w   = (const float*)d_in[15];
  const float* head_w  = (const float*)d_in[16];
  const float* head_b  = (const float*)d_in[17];

  float* ws = (float*)d_ws;
  float* t_buf   = ws;                    // 2048*256
  float* u_buf   = t_buf + 524288;        // 2048*256   (u_bf16 overlay)
  float* xz_buf  = u_buf + 524288;        // 2048*1024  (pw splits overlay; xz)
  float* xc_buf  = xz_buf + 2097152;      // 2*512*1024 (xc; P_scan; y_comb)
  float* xca_buf = xc_buf + 1048576;      // 2*512*1024 (xca; hp/h_in; y_bf16)
  float* xsT_buf = xca_buf + 1048576;     // 8*1024*512 (A_p overlay; xs/ys)
  float* xdbl_buf= xsT_buf + 4194304;     // 8*1024*48
  float* dts_buf = xdbl_buf + 393216;     // 8*1024*512 (P_patch overlay; dts; P_out)
  float* part_buf= dts_buf + 4194304;     // 32
  float* tail    = part_buf + 32;
  // scan scratch (dead-region reuse): P/hp each 16c*65536 = 1048576 f
  float* P_buf   = xc_buf;
  float* hp_buf  = xca_buf;
  // bf16 overlays + split-K partials:
  ushort* A_p    = (ushort*)xsT_buf;                // 2048*4096 us = 16 MB
  ushort* pw_hi  = (ushort*)xz_buf;                 // 1048576 us
  ushort* pw_lo  = (ushort*)(xz_buf + 524288);      // 1048576 us
  float*  P_patch= dts_buf;                         // 8*524288 f = 16 MB
  float*  P_out  = dts_buf;                         // 4*524288 f
  ushort* u_bf   = (ushort*)u_buf;                  // 2048*256 us
  ushort* y_bf   = (ushort*)xca_buf;                // 2048*512 us
  ushort* iw_hi  = (ushort*)tail;
  ushort* iw_lo  = (ushort*)(tail + 131072);
  ushort* ow_hi  = (ushort*)(tail + 262144);
  ushort* ow_lo  = (ushort*)(tail + 327680);

  // 0. weight hi/lo splits + im2col A
  split_bf16<<<4096, 256, 0, stream>>>(patch_w, pw_hi, pw_lo, 1048576);
  split_bf16<<<1024, 256, 0, stream>>>(in_w, iw_hi, iw_lo, 262144);
  split_bf16<<<512, 256, 0, stream>>>(out_w, ow_hi, ow_lo, 131072);
  im2col_bf16<<<dim3(32, 32, 2), 256, 0, stream>>>(x, A_p);
  // 1. patch embed MFMA, split-K=8: t (2048,256)
  mfma_bf<<<dim3(4, 16, 8), 512, 0, stream>>>(A_p, pw_hi, pw_lo, P_patch,
      2048, 256, 4096, 512, 0);
  reduce_split<<<512, 256, 0, stream>>>(P_patch, t_buf, patch_b, 524288, 256, 8, 0);
  // 2. LN1 -> u (bf16)
  ln1_kernel<<<2048, 256, 0, stream>>>(t_buf, u_bf, ln_g, ln_b);
  // 3. xz = u @ in_w^T  (2048,1024), direct
  mfma_bf<<<dim3(16, 16, 1), 512, 0, stream>>>(u_bf, iw_hi, iw_lo, xz_buf,
      2048, 1024, 256, 256, 1);
  // 4. repack xc -> (B,512,32,32)
  repack_xc<<<dim3(32, 16, 2), 256, 0, stream>>>(xz_buf, xc_buf);
  // 5. depthwise conv + silu
  dwconv_kernel<<<dim3(512, 2), 256, 0, stream>>>(xc_buf, conv_w, conv_b, xca_buf);
  // 6. build xsT (B,K,L,512)  (clobbers A_p - dead)
  build_xsT<<<dim3(32, 16, 8), 256, 0, stream>>>(xca_buf, xsT_buf);
  // 7. x_dbl[z] (1024,48) = xsT[z] @ xproj_w[k]^T
  gemm_nt<0><<<dim3(2, 16, 8), 256, 0, stream>>>(xsT_buf, xproj_w, nullptr, xdbl_buf,
      1024, 48, 512, 512, 512, 48, 524288, 24576, 0, 49152, 4, 0);
  // 8. dts[z] (1024,512) = softplus(...)  (clobbers P_patch - dead)
  gemm_nt<1><<<dim3(16, 16, 8), 256, 0, stream>>>(xdbl_buf, dt_w, dt_b, dts_buf,
      1024, 512, 16, 48, 16, 512, 49152, 8192, 512, 524288, 4, 0);
  // 9. chunk-parallel selective scan (NC=16, states in registers)
  scan_chunk3<false><<<dim3(8, 16, 8), 128, 0, stream>>>(dts_buf, xsT_buf, xdbl_buf,
      A_log, Ds, P_buf, hp_buf);
  scan_prefix<<<256, 256, 0, stream>>>(P_buf, hp_buf);
  scan_chunk3<true><<<dim3(8, 16, 8), 128, 0, stream>>>(dts_buf, xsT_buf, xdbl_buf,
      A_log, Ds, nullptr, hp_buf);
  // 10. combine 4 directions -> y_comb (reuse xc_buf)
  combine_kernel<<<2048, 256, 0, stream>>>(xsT_buf, xc_buf);
  // 11. LN2 * silu(z) -> y_bf16 (reuse xca_buf)
  ln2gate_kernel<<<2048, 256, 0, stream>>>(xc_buf, xz_buf, y_bf, on_g, on_b);
  // 12. t += y @ out_w^T (MFMA split-K=4; P_out over dead dts)
  mfma_bf<<<dim3(4, 16, 4), 512, 0, stream>>>(y_bf, ow_hi, ow_lo, P_out,
      2048, 256, 512, 128, 0);
  reduce_split<<<512, 256, 0, stream>>>(P_out, t_buf, nullptr, 524288, 256, 4, 1);
  // 13. pooled head
  head_partial<<<dim3(16, 2), 256, 0, stream>>>(t_buf, head_w, part_buf);
  head_final<<<1, 64, 0, stream>>>(part_buf, head_b, (float*)d_out);
}

// Round 7
// 161.571 us; speedup vs baseline: 5.0049x; 1.1755x over previous
//
#include <hip/hip_runtime.h>
#include <math.h>

// VMamba discriminator forward. GEMMs: bf16 MFMA, weights hi/lo split
// (systematic error -> 2^-18), activations bf16-hi, fp32 accum.
// Scan: chunk-parallel NC=32, states in registers, prefetched staging.
// B=2, C=256, IMG=128, P=4 -> H=W=32, L=1024, D_INNER=512, N=16, R=16, K=4

typedef __attribute__((ext_vector_type(4))) float f32x4;
typedef __attribute__((ext_vector_type(8))) short bf16x8;

__device__ __forceinline__ ushort bf16_rn(float f) {
  uint u = __float_as_uint(f);
  return (ushort)((u + 0x7fffu + ((u >> 16) & 1u)) >> 16);
}

// ---------------- all weight hi/lo splits in one launch ----------------
__global__ __launch_bounds__(256) void split_all(
    const float* __restrict__ pw, const float* __restrict__ iw,
    const float* __restrict__ ow, const float* __restrict__ xw,
    ushort* __restrict__ pwh, ushort* __restrict__ pwl,
    ushort* __restrict__ iwh, ushort* __restrict__ iwl,
    ushort* __restrict__ owh, ushort* __restrict__ owl,
    ushort* __restrict__ xwh, ushort* __restrict__ xwl) {
  int i = blockIdx.x * 256 + threadIdx.x;
  const float* src; ushort* hi; ushort* lo; int off;
  if (i < 1048576)      { src = pw; hi = pwh; lo = pwl; off = i; }
  else if (i < 1310720) { src = iw; hi = iwh; lo = iwl; off = i - 1048576; }
  else if (i < 1441792) { src = ow; hi = owh; lo = owl; off = i - 1310720; }
  else if (i < 1540096) { src = xw; hi = xwh; lo = xwl; off = i - 1441792; }
  else return;
  float f = src[off];
  ushort h = bf16_rn(f);
  hi[off] = h;
  lo[off] = bf16_rn(f - __uint_as_float(((uint)h) << 16));
}

// ---------------- im2col + f32->bf16: x (B,256,128,128) -> A_p (2048,4096) ----
__global__ __launch_bounds__(256) void im2col_bf16(const float* __restrict__ x,
    ushort* __restrict__ Ap) {
  __shared__ __align__(16) ushort tile[32][136];
  int c0 = blockIdx.x * 8, hh = blockIdx.y, b = blockIdx.z;
  int tid = threadIdx.x;
  int ci = tid >> 5, ph = (tid >> 3) & 3, w4 = tid & 7;
  const float* src = x + (((long)(b * 256 + c0 + ci) * 128 + 4 * hh + ph) * 128 + 16 * w4);
  #pragma unroll
  for (int j = 0; j < 4; ++j) {
    float4 v = *(const float4*)(src + 4 * j);
    uint2 pk;
    pk.x = (uint)bf16_rn(v.x) | ((uint)bf16_rn(v.y) << 16);
    pk.y = (uint)bf16_rn(v.z) | ((uint)bf16_rn(v.w) << 16);
    *(uint2*)&tile[w4 * 4 + j][ci * 16 + ph * 4] = pk;
  }
  __syncthreads();
  int w = tid >> 3;
  long rowbase = ((long)(b * 1024 + hh * 32 + w)) * 4096 + c0 * 16;
  #pragma unroll
  for (int i = 0; i < 2; ++i) {
    int gr = (tid & 7) + 8 * i;
    *(uint4*)&Ap[rowbase + gr * 8] = *(const uint4*)&tile[w][gr * 8];
  }
}

// ---------------- MFMA NT GEMM (bf16 A, hi/lo bf16 B, fp32 out) --------------
__global__ __launch_bounds__(512) void mfma_bf(
    const ushort* __restrict__ A, const ushort* __restrict__ Bhi,
    const ushort* __restrict__ Blo, float* __restrict__ Cout,
    int M, int N, int K, int kchunk, int direct)
{
  __shared__ __align__(16) ushort Ah[128 * 64];
  __shared__ __align__(16) ushort Bh[64 * 64];
  __shared__ __align__(16) ushort Bl[64 * 64];
  int tid = threadIdx.x;
  int n0 = blockIdx.x * 64;
  int m0 = blockIdx.y * 128;
  int k0 = blockIdx.z * kchunk;
  int wid = tid >> 6, lane = tid & 63;
  int wm = wid >> 1, wn = wid & 1;
  int lrow = lane & 15, g = lane >> 4;
  f32x4 acc[2][2] = {};
  int nkt = kchunk >> 6;
  for (int kt = 0; kt < nkt; ++kt) {
    int kb = k0 + (kt << 6);
    {
      int gi = tid & 7;
      #pragma unroll
      for (int i = 0; i < 2; ++i) {
        int row = (tid >> 3) + (i << 6);
        uint4 v = *(const uint4*)&A[(long)(m0 + row) * K + kb + gi * 8];
        *(uint4*)&Ah[row * 64 + ((gi ^ (row & 7)) << 3)] = v;
      }
      int row = tid >> 3;
      long off = (long)(n0 + row) * K + kb + gi * 8;
      int la = row * 64 + ((gi ^ (row & 7)) << 3);
      *(uint4*)&Bh[la] = *(const uint4*)&Bhi[off];
      *(uint4*)&Bl[la] = *(const uint4*)&Blo[off];
    }
    __syncthreads();
    #pragma unroll
    for (int kk = 0; kk < 2; ++kk) {
      bf16x8 af[2], bhf[2], blf[2];
      #pragma unroll
      for (int mi = 0; mi < 2; ++mi) {
        int row = wm * 32 + mi * 16 + lrow;
        af[mi] = *(const bf16x8*)&Ah[row * 64 + ((((kk << 2) + g) ^ (row & 7)) << 3)];
      }
      #pragma unroll
      for (int ni = 0; ni < 2; ++ni) {
        int row = wn * 32 + ni * 16 + lrow;
        int col = (((kk << 2) + g) ^ (row & 7)) << 3;
        bhf[ni] = *(const bf16x8*)&Bh[row * 64 + col];
        blf[ni] = *(const bf16x8*)&Bl[row * 64 + col];
      }
      #pragma unroll
      for (int mi = 0; mi < 2; ++mi)
        #pragma unroll
        for (int ni = 0; ni < 2; ++ni) {
          acc[mi][ni] = __builtin_amdgcn_mfma_f32_16x16x32_bf16(af[mi], bhf[ni], acc[mi][ni], 0, 0, 0);
          acc[mi][ni] = __builtin_amdgcn_mfma_f32_16x16x32_bf16(af[mi], blf[ni], acc[mi][ni], 0, 0, 0);
        }
    }
    __syncthreads();
  }
  long zoff = direct ? 0 : (long)blockIdx.z * M * N;
  int r4 = lane >> 4;
  #pragma unroll
  for (int mi = 0; mi < 2; ++mi)
    #pragma unroll
    for (int ni = 0; ni < 2; ++ni) {
      int n = n0 + wn * 32 + ni * 16 + lrow;
      int mb = m0 + wm * 32 + mi * 16 + r4 * 4;
      #pragma unroll
      for (int r = 0; r < 4; ++r)
        Cout[zoff + (long)(mb + r) * N + n] = acc[mi][ni][r];
    }
}

// ---------------- MFMA x_dbl: xdbl[z] (1024,48) = xsT_bf[z] @ xproj[k]^T -----
// Tile 64M x 48N, BK=64, 256 thr (4 waves, each 16m x 48n via 3 n-frags).
__global__ __launch_bounds__(256) void mfma_x(
    const ushort* __restrict__ A, const ushort* __restrict__ Bhi,
    const ushort* __restrict__ Blo, float* __restrict__ xdbl)
{
  __shared__ __align__(16) ushort Ah[64 * 64];
  __shared__ __align__(16) ushort Bh[48 * 64];
  __shared__ __align__(16) ushort Bl[48 * 64];
  int tid = threadIdx.x;
  int m0 = blockIdx.x * 64;
  int z = blockIdx.y, k = z & 3;
  const ushort* Az = A + (long)z * 524288;
  const ushort* Bhz = Bhi + (long)k * 24576;
  const ushort* Blz = Blo + (long)k * 24576;
  int lane = tid & 63, wv = tid >> 6;
  int lrow = lane & 15, g = lane >> 4;
  f32x4 acc[3] = {};
  for (int kt = 0; kt < 8; ++kt) {
    int kb = kt << 6;
    #pragma unroll
    for (int i = 0; i < 2; ++i) {
      int idx = i * 256 + tid;
      int row = idx >> 3, gi = idx & 7;
      uint4 v = *(const uint4*)&Az[(long)(m0 + row) * 512 + kb + gi * 8];
      *(uint4*)&Ah[row * 64 + ((gi ^ (row & 7)) << 3)] = v;
      if (idx < 384) {
        long off = (long)row * 512 + kb + gi * 8;
        int la = row * 64 + ((gi ^ (row & 7)) << 3);
        *(uint4*)&Bh[la] = *(const uint4*)&Bhz[off];
        *(uint4*)&Bl[la] = *(const uint4*)&Blz[off];
      }
    }
    __syncthreads();
    #pragma unroll
    for (int kk = 0; kk < 2; ++kk) {
      int arow = wv * 16 + lrow;
      bf16x8 af = *(const bf16x8*)&Ah[arow * 64 + ((((kk << 2) + g) ^ (arow & 7)) << 3)];
      #pragma unroll
      for (int ni = 0; ni < 3; ++ni) {
        int brow = ni * 16 + lrow;
        int col = (((kk << 2) + g) ^ (brow & 7)) << 3;
        bf16x8 bh = *(const bf16x8*)&Bh[brow * 64 + col];
        bf16x8 bl = *(const bf16x8*)&Bl[brow * 64 + col];
        acc[ni] = __builtin_amdgcn_mfma_f32_16x16x32_bf16(af, bh, acc[ni], 0, 0, 0);
        acc[ni] = __builtin_amdgcn_mfma_f32_16x16x32_bf16(af, bl, acc[ni], 0, 0, 0);
      }
    }
    __syncthreads();
  }
  float* Cz = xdbl + (long)z * 49152;
  int r4 = lane >> 4;
  #pragma unroll
  for (int ni = 0; ni < 3; ++ni) {
    int n = ni * 16 + lrow;
    int mb = m0 + wv * 16 + r4 * 4;
    #pragma unroll
    for (int r = 0; r < 4; ++r)
      Cz[(long)(mb + r) * 48 + n] = acc[ni][r];
  }
}

// ---------------- reduce split-K partials: C (=/+=) sum_s P + bias ----------
__global__ __launch_bounds__(256) void reduce_split(const float* __restrict__ P,
    float* __restrict__ C, const float* __restrict__ bias,
    int MN, int N, int S, int accumulate) {
  int i = blockIdx.x * 256 + threadIdx.x;
  if (i * 4 >= MN) return;
  float4 v = make_float4(0.f, 0.f, 0.f, 0.f);
  for (int s = 0; s < S; ++s) {
    float4 p = *(const float4*)(P + (long)s * MN + i * 4);
    v.x += p.x; v.y += p.y; v.z += p.z; v.w += p.w;
  }
  if (bias) {
    float4 bv = *(const float4*)(bias + ((i * 4) & (N - 1)));
    v.x += bv.x; v.y += bv.y; v.z += bv.z; v.w += bv.w;
  }
  if (accumulate) {
    float4 o = *(const float4*)(C + (long)i * 4);
    v.x += o.x; v.y += o.y; v.z += o.z; v.w += o.w;
  }
  *(float4*)(C + (long)i * 4) = v;
}

// ---------------- block reduce helper (256 threads) ----------------
__device__ __forceinline__ float blk_sum(float v, float* sm) {
  #pragma unroll
  for (int o = 32; o > 0; o >>= 1) v += __shfl_down(v, o);
  int wid = threadIdx.x >> 6, lane = threadIdx.x & 63;
  __syncthreads();
  if (lane == 0) sm[wid] = v;
  __syncthreads();
  int nw = blockDim.x >> 6;
  float r = 0.f;
  for (int i = 0; i < nw; ++i) r += sm[i];
  return r;
}

// ------- fused: patch split-K reduce + bias -> t, then LN1 -> u (bf16) -------
__global__ __launch_bounds__(256) void reduce_ln1(const float* __restrict__ P,
    float* __restrict__ t, const float* __restrict__ bias,
    const float* __restrict__ g, const float* __restrict__ b,
    ushort* __restrict__ u) {
  __shared__ float sm[8];
  int m = blockIdx.x, c = threadIdx.x;
  float v = bias[c];
  #pragma unroll
  for (int s = 0; s < 8; ++s) v += P[(long)s * 524288 + m * 256 + c];
  t[(long)m * 256 + c] = v;
  float s1 = blk_sum(v, sm);
  float s2 = blk_sum(v * v, sm);
  float mu = s1 * (1.f / 256.f);
  float var = s2 * (1.f / 256.f) - mu * mu;
  float rs = rsqrtf(var + 1e-5f);
  u[(long)m * 256 + c] = bf16_rn((v - mu) * rs * g[c] + b[c]);
}

// ---------------- generic NT GEMM (fp32 VALU) for the dts GEMM ---------------
template<int ACT>
__global__ __launch_bounds__(256) void gemm_nt(
    const float* __restrict__ Ag, const float* __restrict__ Bg,
    const float* __restrict__ biasg, float* Cg,
    int M, int N, int Kd, int lda, int ldb, int ldc,
    long sA, long sB, long sBias, long sC, int bmod, int accumulate)
{
  __shared__ __align__(16) float As[64 * 36];
  __shared__ float Bs[32 * 33];
  int z = blockIdx.z;
  int zb = (bmod > 1) ? (z % bmod) : 0;
  const float* A = Ag + (long)z * sA;
  const float* Bm = Bg + (long)zb * sB;
  const float* bias = biasg ? (biasg + (long)zb * sBias) : nullptr;
  float* C = Cg + (long)z * sC;
  int tid = threadIdx.x;
  int n0 = blockIdx.x * 32;
  int m0 = blockIdx.y * 64;
  int tn = tid & 7, tm = tid >> 3;
  float acc[2][4] = {};
  int nk = (Kd + 31) >> 5;
  for (int kt = 0; kt < nk; ++kt) {
    int k0 = kt << 5;
    #pragma unroll
    for (int i = 0; i < 2; ++i) {
      int idx = i * 256 + tid;
      int row = idx >> 3, c4 = idx & 7;
      int m = m0 + row, k = k0 + c4 * 4;
      float4 v = make_float4(0.f, 0.f, 0.f, 0.f);
      if (m < M && k < Kd) v = *(const float4*)(A + (long)m * lda + k);
      *(float4*)&As[row * 36 + c4 * 4] = v;
    }
    {
      int row = tid >> 3, c4 = tid & 7;
      int n = n0 + row, k = k0 + c4 * 4;
      float4 v = make_float4(0.f, 0.f, 0.f, 0.f);
      if (n < N && k < Kd) v = *(const float4*)(Bm + (long)n * ldb + k);
      Bs[row * 33 + c4 * 4 + 0] = v.x;
      Bs[row * 33 + c4 * 4 + 1] = v.y;
      Bs[row * 33 + c4 * 4 + 2] = v.z;
      Bs[row * 33 + c4 * 4 + 3] = v.w;
    }
    __syncthreads();
    #pragma unroll
    for (int kk = 0; kk < 32; ++kk) {
      float a0 = As[(tm * 2 + 0) * 36 + kk];
      float a1 = As[(tm * 2 + 1) * 36 + kk];
      #pragma unroll
      for (int j = 0; j < 4; ++j) {
        float bv = Bs[(tn * 4 + j) * 33 + kk];
        acc[0][j] += a0 * bv;
        acc[1][j] += a1 * bv;
      }
    }
    __syncthreads();
  }
  bool fullN = (n0 + 32 <= N);
  #pragma unroll
  for (int i = 0; i < 2; ++i) {
    int m = m0 + tm * 2 + i;
    if (m >= M) continue;
    float r[4];
    #pragma unroll
    for (int j = 0; j < 4; ++j) {
      int n = n0 + tn * 4 + j;
      float v = acc[i][j];
      if (bias && n < N) v += bias[n];
      if (ACT == 1) v = (v > 20.f) ? v : __logf(1.f + __expf(v));  // softplus
      r[j] = v;
    }
    long base = (long)m * ldc + n0 + tn * 4;
    if (fullN) {
      float4 o = make_float4(r[0], r[1], r[2], r[3]);
      if (accumulate) {
        float4 old = *(float4*)(C + base);
        o.x += old.x; o.y += old.y; o.z += old.z; o.w += old.w;
      }
      *(float4*)(C + base) = o;
    } else {
      #pragma unroll
      for (int j = 0; j < 4; ++j) {
        int n = n0 + tn * 4 + j;
        if (n < N) {
          float v = r[j];
          if (accumulate) v += C[(long)m * ldc + n];
          C[(long)m * ldc + n] = v;
        }
      }
    }
  }
}

// ---------------- transpose xz[:, :512] -> xc (B,512,32,32) ----------------
__global__ __launch_bounds__(256) void repack_xc(const float* __restrict__ xz, float* __restrict__ xc) {
  __shared__ float tile[32][33];
  int b = blockIdx.z, l0 = blockIdx.x * 32, d0 = blockIdx.y * 32;
  int tid = threadIdx.x;
  int a = tid >> 5, q = tid & 31;
  #pragma unroll
  for (int i = 0; i < 4; ++i) {
    int li = a + i * 8;
    tile[li][q] = xz[((long)(b * 1024 + l0 + li)) * 1024 + d0 + q];
  }
  __syncthreads();
  #pragma unroll
  for (int i = 0; i < 4; ++i) {
    int dj = a + i * 8;
    xc[((long)(b * 512 + d0 + dj)) * 1024 + l0 + q] = tile[q][dj];
  }
}

// ---------------- depthwise 3x3 + bias + silu ----------------
__global__ __launch_bounds__(256) void dwconv_kernel(const float* __restrict__ xc,
    const float* __restrict__ cw, const float* __restrict__ cb, float* __restrict__ out) {
  __shared__ float plane[32][33];
  int d = blockIdx.x, b = blockIdx.y;
  long base = ((long)b * 512 + d) * 1024;
  int tid = threadIdx.x;
  float4 v = *(const float4*)(xc + base + tid * 4);
  int h0 = (tid * 4) >> 5, w0 = (tid * 4) & 31;
  plane[h0][w0 + 0] = v.x; plane[h0][w0 + 1] = v.y;
  plane[h0][w0 + 2] = v.z; plane[h0][w0 + 3] = v.w;
  float w9[9];
  #pragma unroll
  for (int i = 0; i < 9; ++i) w9[i] = cw[d * 9 + i];
  float bias = cb[d];
  __syncthreads();
  float4 o;
  float* op = &o.x;
  #pragma unroll
  for (int j = 0; j < 4; ++j) {
    int p = tid * 4 + j, h = p >> 5, w = p & 31;
    float acc = 0.f;
    #pragma unroll
    for (int dh = -1; dh <= 1; ++dh) {
      int hy = h + dh;
      if (hy < 0 || hy > 31) continue;
      #pragma unroll
      for (int dw = -1; dw <= 1; ++dw) {
        int wx = w + dw;
        if (wx < 0 || wx > 31) continue;
        acc += w9[(dh + 1) * 3 + (dw + 1)] * plane[hy][wx];
      }
    }
    acc += bias;
    op[j] = acc / (1.f + __expf(-acc));  // silu
  }
  *(float4*)(out + base + tid * 4) = o;
}

// --------- build xsT (B,K,L,512) f32 + bf16 from xca (B,512,32,32) -----------
__global__ __launch_bounds__(256) void build_xsT(const float* __restrict__ xca,
    float* __restrict__ xsT, ushort* __restrict__ xsTb) {
  __shared__ float tile[32][33];
  int h = blockIdx.x;
  int d0 = blockIdx.y * 32;
  int z = blockIdx.z;          // z = b*4 + k
  int b = z >> 2, k = z & 3;
  int tid = threadIdx.x;
  int a = tid >> 5, q = tid & 31;
  #pragma unroll
  for (int i = 0; i < 4; ++i) {
    int di = a + i * 8;
    tile[di][q] = xca[((long)(b * 512 + d0 + di)) * 1024 + h * 32 + q];
  }
  __syncthreads();
  #pragma unroll
  for (int i = 0; i < 4; ++i) {
    int w = a + i * 8;
    int r;
    if (k == 0) r = h * 32 + w;
    else if (k == 1) r = w * 32 + h;
    else if (k == 2) r = 1023 - (h * 32 + w);
    else r = 1023 - (w * 32 + h);
    long idx = ((long)z * 1024 + r) * 512 + d0 + q;
    float f = tile[q][w];
    xsT[idx] = f;
    xsTb[idx] = bf16_rn(f);
  }
}

// ---------------- chunk-parallel selective scan, NC=32, prefetch ------------
// LC=32, 2 l-tiles of 16. Block 128 thr = 64 d x 2 n-halves, h[8] in VGPRs.
// Grid (8 d-tiles, 32 chunks, 8 z).
template<bool FINAL>
__global__ __launch_bounds__(128) void scan_chunk4(
    const float* __restrict__ dts, float* xsT_ys, const float* __restrict__ xdbl,
    const float* __restrict__ A_log, const float* __restrict__ Ds,
    float* __restrict__ Pb, float* __restrict__ hpb)
{
  __shared__ float sdt[16][64], sxv[16][64], sy[16][64];
  __shared__ float sBC[32][32];     // [l][n]: n<16 -> B, n>=16 -> C
  int tid = threadIdx.x;
  int dl = tid >> 1, ng = tid & 1;
  int d0 = blockIdx.x * 64;
  int d = d0 + dl;
  int c = blockIdx.y;              // 0..31
  int z = blockIdx.z;
  int k = z & 3;
  long baseD = (long)z * 524288;
  int l0 = c * 32;
  float a[8], h[8];
  #pragma unroll
  for (int j = 0; j < 8; ++j) {
    a[j] = -__expf(A_log[((long)k * 512 + d) * 16 + ng * 8 + j]);
    h[j] = 0.f;
  }
  int gbase = c * 65536 + z * 8192 + d * 16 + ng * 8;
  float Dv = 0.f;
  if (FINAL) {
    #pragma unroll
    for (int j = 0; j < 8; ++j) h[j] = hpb[gbase + j];   // h_in (prefix in-place)
    Dv = Ds[k * 512 + d];
  }
  // stage B/C for whole chunk: 32 l x 8 float4 = 256 / 128 thr = 2 each
  #pragma unroll
  for (int i = 0; i < 2; ++i) {
    int idx = i * 128 + tid;
    int l = idx >> 3, q = idx & 7;
    *(float4*)&sBC[l][q * 4] =
        *(const float4*)(xdbl + (long)z * 49152 + (long)(l0 + l) * 48 + 16 + q * 4);
  }
  int sli = tid >> 4;              // 0..7
  int sdj = (tid & 15) * 4;
  float4 rdt[2], rxv[2];
  #pragma unroll
  for (int i = 0; i < 2; ++i) {    // prefetch tile 0
    long off = baseD + (long)(l0 + sli + i * 8) * 512 + d0 + sdj;
    rdt[i] = *(const float4*)(dts + off);
    rxv[i] = *(const float4*)(xsT_ys + off);
  }
  float dtsum = 0.f;
  for (int t = 0; t < 2; ++t) {
    #pragma unroll
    for (int i = 0; i < 2; ++i) {
      *(float4*)&sdt[sli + i * 8][sdj] = rdt[i];
      *(float4*)&sxv[sli + i * 8][sdj] = rxv[i];
    }
    __syncthreads();
    if (t == 0) {
      #pragma unroll
      for (int i = 0; i < 2; ++i) {  // prefetch tile 1 (hides under compute)
        long off = baseD + (long)(l0 + 16 + sli + i * 8) * 512 + d0 + sdj;
        rdt[i] = *(const float4*)(dts + off);
        rxv[i] = *(const float4*)(xsT_ys + off);
      }
    }
    #pragma unroll
    for (int li = 0; li < 16; ++li) {
      float dt = sdt[li][dl];
      float xv = sxv[li][dl];
      float w = dt * xv;
      int lr = t * 16 + li;
      float4 B0 = *(const float4*)&sBC[lr][ng * 8];
      float4 B1 = *(const float4*)&sBC[lr][ng * 8 + 4];
      if (!FINAL) {
        dtsum += dt;
        h[0] = __expf(dt * a[0]) * h[0] + w * B0.x;
        h[1] = __expf(dt * a[1]) * h[1] + w * B0.y;
        h[2] = __expf(dt * a[2]) * h[2] + w * B0.z;
        h[3] = __expf(dt * a[3]) * h[3] + w * B0.w;
        h[4] = __expf(dt * a[4]) * h[4] + w * B1.x;
        h[5] = __expf(dt * a[5]) * h[5] + w * B1.y;
        h[6] = __expf(dt * a[6]) * h[6] + w * B1.z;
        h[7] = __expf(dt * a[7]) * h[7] + w * B1.w;
      } else {
        float4 C0 = *(const float4*)&sBC[lr][16 + ng * 8];
        float4 C1 = *(const float4*)&sBC[lr][16 + ng * 8 + 4];
        float p;
        h[0] = __expf(dt * a[0]) * h[0] + w * B0.x; p  = h[0] * C0.x;
        h[1] = __expf(dt * a[1]) * h[1] + w * B0.y; p += h[1] * C0.y;
        h[2] = __expf(dt * a[2]) * h[2] + w * B0.z; p += h[2] * C0.z;
        h[3] = __expf(dt * a[3]) * h[3] + w * B0.w; p += h[3] * C0.w;
        h[4] = __expf(dt * a[4]) * h[4] + w * B1.x; p += h[4] * C1.x;
        h[5] = __expf(dt * a[5]) * h[5] + w * B1.y; p += h[5] * C1.y;
        h[6] = __expf(dt * a[6]) * h[6] + w * B1.z; p += h[6] * C1.z;
        h[7] = __expf(dt * a[7]) * h[7] + w * B1.w; p += h[7] * C1.w;
        p += __shfl_xor(p, 1);
        if (ng == 0) sy[li][dl] = p + Dv * xv;
      }
    }
    __syncthreads();
    if (FINAL) {
      #pragma unroll
      for (int i = 0; i < 2; ++i) {
        long off = baseD + (long)(l0 + t * 16 + sli + i * 8) * 512 + d0 + sdj;
        *(float4*)(xsT_ys + off) = *(float4*)&sy[sli + i * 8][sdj];
      }
    }
  }
  if (!FINAL) {
    float4 pv;
    #pragma unroll
    for (int i = 0; i < 2; ++i) {
      pv.x = __expf(dtsum * a[i * 4 + 0]);
      pv.y = __expf(dtsum * a[i * 4 + 1]);
      pv.z = __expf(dtsum * a[i * 4 + 2]);
      pv.w = __expf(dtsum * a[i * 4 + 3]);
      *(float4*)(Pb + gbase + i * 4) = pv;
      *(float4*)(hpb + gbase + i * 4) = make_float4(h[i*4+0], h[i*4+1], h[i*4+2], h[i*4+3]);
    }
  }
}

// prefix across the 32 chunks per (z,d,n); writes h_in in-place over hp
__global__ __launch_bounds__(256) void scan_prefix(const float* __restrict__ Pb,
    float* __restrict__ hpb) {
  int g = blockIdx.x * 256 + threadIdx.x;
  float h = 0.f;
  #pragma unroll
  for (int c = 0; c < 32; ++c) {
    float P = Pb[c * 65536 + g];
    float hp = hpb[c * 65536 + g];
    hpb[c * 65536 + g] = h;
    h = P * h + hp;
  }
}

// -------- fused: combine 4 directions + LN over 512 + silu(z) gate ----------
__global__ __launch_bounds__(256) void combine_ln2gate(const float* __restrict__ ys,
    const float* __restrict__ xz, ushort* __restrict__ out,
    const float* __restrict__ g, const float* __restrict__ b) {
  __shared__ float sm[8];
  int m = blockIdx.x, tid = threadIdx.x;
  int bb = m >> 10, l = m & 1023;
  int hh = l >> 5, w = l & 31;
  int lw = w * 32 + hh;
  long b4 = (long)bb * 4;
  float v[2];
  #pragma unroll
  for (int i = 0; i < 2; ++i) {
    int d = tid + i * 256;
    v[i] = ys[((b4 + 0) * 1024 + l) * 512 + d]
         + ys[((b4 + 2) * 1024 + (1023 - l)) * 512 + d]
         + ys[((b4 + 1) * 1024 + lw) * 512 + d]
         + ys[((b4 + 3) * 1024 + (1023 - lw)) * 512 + d];
  }
  float s1 = blk_sum(v[0] + v[1], sm);
  float s2 = blk_sum(v[0] * v[0] + v[1] * v[1], sm);
  float mu = s1 * (1.f / 512.f);
  float var = s2 * (1.f / 512.f) - mu * mu;
  float rs = rsqrtf(var + 1e-5f);
  #pragma unroll
  for (int i = 0; i < 2; ++i) {
    int c = tid + i * 256;
    float yn = (v[i] - mu) * rs * g[c] + b[c];
    float zz = xz[(long)m * 1024 + 512 + c];
    out[(long)m * 512 + c] = bf16_rn(yn * (zz / (1.f + __expf(-zz))));
  }
}

// ---------------- pooled head ----------------
__global__ __launch_bounds__(256) void head_partial(const float* __restrict__ t,
    const float* __restrict__ hw, float* __restrict__ part) {
  __shared__ float sm[8];
  int j = blockIdx.x, b = blockIdx.y;
  int c = threadIdx.x;
  float s = 0.f;
  for (int l = j * 64; l < j * 64 + 64; ++l) s += t[((long)b * 1024 + l) * 256 + c];
  s *= hw[c];
  float tot = blk_sum(s, sm);
  if (c == 0) part[b * 16 + j] = tot;
}

__global__ void head_final(const float* __restrict__ part, const float* __restrict__ hb, float* __restrict__ out) {
  int tid = threadIdx.x;
  float v = (tid < 32) ? part[tid] : 0.f;
  #pragma unroll
  for (int o = 1; o < 16; o <<= 1) v += __shfl_xor(v, o);
  if (tid < 32 && (tid & 15) == 0) out[tid >> 4] = v * (1.f / 1024.f) + hb[0];
}

extern "C" void kernel_launch(void* const* d_in, const int* in_sizes, int n_in,
                              void* d_out, int out_size, void* d_ws, size_t ws_size,
                              hipStream_t stream) {
  const float* x       = (const float*)d_in[0];
  const float* patch_w = (const float*)d_in[1];
  const float* patch_b = (const float*)d_in[2];
  const float* ln_g    = (const float*)d_in[3];
  const float* ln_b    = (const float*)d_in[4];
  const float* in_w    = (const float*)d_in[5];
  const float* conv_w  = (const float*)d_in[6];
  const float* conv_b  = (const float*)d_in[7];
  const float* xproj_w = (const float*)d_in[8];
  const float* dt_w    = (const float*)d_in[9];
  const float* dt_b    = (const float*)d_in[10];
  const float* A_log   = (const float*)d_in[11];
  const float* Ds      = (const float*)d_in[12];
  const float* on_g    = (const float*)d_in[13];
  const float* on_b    = (const float*)d_in[14];
  const float* out_w   = (const float*)d_in[15];
  const float* head_w  = (const float*)d_in[16];
  const float* head_b  = (const float*)d_in[17];

  float* ws = (float*)d_ws;
  float* t_buf   = ws;                    // 2048*256
  float* u_buf   = t_buf + 524288;        // 2048*256   (u_bf16 overlay)
  float* xz_buf  = u_buf + 524288;        // 2048*1024  (pw splits overlay; xz)
  float* xc_buf  = xz_buf + 2097152;      // 2*512*1024 (xc)
  float* xca_buf = xc_buf + 1048576;      // 2*512*1024 (xca; y_bf overlay)
  float* xsT_buf = xca_buf + 1048576;     // 8*1024*512 (A_p overlay; xs/ys)
  float* xdbl_buf= xsT_buf + 4194304;     // 8*1024*48
  float* dts_buf = xdbl_buf + 393216;     // 8*1024*512 (P_patch overlay; dts; P_out)
  float* part_buf= dts_buf + 4194304;     // 32
  float* tail    = part_buf + 32;
  // bf16 overlays + split-K partials:
  ushort* A_p    = (ushort*)xsT_buf;                // 2048*4096 us
  ushort* pw_hi  = (ushort*)xz_buf;                 // 1048576 us
  ushort* pw_lo  = (ushort*)(xz_buf + 524288);      // 1048576 us
  float*  P_patch= dts_buf;                         // 8*524288 f
  float*  P_out  = dts_buf;                         // 4*524288 f
  ushort* u_bf   = (ushort*)u_buf;                  // 2048*256 us
  ushort* y_bf   = (ushort*)xca_buf;                // 2048*512 us
  // tail: weight splits, xsT bf16 copy, scan P/hp
  ushort* iw_hi  = (ushort*)tail;                   // 262144 us
  ushort* iw_lo  = (ushort*)(tail + 131072);
  ushort* ow_hi  = (ushort*)(tail + 262144);        // 131072 us
  ushort* ow_lo  = (ushort*)(tail + 327680);
  ushort* xw_hi  = (ushort*)(tail + 393216);        // 98304 us
  ushort* xw_lo  = (ushort*)(tail + 442368);
  ushort* xsT_bf = (ushort*)(tail + 491520);        // 4194304 us (2097152 f)
  float*  P_buf  = tail + 2588672;                  // 32*65536 = 2097152 f
  float*  hp_buf = tail + 4685824;                  // 2097152 f
  // high-water ~ 18.3M floats ~ 73 MB

  // 0. all weight hi/lo splits + im2col A
  split_all<<<6017, 256, 0, stream>>>(patch_w, in_w, out_w, xproj_w,
      pw_hi, pw_lo, iw_hi, iw_lo, ow_hi, ow_lo, xw_hi, xw_lo);
  im2col_bf16<<<dim3(32, 32, 2), 256, 0, stream>>>(x, A_p);
  // 1. patch embed MFMA, split-K=8 -> partials
  mfma_bf<<<dim3(4, 16, 8), 512, 0, stream>>>(A_p, pw_hi, pw_lo, P_patch,
      2048, 256, 4096, 512, 0);
  // 2. fused reduce + bias -> t, LN1 -> u (bf16)
  reduce_ln1<<<2048, 256, 0, stream>>>(P_patch, t_buf, patch_b, ln_g, ln_b, u_bf);
  // 3. xz = u @ in_w^T  (2048,1024), direct
  mfma_bf<<<dim3(16, 16, 1), 512, 0, stream>>>(u_bf, iw_hi, iw_lo, xz_buf,
      2048, 1024, 256, 256, 1);
  // 4. repack xc -> (B,512,32,32)
  repack_xc<<<dim3(32, 16, 2), 256, 0, stream>>>(xz_buf, xc_buf);
  // 5. depthwise conv + silu
  dwconv_kernel<<<dim3(512, 2), 256, 0, stream>>>(xc_buf, conv_w, conv_b, xca_buf);
  // 6. build xsT f32+bf16 (clobbers A_p - dead)
  build_xsT<<<dim3(32, 16, 8), 256, 0, stream>>>(xca_buf, xsT_buf, xsT_bf);
  // 7. x_dbl[z] (1024,48) = xsT_bf[z] @ xproj[k]^T (MFMA)
  mfma_x<<<dim3(16, 8), 256, 0, stream>>>(xsT_bf, xw_hi, xw_lo, xdbl_buf);
  // 8. dts[z] (1024,512) = softplus(x_dbl[:, :16] @ dt_w[k]^T + dt_b[k])
  gemm_nt<1><<<dim3(16, 16, 8), 256, 0, stream>>>(xdbl_buf, dt_w, dt_b, dts_buf,
      1024, 512, 16, 48, 16, 512, 49152, 8192, 512, 524288, 4, 0);
  // 9. chunk-parallel selective scan (NC=32)
  scan_chunk4<false><<<dim3(8, 32, 8), 128, 0, stream>>>(dts_buf, xsT_buf, xdbl_buf,
      A_log, Ds, P_buf, hp_buf);
  scan_prefix<<<256, 256, 0, stream>>>(P_buf, hp_buf);
  scan_chunk4<true><<<dim3(8, 32, 8), 128, 0, stream>>>(dts_buf, xsT_buf, xdbl_buf,
      A_log, Ds, nullptr, hp_buf);
  // 10. fused combine + LN2 + silu gate -> y_bf16
  combine_ln2gate<<<2048, 256, 0, stream>>>(xsT_buf, xz_buf, y_bf, on_g, on_b);
  // 11. t += y @ out_w^T (MFMA split-K=4; P_out over dead dts)
  mfma_bf<<<dim3(4, 16, 4), 512, 0, stream>>>(y_bf, ow_hi, ow_lo, P_out,
      2048, 256, 512, 128, 0);
  reduce_split<<<512, 256, 0, stream>>>(P_out, t_buf, nullptr, 524288, 256, 4, 1);
  // 12. pooled head
  head_partial<<<dim3(16, 2), 256, 0, stream>>>(t_buf, head_w, part_buf);
  head_final<<<1, 64, 0, stream>>>(part_buf, head_b, (float*)d_out);
}

// Round 8
// 148.294 us; speedup vs baseline: 5.4530x; 1.0895x over previous
//
#include <hip/hip_runtime.h>
#include <math.h>

// VMamba discriminator forward. GEMMs: bf16 MFMA, weights hi/lo split
// (systematic error -> 2^-18), activations bf16-hi, fp32 accum.
// Scan: chunk-parallel NC=32, states in regs; xs/ys pipeline in bf16.
// B=2, C=256, IMG=128, P=4 -> H=W=32, L=1024, D_INNER=512, N=16, R=16, K=4

typedef __attribute__((ext_vector_type(4))) float f32x4;
typedef __attribute__((ext_vector_type(8))) short bf16x8;

__device__ __forceinline__ ushort bf16_rn(float f) {
  uint u = __float_as_uint(f);
  return (ushort)((u + 0x7fffu + ((u >> 16) & 1u)) >> 16);
}
__device__ __forceinline__ float bf2f(uint us) { return __uint_as_float(us << 16); }
__device__ __forceinline__ uint packbf(float a, float b) {
  return (uint)bf16_rn(a) | ((uint)bf16_rn(b) << 16);
}

// ---------------- all weight hi/lo splits in one launch ----------------
__global__ __launch_bounds__(256) void split_all(
    const float* __restrict__ pw, const float* __restrict__ iw,
    const float* __restrict__ ow, const float* __restrict__ xw,
    ushort* __restrict__ pwh, ushort* __restrict__ pwl,
    ushort* __restrict__ iwh, ushort* __restrict__ iwl,
    ushort* __restrict__ owh, ushort* __restrict__ owl,
    ushort* __restrict__ xwh, ushort* __restrict__ xwl) {
  int i = blockIdx.x * 256 + threadIdx.x;
  const float* src; ushort* hi; ushort* lo; int off;
  if (i < 1048576)      { src = pw; hi = pwh; lo = pwl; off = i; }
  else if (i < 1310720) { src = iw; hi = iwh; lo = iwl; off = i - 1048576; }
  else if (i < 1441792) { src = ow; hi = owh; lo = owl; off = i - 1310720; }
  else if (i < 1540096) { src = xw; hi = xwh; lo = xwl; off = i - 1441792; }
  else return;
  float f = src[off];
  ushort h = bf16_rn(f);
  hi[off] = h;
  lo[off] = bf16_rn(f - __uint_as_float(((uint)h) << 16));
}

// ---------------- im2col + f32->bf16: x (B,256,128,128) -> A_p (2048,4096) ----
__global__ __launch_bounds__(256) void im2col_bf16(const float* __restrict__ x,
    ushort* __restrict__ Ap) {
  __shared__ __align__(16) ushort tile[32][136];
  int c0 = blockIdx.x * 8, hh = blockIdx.y, b = blockIdx.z;
  int tid = threadIdx.x;
  int ci = tid >> 5, ph = (tid >> 3) & 3, w4 = tid & 7;
  const float* src = x + (((long)(b * 256 + c0 + ci) * 128 + 4 * hh + ph) * 128 + 16 * w4);
  #pragma unroll
  for (int j = 0; j < 4; ++j) {
    float4 v = *(const float4*)(src + 4 * j);
    uint2 pk;
    pk.x = packbf(v.x, v.y);
    pk.y = packbf(v.z, v.w);
    *(uint2*)&tile[w4 * 4 + j][ci * 16 + ph * 4] = pk;
  }
  __syncthreads();
  int w = tid >> 3;
  long rowbase = ((long)(b * 1024 + hh * 32 + w)) * 4096 + c0 * 16;
  #pragma unroll
  for (int i = 0; i < 2; ++i) {
    int gr = (tid & 7) + 8 * i;
    *(uint4*)&Ap[rowbase + gr * 8] = *(const uint4*)&tile[w][gr * 8];
  }
}

// ---------------- MFMA NT GEMM (bf16 A, hi/lo bf16 B, fp32 out) --------------
// mode 0: split-K partials at Cout + z*M*N.  mode 2: in-proj fused epilogue:
// n<512 -> xc (B,512,32,32) float4; n>=512 -> C2 z-buffer [m][512] scalar.
__global__ __launch_bounds__(512) void mfma_bf(
    const ushort* __restrict__ A, const ushort* __restrict__ Bhi,
    const ushort* __restrict__ Blo, float* __restrict__ Cout, float* __restrict__ C2,
    int M, int N, int K, int kchunk, int mode)
{
  __shared__ __align__(16) ushort Ah[128 * 64];
  __shared__ __align__(16) ushort Bh[64 * 64];
  __shared__ __align__(16) ushort Bl[64 * 64];
  int tid = threadIdx.x;
  int n0 = blockIdx.x * 64;
  int m0 = blockIdx.y * 128;
  int k0 = blockIdx.z * kchunk;
  int wid = tid >> 6, lane = tid & 63;
  int wm = wid >> 1, wn = wid & 1;
  int lrow = lane & 15, g = lane >> 4;
  f32x4 acc[2][2] = {};
  int nkt = kchunk >> 6;
  for (int kt = 0; kt < nkt; ++kt) {
    int kb = k0 + (kt << 6);
    {
      int gi = tid & 7;
      #pragma unroll
      for (int i = 0; i < 2; ++i) {
        int row = (tid >> 3) + (i << 6);
        uint4 v = *(const uint4*)&A[(long)(m0 + row) * K + kb + gi * 8];
        *(uint4*)&Ah[row * 64 + ((gi ^ (row & 7)) << 3)] = v;
      }
      int row = tid >> 3;
      long off = (long)(n0 + row) * K + kb + gi * 8;
      int la = row * 64 + ((gi ^ (row & 7)) << 3);
      *(uint4*)&Bh[la] = *(const uint4*)&Bhi[off];
      *(uint4*)&Bl[la] = *(const uint4*)&Blo[off];
    }
    __syncthreads();
    #pragma unroll
    for (int kk = 0; kk < 2; ++kk) {
      bf16x8 af[2], bhf[2], blf[2];
      #pragma unroll
      for (int mi = 0; mi < 2; ++mi) {
        int row = wm * 32 + mi * 16 + lrow;
        af[mi] = *(const bf16x8*)&Ah[row * 64 + ((((kk << 2) + g) ^ (row & 7)) << 3)];
      }
      #pragma unroll
      for (int ni = 0; ni < 2; ++ni) {
        int row = wn * 32 + ni * 16 + lrow;
        int col = (((kk << 2) + g) ^ (row & 7)) << 3;
        bhf[ni] = *(const bf16x8*)&Bh[row * 64 + col];
        blf[ni] = *(const bf16x8*)&Bl[row * 64 + col];
      }
      #pragma unroll
      for (int mi = 0; mi < 2; ++mi)
        #pragma unroll
        for (int ni = 0; ni < 2; ++ni) {
          acc[mi][ni] = __builtin_amdgcn_mfma_f32_16x16x32_bf16(af[mi], bhf[ni], acc[mi][ni], 0, 0, 0);
          acc[mi][ni] = __builtin_amdgcn_mfma_f32_16x16x32_bf16(af[mi], blf[ni], acc[mi][ni], 0, 0, 0);
        }
    }
    __syncthreads();
  }
  int r4 = lane >> 4;
  if (mode == 2) {
    bool xhalf = (n0 < 512);
    #pragma unroll
    for (int mi = 0; mi < 2; ++mi)
      #pragma unroll
      for (int ni = 0; ni < 2; ++ni) {
        int n = n0 + wn * 32 + ni * 16 + lrow;
        int mb = m0 + wm * 32 + mi * 16 + r4 * 4;
        int bb = mb >> 10, l = mb & 1023;
        if (xhalf) {
          float4 o = make_float4(acc[mi][ni][0], acc[mi][ni][1], acc[mi][ni][2], acc[mi][ni][3]);
          *(float4*)(Cout + ((long)(bb * 512 + n)) * 1024 + l) = o;
        } else {
          #pragma unroll
          for (int r = 0; r < 4; ++r)
            C2[(long)(mb + r) * 512 + (n - 512)] = acc[mi][ni][r];
        }
      }
  } else {
    long zoff = (long)blockIdx.z * M * N;
    #pragma unroll
    for (int mi = 0; mi < 2; ++mi)
      #pragma unroll
      for (int ni = 0; ni < 2; ++ni) {
        int n = n0 + wn * 32 + ni * 16 + lrow;
        int mb = m0 + wm * 32 + mi * 16 + r4 * 4;
        #pragma unroll
        for (int r = 0; r < 4; ++r)
          Cout[zoff + (long)(mb + r) * N + n] = acc[mi][ni][r];
      }
  }
}

// ---------------- MFMA x_dbl: xdbl[z] (1024,48) = xsT_bf[z] @ xproj[k]^T -----
__global__ __launch_bounds__(256) void mfma_x(
    const ushort* __restrict__ A, const ushort* __restrict__ Bhi,
    const ushort* __restrict__ Blo, float* __restrict__ xdbl)
{
  __shared__ __align__(16) ushort Ah[64 * 64];
  __shared__ __align__(16) ushort Bh[48 * 64];
  __shared__ __align__(16) ushort Bl[48 * 64];
  int tid = threadIdx.x;
  int m0 = blockIdx.x * 64;
  int z = blockIdx.y, k = z & 3;
  const ushort* Az = A + (long)z * 524288;
  const ushort* Bhz = Bhi + (long)k * 24576;
  const ushort* Blz = Blo + (long)k * 24576;
  int lane = tid & 63, wv = tid >> 6;
  int lrow = lane & 15, g = lane >> 4;
  f32x4 acc[3] = {};
  for (int kt = 0; kt < 8; ++kt) {
    int kb = kt << 6;
    #pragma unroll
    for (int i = 0; i < 2; ++i) {
      int idx = i * 256 + tid;
      int row = idx >> 3, gi = idx & 7;
      uint4 v = *(const uint4*)&Az[(long)(m0 + row) * 512 + kb + gi * 8];
      *(uint4*)&Ah[row * 64 + ((gi ^ (row & 7)) << 3)] = v;
      if (idx < 384) {
        long off = (long)row * 512 + kb + gi * 8;
        int la = row * 64 + ((gi ^ (row & 7)) << 3);
        *(uint4*)&Bh[la] = *(const uint4*)&Bhz[off];
        *(uint4*)&Bl[la] = *(const uint4*)&Blz[off];
      }
    }
    __syncthreads();
    #pragma unroll
    for (int kk = 0; kk < 2; ++kk) {
      int arow = wv * 16 + lrow;
      bf16x8 af = *(const bf16x8*)&Ah[arow * 64 + ((((kk << 2) + g) ^ (arow & 7)) << 3)];
      #pragma unroll
      for (int ni = 0; ni < 3; ++ni) {
        int brow = ni * 16 + lrow;
        int col = (((kk << 2) + g) ^ (brow & 7)) << 3;
        bf16x8 bh = *(const bf16x8*)&Bh[brow * 64 + col];
        bf16x8 bl = *(const bf16x8*)&Bl[brow * 64 + col];
        acc[ni] = __builtin_amdgcn_mfma_f32_16x16x32_bf16(af, bh, acc[ni], 0, 0, 0);
        acc[ni] = __builtin_amdgcn_mfma_f32_16x16x32_bf16(af, bl, acc[ni], 0, 0, 0);
      }
    }
    __syncthreads();
  }
  float* Cz = xdbl + (long)z * 49152;
  int r4 = lane >> 4;
  #pragma unroll
  for (int ni = 0; ni < 3; ++ni) {
    int n = ni * 16 + lrow;
    int mb = m0 + wv * 16 + r4 * 4;
    #pragma unroll
    for (int r = 0; r < 4; ++r)
      Cz[(long)(mb + r) * 48 + n] = acc[ni][r];
  }
}

// ---------------- reduce split-K partials: C (=/+=) sum_s P + bias ----------
__global__ __launch_bounds__(256) void reduce_split(const float* __restrict__ P,
    float* __restrict__ C, const float* __restrict__ bias,
    int MN, int N, int S, int accumulate) {
  int i = blockIdx.x * 256 + threadIdx.x;
  if (i * 4 >= MN) return;
  float4 v = make_float4(0.f, 0.f, 0.f, 0.f);
  for (int s = 0; s < S; ++s) {
    float4 p = *(const float4*)(P + (long)s * MN + i * 4);
    v.x += p.x; v.y += p.y; v.z += p.z; v.w += p.w;
  }
  if (bias) {
    float4 bv = *(const float4*)(bias + ((i * 4) & (N - 1)));
    v.x += bv.x; v.y += bv.y; v.z += bv.z; v.w += bv.w;
  }
  if (accumulate) {
    float4 o = *(const float4*)(C + (long)i * 4);
    v.x += o.x; v.y += o.y; v.z += o.z; v.w += o.w;
  }
  *(float4*)(C + (long)i * 4) = v;
}

// ---------------- block reduce helper (256 threads) ----------------
__device__ __forceinline__ float blk_sum(float v, float* sm) {
  #pragma unroll
  for (int o = 32; o > 0; o >>= 1) v += __shfl_down(v, o);
  int wid = threadIdx.x >> 6, lane = threadIdx.x & 63;
  __syncthreads();
  if (lane == 0) sm[wid] = v;
  __syncthreads();
  int nw = blockDim.x >> 6;
  float r = 0.f;
  for (int i = 0; i < nw; ++i) r += sm[i];
  return r;
}

// ------- fused: patch split-K reduce + bias -> t, then LN1 -> u (bf16) -------
__global__ __launch_bounds__(256) void reduce_ln1(const float* __restrict__ P,
    float* __restrict__ t, const float* __restrict__ bias,
    const float* __restrict__ g, const float* __restrict__ b,
    ushort* __restrict__ u) {
  __shared__ float sm[8];
  int m = blockIdx.x, c = threadIdx.x;
  float v = bias[c];
  #pragma unroll
  for (int s = 0; s < 8; ++s) v += P[(long)s * 524288 + m * 256 + c];
  t[(long)m * 256 + c] = v;
  float s1 = blk_sum(v, sm);
  float s2 = blk_sum(v * v, sm);
  float mu = s1 * (1.f / 256.f);
  float var = s2 * (1.f / 256.f) - mu * mu;
  float rs = rsqrtf(var + 1e-5f);
  u[(long)m * 256 + c] = bf16_rn((v - mu) * rs * g[c] + b[c]);
}

// ---------------- generic NT GEMM (fp32 VALU) for the dts GEMM ---------------
template<int ACT>
__global__ __launch_bounds__(256) void gemm_nt(
    const float* __restrict__ Ag, const float* __restrict__ Bg,
    const float* __restrict__ biasg, float* Cg,
    int M, int N, int Kd, int lda, int ldb, int ldc,
    long sA, long sB, long sBias, long sC, int bmod, int accumulate)
{
  __shared__ __align__(16) float As[64 * 36];
  __shared__ float Bs[32 * 33];
  int z = blockIdx.z;
  int zb = (bmod > 1) ? (z % bmod) : 0;
  const float* A = Ag + (long)z * sA;
  const float* Bm = Bg + (long)zb * sB;
  const float* bias = biasg ? (biasg + (long)zb * sBias) : nullptr;
  float* C = Cg + (long)z * sC;
  int tid = threadIdx.x;
  int n0 = blockIdx.x * 32;
  int m0 = blockIdx.y * 64;
  int tn = tid & 7, tm = tid >> 3;
  float acc[2][4] = {};
  int nk = (Kd + 31) >> 5;
  for (int kt = 0; kt < nk; ++kt) {
    int k0 = kt << 5;
    #pragma unroll
    for (int i = 0; i < 2; ++i) {
      int idx = i * 256 + tid;
      int row = idx >> 3, c4 = idx & 7;
      int m = m0 + row, k = k0 + c4 * 4;
      float4 v = make_float4(0.f, 0.f, 0.f, 0.f);
      if (m < M && k < Kd) v = *(const float4*)(A + (long)m * lda + k);
      *(float4*)&As[row * 36 + c4 * 4] = v;
    }
    {
      int row = tid >> 3, c4 = tid & 7;
      int n = n0 + row, k = k0 + c4 * 4;
      float4 v = make_float4(0.f, 0.f, 0.f, 0.f);
      if (n < N && k < Kd) v = *(const float4*)(Bm + (long)n * ldb + k);
      Bs[row * 33 + c4 * 4 + 0] = v.x;
      Bs[row * 33 + c4 * 4 + 1] = v.y;
      Bs[row * 33 + c4 * 4 + 2] = v.z;
      Bs[row * 33 + c4 * 4 + 3] = v.w;
    }
    __syncthreads();
    #pragma unroll
    for (int kk = 0; kk < 32; ++kk) {
      float a0 = As[(tm * 2 + 0) * 36 + kk];
      float a1 = As[(tm * 2 + 1) * 36 + kk];
      #pragma unroll
      for (int j = 0; j < 4; ++j) {
        float bv = Bs[(tn * 4 + j) * 33 + kk];
        acc[0][j] += a0 * bv;
        acc[1][j] += a1 * bv;
      }
    }
    __syncthreads();
  }
  bool fullN = (n0 + 32 <= N);
  #pragma unroll
  for (int i = 0; i < 2; ++i) {
    int m = m0 + tm * 2 + i;
    if (m >= M) continue;
    float r[4];
    #pragma unroll
    for (int j = 0; j < 4; ++j) {
      int n = n0 + tn * 4 + j;
      float v = acc[i][j];
      if (bias && n < N) v += bias[n];
      if (ACT == 1) v = (v > 20.f) ? v : __logf(1.f + __expf(v));  // softplus
      r[j] = v;
    }
    long base = (long)m * ldc + n0 + tn * 4;
    if (fullN) {
      float4 o = make_float4(r[0], r[1], r[2], r[3]);
      if (accumulate) {
        float4 old = *(float4*)(C + base);
        o.x += old.x; o.y += old.y; o.z += old.z; o.w += old.w;
      }
      *(float4*)(C + base) = o;
    } else {
      #pragma unroll
      for (int j = 0; j < 4; ++j) {
        int n = n0 + tn * 4 + j;
        if (n < N) {
          float v = r[j];
          if (accumulate) v += C[(long)m * ldc + n];
          C[(long)m * ldc + n] = v;
        }
      }
    }
  }
}

// ---------------- depthwise 3x3 + bias + silu (bf16 output) ----------------
__global__ __launch_bounds__(256) void dwconv_kernel(const float* __restrict__ xc,
    const float* __restrict__ cw, const float* __restrict__ cb, ushort* __restrict__ out) {
  __shared__ float plane[32][33];
  int d = blockIdx.x, b = blockIdx.y;
  long base = ((long)b * 512 + d) * 1024;
  int tid = threadIdx.x;
  float4 v = *(const float4*)(xc + base + tid * 4);
  int h0 = (tid * 4) >> 5, w0 = (tid * 4) & 31;
  plane[h0][w0 + 0] = v.x; plane[h0][w0 + 1] = v.y;
  plane[h0][w0 + 2] = v.z; plane[h0][w0 + 3] = v.w;
  float w9[9];
  #pragma unroll
  for (int i = 0; i < 9; ++i) w9[i] = cw[d * 9 + i];
  float bias = cb[d];
  __syncthreads();
  float o4[4];
  #pragma unroll
  for (int j = 0; j < 4; ++j) {
    int p = tid * 4 + j, h = p >> 5, w = p & 31;
    float acc = 0.f;
    #pragma unroll
    for (int dh = -1; dh <= 1; ++dh) {
      int hy = h + dh;
      if (hy < 0 || hy > 31) continue;
      #pragma unroll
      for (int dw = -1; dw <= 1; ++dw) {
        int wx = w + dw;
        if (wx < 0 || wx > 31) continue;
        acc += w9[(dh + 1) * 3 + (dw + 1)] * plane[hy][wx];
      }
    }
    acc += bias;
    o4[j] = acc / (1.f + __expf(-acc));  // silu
  }
  uint2 o2;
  o2.x = packbf(o4[0], o4[1]);
  o2.y = packbf(o4[2], o4[3]);
  *(uint2*)&out[base + tid * 4] = o2;
}

// --------- build xsT_bf (B,K,L,512) bf16 from xca_bf (B,512,32,32) -----------
__global__ __launch_bounds__(256) void build_xsT(const ushort* __restrict__ xca,
    ushort* __restrict__ xsTb) {
  __shared__ ushort tile[32][34];
  int h = blockIdx.x;
  int d0 = blockIdx.y * 32;
  int z = blockIdx.z;          // z = b*4 + k
  int b = z >> 2, k = z & 3;
  int tid = threadIdx.x;
  int a = tid >> 5, q = tid & 31;
  #pragma unroll
  for (int i = 0; i < 4; ++i) {
    int di = a + i * 8;
    tile[di][q] = xca[((long)(b * 512 + d0 + di)) * 1024 + h * 32 + q];
  }
  __syncthreads();
  #pragma unroll
  for (int i = 0; i < 4; ++i) {
    int w = a + i * 8;
    int r;
    if (k == 0) r = h * 32 + w;
    else if (k == 1) r = w * 32 + h;
    else if (k == 2) r = 1023 - (h * 32 + w);
    else r = 1023 - (w * 32 + h);
    xsTb[((long)z * 1024 + r) * 512 + d0 + q] = tile[q][w];
  }
}

// ---------------- chunk-parallel selective scan, NC=32, bf16 xv/ys ----------
// LC=32, 2 l-tiles of 16. Block 128 thr = 64 d x 2 n-halves, h[8] in VGPRs.
// Grid (8 d-tiles, 32 chunks, 8 z).
template<bool FINAL>
__global__ __launch_bounds__(128) void scan_chunk5(
    const float* __restrict__ dts, ushort* xsb, const float* __restrict__ xdbl,
    const float* __restrict__ A_log, const float* __restrict__ Ds,
    float* __restrict__ Pb, float* __restrict__ hpb)
{
  __shared__ float sdt[16][64], sxv[16][64], sy[16][64];
  __shared__ float sBC[32][32];     // [l][n]: n<16 -> B, n>=16 -> C
  int tid = threadIdx.x;
  int dl = tid >> 1, ng = tid & 1;
  int d0 = blockIdx.x * 64;
  int d = d0 + dl;
  int c = blockIdx.y;              // 0..31
  int z = blockIdx.z;
  int k = z & 3;
  long baseD = (long)z * 524288;
  int l0 = c * 32;
  float a[8], h[8];
  #pragma unroll
  for (int j = 0; j < 8; ++j) {
    a[j] = -__expf(A_log[((long)k * 512 + d) * 16 + ng * 8 + j]);
    h[j] = 0.f;
  }
  int gbase = c * 65536 + z * 8192 + d * 16 + ng * 8;
  float Dv = 0.f;
  if (FINAL) {
    #pragma unroll
    for (int j = 0; j < 8; ++j) h[j] = hpb[gbase + j];   // h_in (prefix in-place)
    Dv = Ds[k * 512 + d];
  }
  // stage B/C for whole chunk
  #pragma unroll
  for (int i = 0; i < 2; ++i) {
    int idx = i * 128 + tid;
    int l = idx >> 3, q = idx & 7;
    *(float4*)&sBC[l][q * 4] =
        *(const float4*)(xdbl + (long)z * 49152 + (long)(l0 + l) * 48 + 16 + q * 4);
  }
  int sli = tid >> 4;              // dt staging: 8 rows/pass, 2 passes
  int sdj = (tid & 15) * 4;
  int xli = tid >> 3;              // xv staging: 16 rows, 1 pass (8 bf16/thread)
  int xdj = (tid & 7) * 8;
  float4 rdt[2]; uint4 rxv;
  #pragma unroll
  for (int i = 0; i < 2; ++i)
    rdt[i] = *(const float4*)(dts + baseD + (long)(l0 + sli + i * 8) * 512 + d0 + sdj);
  rxv = *(const uint4*)&xsb[baseD + (long)(l0 + xli) * 512 + d0 + xdj];
  float dtsum = 0.f;
  for (int t = 0; t < 2; ++t) {
    #pragma unroll
    for (int i = 0; i < 2; ++i)
      *(float4*)&sdt[sli + i * 8][sdj] = rdt[i];
    {
      float4 f0, f1;
      f0.x = bf2f(rxv.x & 0xffff); f0.y = bf2f(rxv.x >> 16);
      f0.z = bf2f(rxv.y & 0xffff); f0.w = bf2f(rxv.y >> 16);
      f1.x = bf2f(rxv.z & 0xffff); f1.y = bf2f(rxv.z >> 16);
      f1.z = bf2f(rxv.w & 0xffff); f1.w = bf2f(rxv.w >> 16);
      *(float4*)&sxv[xli][xdj] = f0;
      *(float4*)&sxv[xli][xdj + 4] = f1;
    }
    __syncthreads();
    if (t == 0) {
      #pragma unroll
      for (int i = 0; i < 2; ++i)
        rdt[i] = *(const float4*)(dts + baseD + (long)(l0 + 16 + sli + i * 8) * 512 + d0 + sdj);
      rxv = *(const uint4*)&xsb[baseD + (long)(l0 + 16 + xli) * 512 + d0 + xdj];
    }
    #pragma unroll
    for (int li = 0; li < 16; ++li) {
      float dt = sdt[li][dl];
      float xv = sxv[li][dl];
      float w = dt * xv;
      int lr = t * 16 + li;
      float4 B0 = *(const float4*)&sBC[lr][ng * 8];
      float4 B1 = *(const float4*)&sBC[lr][ng * 8 + 4];
      if (!FINAL) {
        dtsum += dt;
        h[0] = __expf(dt * a[0]) * h[0] + w * B0.x;
        h[1] = __expf(dt * a[1]) * h[1] + w * B0.y;
        h[2] = __expf(dt * a[2]) * h[2] + w * B0.z;
        h[3] = __expf(dt * a[3]) * h[3] + w * B0.w;
        h[4] = __expf(dt * a[4]) * h[4] + w * B1.x;
        h[5] = __expf(dt * a[5]) * h[5] + w * B1.y;
        h[6] = __expf(dt * a[6]) * h[6] + w * B1.z;
        h[7] = __expf(dt * a[7]) * h[7] + w * B1.w;
      } else {
        float4 C0 = *(const float4*)&sBC[lr][16 + ng * 8];
        float4 C1 = *(const float4*)&sBC[lr][16 + ng * 8 + 4];
        float p;
        h[0] = __expf(dt * a[0]) * h[0] + w * B0.x; p  = h[0] * C0.x;
        h[1] = __expf(dt * a[1]) * h[1] + w * B0.y; p += h[1] * C0.y;
        h[2] = __expf(dt * a[2]) * h[2] + w * B0.z; p += h[2] * C0.z;
        h[3] = __expf(dt * a[3]) * h[3] + w * B0.w; p += h[3] * C0.w;
        h[4] = __expf(dt * a[4]) * h[4] + w * B1.x; p += h[4] * C1.x;
        h[5] = __expf(dt * a[5]) * h[5] + w * B1.y; p += h[5] * C1.y;
        h[6] = __expf(dt * a[6]) * h[6] + w * B1.z; p += h[6] * C1.z;
        h[7] = __expf(dt * a[7]) * h[7] + w * B1.w; p += h[7] * C1.w;
        p += __shfl_xor(p, 1);
        if (ng == 0) sy[li][dl] = p + Dv * xv;
      }
    }
    __syncthreads();
    if (FINAL) {
      float4 f0 = *(float4*)&sy[xli][xdj];
      float4 f1 = *(float4*)&sy[xli][xdj + 4];
      uint4 o;
      o.x = packbf(f0.x, f0.y); o.y = packbf(f0.z, f0.w);
      o.z = packbf(f1.x, f1.y); o.w = packbf(f1.z, f1.w);
      *(uint4*)&xsb[baseD + (long)(l0 + t * 16 + xli) * 512 + d0 + xdj] = o;
    }
  }
  if (!FINAL) {
    float4 pv;
    #pragma unroll
    for (int i = 0; i < 2; ++i) {
      pv.x = __expf(dtsum * a[i * 4 + 0]);
      pv.y = __expf(dtsum * a[i * 4 + 1]);
      pv.z = __expf(dtsum * a[i * 4 + 2]);
      pv.w = __expf(dtsum * a[i * 4 + 3]);
      *(float4*)(Pb + gbase + i * 4) = pv;
      *(float4*)(hpb + gbase + i * 4) = make_float4(h[i*4+0], h[i*4+1], h[i*4+2], h[i*4+3]);
    }
  }
}

// prefix across the 32 chunks per (z,d,n); writes h_in in-place over hp
__global__ __launch_bounds__(256) void scan_prefix(const float* __restrict__ Pb,
    float* __restrict__ hpb) {
  int g = blockIdx.x * 256 + threadIdx.x;
  float h = 0.f;
  #pragma unroll
  for (int c = 0; c < 32; ++c) {
    float P = Pb[c * 65536 + g];
    float hp = hpb[c * 65536 + g];
    hpb[c * 65536 + g] = h;
    h = P * h + hp;
  }
}

// -------- fused: combine 4 directions (bf16) + LN over 512 + silu(z) --------
__global__ __launch_bounds__(256) void combine_ln2gate(const ushort* __restrict__ ys,
    const float* __restrict__ zb, ushort* __restrict__ out,
    const float* __restrict__ g, const float* __restrict__ b) {
  __shared__ float sm[8];
  int m = blockIdx.x, tid = threadIdx.x;
  int bb = m >> 10, l = m & 1023;
  int hh = l >> 5, w = l & 31;
  int lw = w * 32 + hh;
  long b4 = (long)bb * 4;
  uint u0 = *(const uint*)&ys[((b4 + 0) * 1024 + l) * 512 + tid * 2];
  uint u1 = *(const uint*)&ys[((b4 + 2) * 1024 + (1023 - l)) * 512 + tid * 2];
  uint u2 = *(const uint*)&ys[((b4 + 1) * 1024 + lw) * 512 + tid * 2];
  uint u3 = *(const uint*)&ys[((b4 + 3) * 1024 + (1023 - lw)) * 512 + tid * 2];
  float v0 = bf2f(u0 & 0xffff) + bf2f(u1 & 0xffff) + bf2f(u2 & 0xffff) + bf2f(u3 & 0xffff);
  float v1 = bf2f(u0 >> 16) + bf2f(u1 >> 16) + bf2f(u2 >> 16) + bf2f(u3 >> 16);
  float s1 = blk_sum(v0 + v1, sm);
  float s2 = blk_sum(v0 * v0 + v1 * v1, sm);
  float mu = s1 * (1.f / 512.f);
  float var = s2 * (1.f / 512.f) - mu * mu;
  float rs = rsqrtf(var + 1e-5f);
  float2 gg = *(const float2*)(g + tid * 2);
  float2 bbv = *(const float2*)(b + tid * 2);
  float2 zz = *(const float2*)(zb + (long)m * 512 + tid * 2);
  float y0 = ((v0 - mu) * rs * gg.x + bbv.x) * (zz.x / (1.f + __expf(-zz.x)));
  float y1 = ((v1 - mu) * rs * gg.y + bbv.y) * (zz.y / (1.f + __expf(-zz.y)));
  *(uint*)&out[(long)m * 512 + tid * 2] = packbf(y0, y1);
}

// ---------------- pooled head ----------------
__global__ __launch_bounds__(256) void head_partial(const float* __restrict__ t,
    const float* __restrict__ hw, float* __restrict__ part) {
  __shared__ float sm[8];
  int j = blockIdx.x, b = blockIdx.y;
  int c = threadIdx.x;
  float s = 0.f;
  for (int l = j * 64; l < j * 64 + 64; ++l) s += t[((long)b * 1024 + l) * 256 + c];
  s *= hw[c];
  float tot = blk_sum(s, sm);
  if (c == 0) part[b * 16 + j] = tot;
}

__global__ void head_final(const float* __restrict__ part, const float* __restrict__ hb, float* __restrict__ out) {
  int tid = threadIdx.x;
  float v = (tid < 32) ? part[tid] : 0.f;
  #pragma unroll
  for (int o = 1; o < 16; o <<= 1) v += __shfl_xor(v, o);
  if (tid < 32 && (tid & 15) == 0) out[tid >> 4] = v * (1.f / 1024.f) + hb[0];
}

extern "C" void kernel_launch(void* const* d_in, const int* in_sizes, int n_in,
                              void* d_out, int out_size, void* d_ws, size_t ws_size,
                              hipStream_t stream) {
  const float* x       = (const float*)d_in[0];
  const float* patch_w = (const float*)d_in[1];
  const float* patch_b = (const float*)d_in[2];
  const float* ln_g    = (const float*)d_in[3];
  const float* ln_b    = (const float*)d_in[4];
  const float* in_w    = (const float*)d_in[5];
  const float* conv_w  = (const float*)d_in[6];
  const float* conv_b  = (const float*)d_in[7];
  const float* xproj_w = (const float*)d_in[8];
  const float* dt_w    = (const float*)d_in[9];
  const float* dt_b    = (const float*)d_in[10];
  const float* A_log   = (const float*)d_in[11];
  const float* Ds      = (const float*)d_in[12];
  const float* on_g    = (const float*)d_in[13];
  const float* on_b    = (const float*)d_in[14];
  const float* out_w   = (const float*)d_in[15];
  const float* head_w  = (const float*)d_in[16];
  const float* head_b  = (const float*)d_in[17];

  float* ws = (float*)d_ws;
  float* t_buf   = ws;                    // 2048*256
  float* u_buf   = t_buf + 524288;        // 2048*256   (u_bf16 overlay)
  float* xz_buf  = u_buf + 524288;        // pw splits overlay; later z_buf
  float* xc_buf  = xz_buf + 2097152;      // 2*512*1024 f32 (xc)
  float* xca_buf = xc_buf + 1048576;      // xca_bf overlay; later y_bf overlay
  float* xsT_buf = xca_buf + 1048576;     // A_p overlay (dead after patch mfma)
  float* xdbl_buf= xsT_buf + 4194304;     // 8*1024*48
  float* dts_buf = xdbl_buf + 393216;     // P_patch overlay; dts; P_out
  float* part_buf= dts_buf + 4194304;     // 32
  float* tail    = part_buf + 32;
  // overlays:
  ushort* A_p    = (ushort*)xsT_buf;                // 2048*4096 us
  ushort* pw_hi  = (ushort*)xz_buf;                 // 1048576 us
  ushort* pw_lo  = (ushort*)(xz_buf + 524288);      // 1048576 us
  float*  z_buf  = xz_buf;                          // 2048*512 f (after patch mfma)
  float*  P_patch= dts_buf;                         // 8*524288 f
  float*  P_out  = dts_buf;                         // 4*524288 f
  ushort* u_bf   = (ushort*)u_buf;                  // 2048*256 us
  ushort* xca_bf = (ushort*)xca_buf;                // 2*512*1024 us
  ushort* y_bf   = (ushort*)xca_buf;                // 2048*512 us (after build_xsT)
  // tail: weight splits, xsT bf16, scan P/hp
  ushort* iw_hi  = (ushort*)tail;                   // 262144 us
  ushort* iw_lo  = (ushort*)(tail + 131072);
  ushort* ow_hi  = (ushort*)(tail + 262144);        // 131072 us
  ushort* ow_lo  = (ushort*)(tail + 327680);
  ushort* xw_hi  = (ushort*)(tail + 393216);        // 98304 us
  ushort* xw_lo  = (ushort*)(tail + 442368);
  ushort* xsT_bf = (ushort*)(tail + 491520);        // 4194304 us
  float*  P_buf  = tail + 2588672;                  // 2097152 f
  float*  hp_buf = tail + 4685824;                  // 2097152 f

  // 0. all weight hi/lo splits + im2col A
  split_all<<<6017, 256, 0, stream>>>(patch_w, in_w, out_w, xproj_w,
      pw_hi, pw_lo, iw_hi, iw_lo, ow_hi, ow_lo, xw_hi, xw_lo);
  im2col_bf16<<<dim3(32, 32, 2), 256, 0, stream>>>(x, A_p);
  // 1. patch embed MFMA, split-K=8 -> partials
  mfma_bf<<<dim3(4, 16, 8), 512, 0, stream>>>(A_p, pw_hi, pw_lo, P_patch, nullptr,
      2048, 256, 4096, 512, 0);
  // 2. fused reduce + bias -> t, LN1 -> u (bf16)
  reduce_ln1<<<2048, 256, 0, stream>>>(P_patch, t_buf, patch_b, ln_g, ln_b, u_bf);
  // 3. in-proj MFMA fused epilogue: xc (transposed f32) + z (f32)
  mfma_bf<<<dim3(16, 16, 1), 512, 0, stream>>>(u_bf, iw_hi, iw_lo, xc_buf, z_buf,
      2048, 1024, 256, 256, 2);
  // 4. depthwise conv + silu -> xca (bf16)
  dwconv_kernel<<<dim3(512, 2), 256, 0, stream>>>(xc_buf, conv_w, conv_b, xca_bf);
  // 5. build xsT (bf16, 4 directions)
  build_xsT<<<dim3(32, 16, 8), 256, 0, stream>>>(xca_bf, xsT_bf);
  // 6. x_dbl[z] (1024,48) = xsT_bf[z] @ xproj[k]^T (MFMA)
  mfma_x<<<dim3(16, 8), 256, 0, stream>>>(xsT_bf, xw_hi, xw_lo, xdbl_buf);
  // 7. dts[z] (1024,512) = softplus(x_dbl[:, :16] @ dt_w[k]^T + dt_b[k])
  gemm_nt<1><<<dim3(16, 16, 8), 256, 0, stream>>>(xdbl_buf, dt_w, dt_b, dts_buf,
      1024, 512, 16, 48, 16, 512, 49152, 8192, 512, 524288, 4, 0);
  // 8. chunk-parallel selective scan (NC=32, bf16 xv/ys in-place)
  scan_chunk5<false><<<dim3(8, 32, 8), 128, 0, stream>>>(dts_buf, xsT_bf, xdbl_buf,
      A_log, Ds, P_buf, hp_buf);
  scan_prefix<<<256, 256, 0, stream>>>(P_buf, hp_buf);
  scan_chunk5<true><<<dim3(8, 32, 8), 128, 0, stream>>>(dts_buf, xsT_bf, xdbl_buf,
      A_log, Ds, nullptr, hp_buf);
  // 9. fused combine + LN2 + silu gate -> y_bf16
  combine_ln2gate<<<2048, 256, 0, stream>>>(xsT_bf, z_buf, y_bf, on_g, on_b);
  // 10. t += y @ out_w^T (MFMA split-K=4; P_out over dead dts)
  mfma_bf<<<dim3(4, 16, 4), 512, 0, stream>>>(y_bf, ow_hi, ow_lo, P_out, nullptr,
      2048, 256, 512, 128, 0);
  reduce_split<<<512, 256, 0, stream>>>(P_out, t_buf, nullptr, 524288, 256, 4, 1);
  // 11. pooled head
  head_partial<<<dim3(16, 2), 256, 0, stream>>>(t_buf, head_w, part_buf);
  head_final<<<1, 64, 0, stream>>>(part_buf, head_b, (float*)d_out);
}

// Round 9
// 140.754 us; speedup vs baseline: 5.7451x; 1.0536x over previous
//
#include <hip/hip_runtime.h>
#include <math.h>

// VMamba discriminator forward. GEMMs: bf16 MFMA, weights hi/lo split
// (systematic error -> 2^-18), activations bf16-hi, fp32 accum.
// Scan: chunk-parallel NC=32, states in regs, dt-projection fused in-kernel;
// xs/ys/xc pipeline in bf16.
// B=2, C=256, IMG=128, P=4 -> H=W=32, L=1024, D_INNER=512, N=16, R=16, K=4

typedef __attribute__((ext_vector_type(4))) float f32x4;
typedef __attribute__((ext_vector_type(8))) short bf16x8;

__device__ __forceinline__ ushort bf16_rn(float f) {
  uint u = __float_as_uint(f);
  return (ushort)((u + 0x7fffu + ((u >> 16) & 1u)) >> 16);
}
__device__ __forceinline__ float bf2f(uint us) { return __uint_as_float(us << 16); }
__device__ __forceinline__ uint packbf(float a, float b) {
  return (uint)bf16_rn(a) | ((uint)bf16_rn(b) << 16);
}

// ---------------- all weight hi/lo splits in one launch ----------------
__global__ __launch_bounds__(256) void split_all(
    const float* __restrict__ pw, const float* __restrict__ iw,
    const float* __restrict__ ow, const float* __restrict__ xw,
    ushort* __restrict__ pwh, ushort* __restrict__ pwl,
    ushort* __restrict__ iwh, ushort* __restrict__ iwl,
    ushort* __restrict__ owh, ushort* __restrict__ owl,
    ushort* __restrict__ xwh, ushort* __restrict__ xwl) {
  int i = blockIdx.x * 256 + threadIdx.x;
  const float* src; ushort* hi; ushort* lo; int off;
  if (i < 1048576)      { src = pw; hi = pwh; lo = pwl; off = i; }
  else if (i < 1310720) { src = iw; hi = iwh; lo = iwl; off = i - 1048576; }
  else if (i < 1441792) { src = ow; hi = owh; lo = owl; off = i - 1310720; }
  else if (i < 1540096) { src = xw; hi = xwh; lo = xwl; off = i - 1441792; }
  else return;
  float f = src[off];
  ushort h = bf16_rn(f);
  hi[off] = h;
  lo[off] = bf16_rn(f - __uint_as_float(((uint)h) << 16));
}

// ---------------- im2col + f32->bf16: x (B,256,128,128) -> A_p (2048,4096) ----
__global__ __launch_bounds__(256) void im2col_bf16(const float* __restrict__ x,
    ushort* __restrict__ Ap) {
  __shared__ __align__(16) ushort tile[32][136];
  int c0 = blockIdx.x * 8, hh = blockIdx.y, b = blockIdx.z;
  int tid = threadIdx.x;
  int ci = tid >> 5, ph = (tid >> 3) & 3, w4 = tid & 7;
  const float* src = x + (((long)(b * 256 + c0 + ci) * 128 + 4 * hh + ph) * 128 + 16 * w4);
  #pragma unroll
  for (int j = 0; j < 4; ++j) {
    float4 v = *(const float4*)(src + 4 * j);
    uint2 pk;
    pk.x = packbf(v.x, v.y);
    pk.y = packbf(v.z, v.w);
    *(uint2*)&tile[w4 * 4 + j][ci * 16 + ph * 4] = pk;
  }
  __syncthreads();
  int w = tid >> 3;
  long rowbase = ((long)(b * 1024 + hh * 32 + w)) * 4096 + c0 * 16;
  #pragma unroll
  for (int i = 0; i < 2; ++i) {
    int gr = (tid & 7) + 8 * i;
    *(uint4*)&Ap[rowbase + gr * 8] = *(const uint4*)&tile[w][gr * 8];
  }
}

// ---------------- MFMA NT GEMM (bf16 A, hi/lo bf16 B, fp32 out) --------------
// mode 0: split-K partials at Cout + z*M*N.  mode 2: in-proj fused epilogue:
// n<512 -> xc bf16 (B,512,32,32) uint2; n>=512 -> C2 z-buffer [m][512] f32.
__global__ __launch_bounds__(512) void mfma_bf(
    const ushort* __restrict__ A, const ushort* __restrict__ Bhi,
    const ushort* __restrict__ Blo, float* __restrict__ Cout, float* __restrict__ C2,
    int M, int N, int K, int kchunk, int mode)
{
  __shared__ __align__(16) ushort Ah[128 * 64];
  __shared__ __align__(16) ushort Bh[64 * 64];
  __shared__ __align__(16) ushort Bl[64 * 64];
  int tid = threadIdx.x;
  int n0 = blockIdx.x * 64;
  int m0 = blockIdx.y * 128;
  int k0 = blockIdx.z * kchunk;
  int wid = tid >> 6, lane = tid & 63;
  int wm = wid >> 1, wn = wid & 1;
  int lrow = lane & 15, g = lane >> 4;
  f32x4 acc[2][2] = {};
  int nkt = kchunk >> 6;
  for (int kt = 0; kt < nkt; ++kt) {
    int kb = k0 + (kt << 6);
    {
      int gi = tid & 7;
      #pragma unroll
      for (int i = 0; i < 2; ++i) {
        int row = (tid >> 3) + (i << 6);
        uint4 v = *(const uint4*)&A[(long)(m0 + row) * K + kb + gi * 8];
        *(uint4*)&Ah[row * 64 + ((gi ^ (row & 7)) << 3)] = v;
      }
      int row = tid >> 3;
      long off = (long)(n0 + row) * K + kb + gi * 8;
      int la = row * 64 + ((gi ^ (row & 7)) << 3);
      *(uint4*)&Bh[la] = *(const uint4*)&Bhi[off];
      *(uint4*)&Bl[la] = *(const uint4*)&Blo[off];
    }
    __syncthreads();
    #pragma unroll
    for (int kk = 0; kk < 2; ++kk) {
      bf16x8 af[2], bhf[2], blf[2];
      #pragma unroll
      for (int mi = 0; mi < 2; ++mi) {
        int row = wm * 32 + mi * 16 + lrow;
        af[mi] = *(const bf16x8*)&Ah[row * 64 + ((((kk << 2) + g) ^ (row & 7)) << 3)];
      }
      #pragma unroll
      for (int ni = 0; ni < 2; ++ni) {
        int row = wn * 32 + ni * 16 + lrow;
        int col = (((kk << 2) + g) ^ (row & 7)) << 3;
        bhf[ni] = *(const bf16x8*)&Bh[row * 64 + col];
        blf[ni] = *(const bf16x8*)&Bl[row * 64 + col];
      }
      #pragma unroll
      for (int mi = 0; mi < 2; ++mi)
        #pragma unroll
        for (int ni = 0; ni < 2; ++ni) {
          acc[mi][ni] = __builtin_amdgcn_mfma_f32_16x16x32_bf16(af[mi], bhf[ni], acc[mi][ni], 0, 0, 0);
          acc[mi][ni] = __builtin_amdgcn_mfma_f32_16x16x32_bf16(af[mi], blf[ni], acc[mi][ni], 0, 0, 0);
        }
    }
    __syncthreads();
  }
  int r4 = lane >> 4;
  if (mode == 2) {
    bool xhalf = (n0 < 512);
    ushort* xcb = (ushort*)Cout;
    #pragma unroll
    for (int mi = 0; mi < 2; ++mi)
      #pragma unroll
      for (int ni = 0; ni < 2; ++ni) {
        int n = n0 + wn * 32 + ni * 16 + lrow;
        int mb = m0 + wm * 32 + mi * 16 + r4 * 4;
        int bb = mb >> 10, l = mb & 1023;
        if (xhalf) {
          uint2 o;
          o.x = packbf(acc[mi][ni][0], acc[mi][ni][1]);
          o.y = packbf(acc[mi][ni][2], acc[mi][ni][3]);
          *(uint2*)&xcb[((long)(bb * 512 + n)) * 1024 + l] = o;
        } else {
          #pragma unroll
          for (int r = 0; r < 4; ++r)
            C2[(long)(mb + r) * 512 + (n - 512)] = acc[mi][ni][r];
        }
      }
  } else {
    long zoff = (long)blockIdx.z * M * N;
    #pragma unroll
    for (int mi = 0; mi < 2; ++mi)
      #pragma unroll
      for (int ni = 0; ni < 2; ++ni) {
        int n = n0 + wn * 32 + ni * 16 + lrow;
        int mb = m0 + wm * 32 + mi * 16 + r4 * 4;
        #pragma unroll
        for (int r = 0; r < 4; ++r)
          Cout[zoff + (long)(mb + r) * N + n] = acc[mi][ni][r];
      }
  }
}

// ---------------- MFMA x_dbl: xdbl[z] (1024,48) = xsT_bf[z] @ xproj[k]^T -----
__global__ __launch_bounds__(256) void mfma_x(
    const ushort* __restrict__ A, const ushort* __restrict__ Bhi,
    const ushort* __restrict__ Blo, float* __restrict__ xdbl)
{
  __shared__ __align__(16) ushort Ah[64 * 64];
  __shared__ __align__(16) ushort Bh[48 * 64];
  __shared__ __align__(16) ushort Bl[48 * 64];
  int tid = threadIdx.x;
  int m0 = blockIdx.x * 64;
  int z = blockIdx.y, k = z & 3;
  const ushort* Az = A + (long)z * 524288;
  const ushort* Bhz = Bhi + (long)k * 24576;
  const ushort* Blz = Blo + (long)k * 24576;
  int lane = tid & 63, wv = tid >> 6;
  int lrow = lane & 15, g = lane >> 4;
  f32x4 acc[3] = {};
  for (int kt = 0; kt < 8; ++kt) {
    int kb = kt << 6;
    #pragma unroll
    for (int i = 0; i < 2; ++i) {
      int idx = i * 256 + tid;
      int row = idx >> 3, gi = idx & 7;
      uint4 v = *(const uint4*)&Az[(long)(m0 + row) * 512 + kb + gi * 8];
      *(uint4*)&Ah[row * 64 + ((gi ^ (row & 7)) << 3)] = v;
      if (idx < 384) {
        long off = (long)row * 512 + kb + gi * 8;
        int la = row * 64 + ((gi ^ (row & 7)) << 3);
        *(uint4*)&Bh[la] = *(const uint4*)&Bhz[off];
        *(uint4*)&Bl[la] = *(const uint4*)&Blz[off];
      }
    }
    __syncthreads();
    #pragma unroll
    for (int kk = 0; kk < 2; ++kk) {
      int arow = wv * 16 + lrow;
      bf16x8 af = *(const bf16x8*)&Ah[arow * 64 + ((((kk << 2) + g) ^ (arow & 7)) << 3)];
      #pragma unroll
      for (int ni = 0; ni < 3; ++ni) {
        int brow = ni * 16 + lrow;
        int col = (((kk << 2) + g) ^ (brow & 7)) << 3;
        bf16x8 bh = *(const bf16x8*)&Bh[brow * 64 + col];
        bf16x8 bl = *(const bf16x8*)&Bl[brow * 64 + col];
        acc[ni] = __builtin_amdgcn_mfma_f32_16x16x32_bf16(af, bh, acc[ni], 0, 0, 0);
        acc[ni] = __builtin_amdgcn_mfma_f32_16x16x32_bf16(af, bl, acc[ni], 0, 0, 0);
      }
    }
    __syncthreads();
  }
  float* Cz = xdbl + (long)z * 49152;
  int r4 = lane >> 4;
  #pragma unroll
  for (int ni = 0; ni < 3; ++ni) {
    int n = ni * 16 + lrow;
    int mb = m0 + wv * 16 + r4 * 4;
    #pragma unroll
    for (int r = 0; r < 4; ++r)
      Cz[(long)(mb + r) * 48 + n] = acc[ni][r];
  }
}

// ---------------- reduce split-K partials: C (=/+=) sum_s P + bias ----------
__global__ __launch_bounds__(256) void reduce_split(const float* __restrict__ P,
    float* __restrict__ C, const float* __restrict__ bias,
    int MN, int N, int S, int accumulate) {
  int i = blockIdx.x * 256 + threadIdx.x;
  if (i * 4 >= MN) return;
  float4 v = make_float4(0.f, 0.f, 0.f, 0.f);
  for (int s = 0; s < S; ++s) {
    float4 p = *(const float4*)(P + (long)s * MN + i * 4);
    v.x += p.x; v.y += p.y; v.z += p.z; v.w += p.w;
  }
  if (bias) {
    float4 bv = *(const float4*)(bias + ((i * 4) & (N - 1)));
    v.x += bv.x; v.y += bv.y; v.z += bv.z; v.w += bv.w;
  }
  if (accumulate) {
    float4 o = *(const float4*)(C + (long)i * 4);
    v.x += o.x; v.y += o.y; v.z += o.z; v.w += o.w;
  }
  *(float4*)(C + (long)i * 4) = v;
}

// ---------------- block reduce helper (256 threads) ----------------
__device__ __forceinline__ float blk_sum(float v, float* sm) {
  #pragma unroll
  for (int o = 32; o > 0; o >>= 1) v += __shfl_down(v, o);
  int wid = threadIdx.x >> 6, lane = threadIdx.x & 63;
  __syncthreads();
  if (lane == 0) sm[wid] = v;
  __syncthreads();
  int nw = blockDim.x >> 6;
  float r = 0.f;
  for (int i = 0; i < nw; ++i) r += sm[i];
  return r;
}

// ------- fused: patch split-K reduce + bias -> t, then LN1 -> u (bf16) -------
__global__ __launch_bounds__(256) void reduce_ln1(const float* __restrict__ P,
    float* __restrict__ t, const float* __restrict__ bias,
    const float* __restrict__ g, const float* __restrict__ b,
    ushort* __restrict__ u) {
  __shared__ float sm[8];
  int m = blockIdx.x, c = threadIdx.x;
  float v = bias[c];
  #pragma unroll
  for (int s = 0; s < 8; ++s) v += P[(long)s * 524288 + m * 256 + c];
  t[(long)m * 256 + c] = v;
  float s1 = blk_sum(v, sm);
  float s2 = blk_sum(v * v, sm);
  float mu = s1 * (1.f / 256.f);
  float var = s2 * (1.f / 256.f) - mu * mu;
  float rs = rsqrtf(var + 1e-5f);
  u[(long)m * 256 + c] = bf16_rn((v - mu) * rs * g[c] + b[c]);
}

// ---------------- depthwise 3x3 + bias + silu (bf16 in/out) ----------------
__global__ __launch_bounds__(256) void dwconv_kernel(const ushort* __restrict__ xc,
    const float* __restrict__ cw, const float* __restrict__ cb, ushort* __restrict__ out) {
  __shared__ float plane[32][33];
  int d = blockIdx.x, b = blockIdx.y;
  long base = ((long)b * 512 + d) * 1024;
  int tid = threadIdx.x;
  uint2 v = *(const uint2*)&xc[base + tid * 4];
  int h0 = (tid * 4) >> 5, w0 = (tid * 4) & 31;
  plane[h0][w0 + 0] = bf2f(v.x & 0xffff); plane[h0][w0 + 1] = bf2f(v.x >> 16);
  plane[h0][w0 + 2] = bf2f(v.y & 0xffff); plane[h0][w0 + 3] = bf2f(v.y >> 16);
  float w9[9];
  #pragma unroll
  for (int i = 0; i < 9; ++i) w9[i] = cw[d * 9 + i];
  float bias = cb[d];
  __syncthreads();
  float o4[4];
  #pragma unroll
  for (int j = 0; j < 4; ++j) {
    int p = tid * 4 + j, h = p >> 5, w = p & 31;
    float acc = 0.f;
    #pragma unroll
    for (int dh = -1; dh <= 1; ++dh) {
      int hy = h + dh;
      if (hy < 0 || hy > 31) continue;
      #pragma unroll
      for (int dw = -1; dw <= 1; ++dw) {
        int wx = w + dw;
        if (wx < 0 || wx > 31) continue;
        acc += w9[(dh + 1) * 3 + (dw + 1)] * plane[hy][wx];
      }
    }
    acc += bias;
    o4[j] = acc / (1.f + __expf(-acc));  // silu
  }
  uint2 o2;
  o2.x = packbf(o4[0], o4[1]);
  o2.y = packbf(o4[2], o4[3]);
  *(uint2*)&out[base + tid * 4] = o2;
}

// --------- build xsT_bf (B,K,L,512) bf16 from xca_bf (B,512,32,32) -----------
__global__ __launch_bounds__(256) void build_xsT(const ushort* __restrict__ xca,
    ushort* __restrict__ xsTb) {
  __shared__ ushort tile[32][34];
  int h = blockIdx.x;
  int d0 = blockIdx.y * 32;
  int z = blockIdx.z;          // z = b*4 + k
  int b = z >> 2, k = z & 3;
  int tid = threadIdx.x;
  int a = tid >> 5, q = tid & 31;
  #pragma unroll
  for (int i = 0; i < 4; ++i) {
    int di = a + i * 8;
    tile[di][q] = xca[((long)(b * 512 + d0 + di)) * 1024 + h * 32 + q];
  }
  __syncthreads();
  #pragma unroll
  for (int i = 0; i < 4; ++i) {
    int w = a + i * 8;
    int r;
    if (k == 0) r = h * 32 + w;
    else if (k == 1) r = w * 32 + h;
    else if (k == 2) r = 1023 - (h * 32 + w);
    else r = 1023 - (w * 32 + h);
    xsTb[((long)z * 1024 + r) * 512 + d0 + q] = tile[q][w];
  }
}

// ------- chunk-parallel selective scan, NC=32, fused dt-projection ----------
// LC=32, 2 l-tiles of 16. Block 128 thr = 64 d x 2 n-halves, h[8] in VGPRs.
// dt computed in-kernel: dt[l][d] = softplus(sum_r xdbl[l][r]*dtw[d][r]+dtb[d]).
// Grid (8 d-tiles, 32 chunks, 8 z).
template<bool FINAL>
__global__ __launch_bounds__(128) void scan_chunk6(
    const float* __restrict__ xdbl, ushort* xsb,
    const float* __restrict__ dtw, const float* __restrict__ dtb,
    const float* __restrict__ A_log, const float* __restrict__ Ds,
    float* __restrict__ Pb, float* __restrict__ hpb)
{
  __shared__ float sdt[32][64];       // 8KB: dt for whole chunk
  __shared__ float sxv[16][64];       // 4KB
  __shared__ float sy[16][64];        // 4KB; first 2KB aliased as sR during dt-calc
  __shared__ float sBC[32][32];       // 4KB: [l][n]: n<16 B, n>=16 C
  float (*sR)[16] = (float(*)[16])sy; // [32][16] R-slice of xdbl
  int tid = threadIdx.x;
  int dl = tid >> 1, ng = tid & 1;
  int d0 = blockIdx.x * 64;
  int d = d0 + dl;
  int c = blockIdx.y;              // 0..31
  int z = blockIdx.z;
  int k = z & 3;
  long baseD = (long)z * 524288;
  int l0 = c * 32;
  const float* xdz = xdbl + (long)z * 49152 + (long)l0 * 48;
  // stage B/C and R slices of xdbl
  #pragma unroll
  for (int i = 0; i < 2; ++i) {
    int idx = i * 128 + tid;
    int l = idx >> 3, q = idx & 7;
    *(float4*)&sBC[l][q * 4] = *(const float4*)(xdz + l * 48 + 16 + q * 4);
  }
  {
    int l = tid >> 2, q = tid & 3;
    *(float4*)&sR[l][q * 4] = *(const float4*)(xdz + l * 48 + q * 4);
  }
  float a[8], h[8];
  #pragma unroll
  for (int j = 0; j < 8; ++j) {
    a[j] = -__expf(A_log[((long)k * 512 + d) * 16 + ng * 8 + j]);
    h[j] = 0.f;
  }
  float4 wr0 = *(const float4*)(dtw + ((long)k * 512 + d) * 16);
  float4 wr1 = *(const float4*)(dtw + ((long)k * 512 + d) * 16 + 4);
  float4 wr2 = *(const float4*)(dtw + ((long)k * 512 + d) * 16 + 8);
  float4 wr3 = *(const float4*)(dtw + ((long)k * 512 + d) * 16 + 12);
  float dbias = dtb[k * 512 + d];
  int gbase = c * 65536 + z * 8192 + d * 16 + ng * 8;
  float Dv = 0.f;
  if (FINAL) {
    #pragma unroll
    for (int j = 0; j < 8; ++j) h[j] = hpb[gbase + j];   // h_in (prefix in-place)
    Dv = Ds[k * 512 + d];
  }
  __syncthreads();                 // sR ready
  // compute dt for this thread's 16 l rows (ng selects half)
  #pragma unroll
  for (int li = 0; li < 16; ++li) {
    int l = ng * 16 + li;
    const float* rr = &sR[l][0];
    float acc = dbias;
    acc += wr0.x * rr[0];  acc += wr0.y * rr[1];  acc += wr0.z * rr[2];  acc += wr0.w * rr[3];
    acc += wr1.x * rr[4];  acc += wr1.y * rr[5];  acc += wr1.z * rr[6];  acc += wr1.w * rr[7];
    acc += wr2.x * rr[8];  acc += wr2.y * rr[9];  acc += wr2.z * rr[10]; acc += wr2.w * rr[11];
    acc += wr3.x * rr[12]; acc += wr3.y * rr[13]; acc += wr3.z * rr[14]; acc += wr3.w * rr[15];
    sdt[l][dl] = (acc > 20.f) ? acc : __logf(1.f + __expf(acc));
  }
  __syncthreads();                 // sdt ready; sR dead -> sy writable
  int xli = tid >> 3;              // xv staging: 16 rows, 8 bf16/thread
  int xdj = (tid & 7) * 8;
  uint4 rxv = *(const uint4*)&xsb[baseD + (long)(l0 + xli) * 512 + d0 + xdj];
  float dtsum = 0.f;
  for (int t = 0; t < 2; ++t) {
    {
      float4 f0, f1;
      f0.x = bf2f(rxv.x & 0xffff); f0.y = bf2f(rxv.x >> 16);
      f0.z = bf2f(rxv.y & 0xffff); f0.w = bf2f(rxv.y >> 16);
      f1.x = bf2f(rxv.z & 0xffff); f1.y = bf2f(rxv.z >> 16);
      f1.z = bf2f(rxv.w & 0xffff); f1.w = bf2f(rxv.w >> 16);
      *(float4*)&sxv[xli][xdj] = f0;
      *(float4*)&sxv[xli][xdj + 4] = f1;
    }
    __syncthreads();
    if (t == 0)
      rxv = *(const uint4*)&xsb[baseD + (long)(l0 + 16 + xli) * 512 + d0 + xdj];
    #pragma unroll
    for (int li = 0; li < 16; ++li) {
      int lr = t * 16 + li;
      float dt = sdt[lr][dl];
      float xv = sxv[li][dl];
      float w = dt * xv;
      float4 B0 = *(const float4*)&sBC[lr][ng * 8];
      float4 B1 = *(const float4*)&sBC[lr][ng * 8 + 4];
      if (!FINAL) {
        dtsum += dt;
        h[0] = __expf(dt * a[0]) * h[0] + w * B0.x;
        h[1] = __expf(dt * a[1]) * h[1] + w * B0.y;
        h[2] = __expf(dt * a[2]) * h[2] + w * B0.z;
        h[3] = __expf(dt * a[3]) * h[3] + w * B0.w;
        h[4] = __expf(dt * a[4]) * h[4] + w * B1.x;
        h[5] = __expf(dt * a[5]) * h[5] + w * B1.y;
        h[6] = __expf(dt * a[6]) * h[6] + w * B1.z;
        h[7] = __expf(dt * a[7]) * h[7] + w * B1.w;
      } else {
        float4 C0 = *(const float4*)&sBC[lr][16 + ng * 8];
        float4 C1 = *(const float4*)&sBC[lr][16 + ng * 8 + 4];
        float p;
        h[0] = __expf(dt * a[0]) * h[0] + w * B0.x; p  = h[0] * C0.x;
        h[1] = __expf(dt * a[1]) * h[1] + w * B0.y; p += h[1] * C0.y;
        h[2] = __expf(dt * a[2]) * h[2] + w * B0.z; p += h[2] * C0.z;
        h[3] = __expf(dt * a[3]) * h[3] + w * B0.w; p += h[3] * C0.w;
        h[4] = __expf(dt * a[4]) * h[4] + w * B1.x; p += h[4] * C1.x;
        h[5] = __expf(dt * a[5]) * h[5] + w * B1.y; p += h[5] * C1.y;
        h[6] = __expf(dt * a[6]) * h[6] + w * B1.z; p += h[6] * C1.z;
        h[7] = __expf(dt * a[7]) * h[7] + w * B1.w; p += h[7] * C1.w;
        p += __shfl_xor(p, 1);
        if (ng == 0) sy[li][dl] = p + Dv * xv;
      }
    }
    __syncthreads();
    if (FINAL) {
      float4 f0 = *(float4*)&sy[xli][xdj];
      float4 f1 = *(float4*)&sy[xli][xdj + 4];
      uint4 o;
      o.x = packbf(f0.x, f0.y); o.y = packbf(f0.z, f0.w);
      o.z = packbf(f1.x, f1.y); o.w = packbf(f1.z, f1.w);
      *(uint4*)&xsb[baseD + (long)(l0 + t * 16 + xli) * 512 + d0 + xdj] = o;
    }
  }
  if (!FINAL) {
    float4 pv;
    #pragma unroll
    for (int i = 0; i < 2; ++i) {
      pv.x = __expf(dtsum * a[i * 4 + 0]);
      pv.y = __expf(dtsum * a[i * 4 + 1]);
      pv.z = __expf(dtsum * a[i * 4 + 2]);
      pv.w = __expf(dtsum * a[i * 4 + 3]);
      *(float4*)(Pb + gbase + i * 4) = pv;
      *(float4*)(hpb + gbase + i * 4) = make_float4(h[i*4+0], h[i*4+1], h[i*4+2], h[i*4+3]);
    }
  }
}

// prefix across the 32 chunks per (z,d,n); writes h_in in-place over hp
__global__ __launch_bounds__(256) void scan_prefix(const float* __restrict__ Pb,
    float* __restrict__ hpb) {
  int g = blockIdx.x * 256 + threadIdx.x;
  float h = 0.f;
  #pragma unroll
  for (int c = 0; c < 32; ++c) {
    float P = Pb[c * 65536 + g];
    float hp = hpb[c * 65536 + g];
    hpb[c * 65536 + g] = h;
    h = P * h + hp;
  }
}

// -------- fused: combine 4 directions (bf16) + LN over 512 + silu(z) --------
__global__ __launch_bounds__(256) void combine_ln2gate(const ushort* __restrict__ ys,
    const float* __restrict__ zb, ushort* __restrict__ out,
    const float* __restrict__ g, const float* __restrict__ b) {
  __shared__ float sm[8];
  int m = blockIdx.x, tid = threadIdx.x;
  int bb = m >> 10, l = m & 1023;
  int hh = l >> 5, w = l & 31;
  int lw = w * 32 + hh;
  long b4 = (long)bb * 4;
  uint u0 = *(const uint*)&ys[((b4 + 0) * 1024 + l) * 512 + tid * 2];
  uint u1 = *(const uint*)&ys[((b4 + 2) * 1024 + (1023 - l)) * 512 + tid * 2];
  uint u2 = *(const uint*)&ys[((b4 + 1) * 1024 + lw) * 512 + tid * 2];
  uint u3 = *(const uint*)&ys[((b4 + 3) * 1024 + (1023 - lw)) * 512 + tid * 2];
  float v0 = bf2f(u0 & 0xffff) + bf2f(u1 & 0xffff) + bf2f(u2 & 0xffff) + bf2f(u3 & 0xffff);
  float v1 = bf2f(u0 >> 16) + bf2f(u1 >> 16) + bf2f(u2 >> 16) + bf2f(u3 >> 16);
  float s1 = blk_sum(v0 + v1, sm);
  float s2 = blk_sum(v0 * v0 + v1 * v1, sm);
  float mu = s1 * (1.f / 512.f);
  float var = s2 * (1.f / 512.f) - mu * mu;
  float rs = rsqrtf(var + 1e-5f);
  float2 gg = *(const float2*)(g + tid * 2);
  float2 bbv = *(const float2*)(b + tid * 2);
  float2 zz = *(const float2*)(zb + (long)m * 512 + tid * 2);
  float y0 = ((v0 - mu) * rs * gg.x + bbv.x) * (zz.x / (1.f + __expf(-zz.x)));
  float y1 = ((v1 - mu) * rs * gg.y + bbv.y) * (zz.y / (1.f + __expf(-zz.y)));
  *(uint*)&out[(long)m * 512 + tid * 2] = packbf(y0, y1);
}

// ---------------- pooled head ----------------
__global__ __launch_bounds__(256) void head_partial(const float* __restrict__ t,
    const float* __restrict__ hw, float* __restrict__ part) {
  __shared__ float sm[8];
  int j = blockIdx.x, b = blockIdx.y;
  int c = threadIdx.x;
  float s = 0.f;
  for (int l = j * 64; l < j * 64 + 64; ++l) s += t[((long)b * 1024 + l) * 256 + c];
  s *= hw[c];
  float tot = blk_sum(s, sm);
  if (c == 0) part[b * 16 + j] = tot;
}

__global__ void head_final(const float* __restrict__ part, const float* __restrict__ hb, float* __restrict__ out) {
  int tid = threadIdx.x;
  float v = (tid < 32) ? part[tid] : 0.f;
  #pragma unroll
  for (int o = 1; o < 16; o <<= 1) v += __shfl_xor(v, o);
  if (tid < 32 && (tid & 15) == 0) out[tid >> 4] = v * (1.f / 1024.f) + hb[0];
}

extern "C" void kernel_launch(void* const* d_in, const int* in_sizes, int n_in,
                              void* d_out, int out_size, void* d_ws, size_t ws_size,
                              hipStream_t stream) {
  const float* x       = (const float*)d_in[0];
  const float* patch_w = (const float*)d_in[1];
  const float* patch_b = (const float*)d_in[2];
  const float* ln_g    = (const float*)d_in[3];
  const float* ln_b    = (const float*)d_in[4];
  const float* in_w    = (const float*)d_in[5];
  const float* conv_w  = (const float*)d_in[6];
  const float* conv_b  = (const float*)d_in[7];
  const float* xproj_w = (const float*)d_in[8];
  const float* dt_w    = (const float*)d_in[9];
  const float* dt_b    = (const float*)d_in[10];
  const float* A_log   = (const float*)d_in[11];
  const float* Ds      = (const float*)d_in[12];
  const float* on_g    = (const float*)d_in[13];
  const float* on_b    = (const float*)d_in[14];
  const float* out_w   = (const float*)d_in[15];
  const float* head_w  = (const float*)d_in[16];
  const float* head_b  = (const float*)d_in[17];

  float* ws = (float*)d_ws;
  float* t_buf   = ws;                    // 2048*256
  float* u_buf   = t_buf + 524288;        // 2048*256   (u_bf16 overlay)
  float* xz_buf  = u_buf + 524288;        // pw splits overlay; later z_buf
  float* xc_buf  = xz_buf + 2097152;      // xc_bf overlay (2048*512 us)
  float* xca_buf = xc_buf + 1048576;      // xca_bf overlay; later y_bf overlay
  float* xsT_buf = xca_buf + 1048576;     // A_p overlay (dead after patch mfma)
  float* xdbl_buf= xsT_buf + 4194304;     // 8*1024*48
  float* spl_buf = xdbl_buf + 393216;     // P_patch / P_out overlay (16 MB)
  float* part_buf= spl_buf + 4194304;     // 32
  float* tail    = part_buf + 32;
  // overlays:
  ushort* A_p    = (ushort*)xsT_buf;                // 2048*4096 us
  ushort* pw_hi  = (ushort*)xz_buf;                 // 1048576 us
  ushort* pw_lo  = (ushort*)(xz_buf + 524288);      // 1048576 us
  float*  z_buf  = xz_buf;                          // 2048*512 f (after patch mfma)
  float*  P_patch= spl_buf;                         // 8*524288 f
  float*  P_out  = spl_buf;                         // 4*524288 f
  ushort* u_bf   = (ushort*)u_buf;                  // 2048*256 us
  ushort* xc_bf  = (ushort*)xc_buf;                 // 2048*512 us
  ushort* xca_bf = (ushort*)xca_buf;                // 2*512*1024 us
  ushort* y_bf   = (ushort*)xca_buf;                // 2048*512 us (after build_xsT)
  // tail: weight splits, xsT bf16, scan P/hp
  ushort* iw_hi  = (ushort*)tail;                   // 262144 us
  ushort* iw_lo  = (ushort*)(tail + 131072);
  ushort* ow_hi  = (ushort*)(tail + 262144);        // 131072 us
  ushort* ow_lo  = (ushort*)(tail + 327680);
  ushort* xw_hi  = (ushort*)(tail + 393216);        // 98304 us
  ushort* xw_lo  = (ushort*)(tail + 442368);
  ushort* xsT_bf = (ushort*)(tail + 491520);        // 4194304 us
  float*  P_buf  = tail + 2588672;                  // 2097152 f
  float*  hp_buf = tail + 4685824;                  // 2097152 f

  // 0. all weight hi/lo splits + im2col A
  split_all<<<6017, 256, 0, stream>>>(patch_w, in_w, out_w, xproj_w,
      pw_hi, pw_lo, iw_hi, iw_lo, ow_hi, ow_lo, xw_hi, xw_lo);
  im2col_bf16<<<dim3(32, 32, 2), 256, 0, stream>>>(x, A_p);
  // 1. patch embed MFMA, split-K=8 -> partials
  mfma_bf<<<dim3(4, 16, 8), 512, 0, stream>>>(A_p, pw_hi, pw_lo, P_patch, nullptr,
      2048, 256, 4096, 512, 0);
  // 2. fused reduce + bias -> t, LN1 -> u (bf16)
  reduce_ln1<<<2048, 256, 0, stream>>>(P_patch, t_buf, patch_b, ln_g, ln_b, u_bf);
  // 3. in-proj MFMA fused epilogue: xc (transposed bf16) + z (f32)
  mfma_bf<<<dim3(16, 16, 1), 512, 0, stream>>>(u_bf, iw_hi, iw_lo, xc_buf, z_buf,
      2048, 1024, 256, 256, 2);
  // 4. depthwise conv + silu -> xca (bf16)
  dwconv_kernel<<<dim3(512, 2), 256, 0, stream>>>(xc_bf, conv_w, conv_b, xca_bf);
  // 5. build xsT (bf16, 4 directions)
  build_xsT<<<dim3(32, 16, 8), 256, 0, stream>>>(xca_bf, xsT_bf);
  // 6. x_dbl[z] (1024,48) = xsT_bf[z] @ xproj[k]^T (MFMA)
  mfma_x<<<dim3(16, 8), 256, 0, stream>>>(xsT_bf, xw_hi, xw_lo, xdbl_buf);
  // 7. chunk-parallel selective scan (NC=32, fused dt-projection)
  scan_chunk6<false><<<dim3(8, 32, 8), 128, 0, stream>>>(xdbl_buf, xsT_bf,
      dt_w, dt_b, A_log, Ds, P_buf, hp_buf);
  scan_prefix<<<256, 256, 0, stream>>>(P_buf, hp_buf);
  scan_chunk6<true><<<dim3(8, 32, 8), 128, 0, stream>>>(xdbl_buf, xsT_bf,
      dt_w, dt_b, A_log, Ds, nullptr, hp_buf);
  // 8. fused combine + LN2 + silu gate -> y_bf16
  combine_ln2gate<<<2048, 256, 0, stream>>>(xsT_bf, z_buf, y_bf, on_g, on_b);
  // 9. t += y @ out_w^T (MFMA split-K=4)
  mfma_bf<<<dim3(4, 16, 4), 512, 0, stream>>>(y_bf, ow_hi, ow_lo, P_out, nullptr,
      2048, 256, 512, 128, 0);
  reduce_split<<<512, 256, 0, stream>>>(P_out, t_buf, nullptr, 524288, 256, 4, 1);
  // 10. pooled head
  head_partial<<<dim3(16, 2), 256, 0, stream>>>(t_buf, head_w, part_buf);
  head_final<<<1, 64, 0, stream>>>(part_buf, head_b, (float*)d_out);
}

// Round 10
// 133.257 us; speedup vs baseline: 6.0683x; 1.0563x over previous
//
#include <hip/hip_runtime.h>
#include <math.h>

// VMamba discriminator forward. GEMMs: bf16 MFMA, weights hi/lo split
// (systematic error -> 2^-18), activations bf16-hi, fp32 accum, XCD-local
// n-major block decode. Scan: chunk-parallel NC=32, states in regs, fused
// dt-projection, dtsum-compressed prefix state; xs/ys/xc pipeline in bf16.
// B=2, C=256, IMG=128, P=4 -> H=W=32, L=1024, D_INNER=512, N=16, R=16, K=4

typedef __attribute__((ext_vector_type(4))) float f32x4;
typedef __attribute__((ext_vector_type(8))) short bf16x8;

__device__ __forceinline__ ushort bf16_rn(float f) {
  uint u = __float_as_uint(f);
  return (ushort)((u + 0x7fffu + ((u >> 16) & 1u)) >> 16);
}
__device__ __forceinline__ float bf2f(uint us) { return __uint_as_float(us << 16); }
__device__ __forceinline__ uint packbf(float a, float b) {
  return (uint)bf16_rn(a) | ((uint)bf16_rn(b) << 16);
}

// ------ fused prep: im2col (blocks 0..2047) + weight splits (rest) ----------
__global__ __launch_bounds__(256) void prep_kernel(const float* __restrict__ x,
    ushort* __restrict__ Ap,
    const float* __restrict__ pw, const float* __restrict__ iw,
    const float* __restrict__ ow, const float* __restrict__ xw,
    ushort* __restrict__ pwh, ushort* __restrict__ pwl,
    ushort* __restrict__ iwh, ushort* __restrict__ iwl,
    ushort* __restrict__ owh, ushort* __restrict__ owl,
    ushort* __restrict__ xwh, ushort* __restrict__ xwl) {
  int bid = blockIdx.x;
  int tid = threadIdx.x;
  if (bid < 2048) {
    // im2col + f32->bf16: x (B,256,128,128) -> A_p (2048,4096)
    __shared__ __align__(16) ushort tile[32][136];
    int b = bid >> 10, hh = (bid >> 5) & 31, c0 = (bid & 31) * 8;
    int ci = tid >> 5, ph = (tid >> 3) & 3, w4 = tid & 7;
    const float* src = x + (((long)(b * 256 + c0 + ci) * 128 + 4 * hh + ph) * 128 + 16 * w4);
    #pragma unroll
    for (int j = 0; j < 4; ++j) {
      float4 v = *(const float4*)(src + 4 * j);
      uint2 pk;
      pk.x = packbf(v.x, v.y);
      pk.y = packbf(v.z, v.w);
      *(uint2*)&tile[w4 * 4 + j][ci * 16 + ph * 4] = pk;
    }
    __syncthreads();
    int w = tid >> 3;
    long rowbase = ((long)(b * 1024 + hh * 32 + w)) * 4096 + c0 * 16;
    #pragma unroll
    for (int i = 0; i < 2; ++i) {
      int gr = (tid & 7) + 8 * i;
      *(uint4*)&Ap[rowbase + gr * 8] = *(const uint4*)&tile[w][gr * 8];
    }
  } else {
    int i = (bid - 2048) * 256 + tid;
    const float* src; ushort* hi; ushort* lo; int off;
    if (i < 1048576)      { src = pw; hi = pwh; lo = pwl; off = i; }
    else if (i < 1310720) { src = iw; hi = iwh; lo = iwl; off = i - 1048576; }
    else if (i < 1441792) { src = ow; hi = owh; lo = owl; off = i - 1310720; }
    else if (i < 1540096) { src = xw; hi = xwh; lo = xwl; off = i - 1441792; }
    else return;
    float f = src[off];
    ushort h = bf16_rn(f);
    hi[off] = h;
    lo[off] = bf16_rn(f - __uint_as_float(((uint)h) << 16));
  }
}

// ---------------- MFMA NT GEMM (bf16 A, hi/lo bf16 B, fp32 out) --------------
// 1D grid, n-major decode: id = n*NBM*NBZ + m*NBZ + z so the n-blocks sharing
// an A tile land on the same XCD (stride multiple of 8). mode 0: split-K
// partials at Cout + z*M*N. mode 2: in-proj fused epilogue (xc bf16 + z f32).
__global__ __launch_bounds__(512) void mfma_bf(
    const ushort* __restrict__ A, const ushort* __restrict__ Bhi,
    const ushort* __restrict__ Blo, float* __restrict__ Cout, float* __restrict__ C2,
    int M, int N, int K, int kchunk, int mode, int NBM, int NBZ)
{
  __shared__ __align__(16) ushort Ah[128 * 64];
  __shared__ __align__(16) ushort Bh[64 * 64];
  __shared__ __align__(16) ushort Bl[64 * 64];
  int tid = threadIdx.x;
  int bid = blockIdx.x;
  int kz = bid % NBZ;
  int n0 = (bid / (NBZ * NBM)) * 64;
  int m0 = ((bid / NBZ) % NBM) * 128;
  int k0 = kz * kchunk;
  int wid = tid >> 6, lane = tid & 63;
  int wm = wid >> 1, wn = wid & 1;
  int lrow = lane & 15, g = lane >> 4;
  f32x4 acc[2][2] = {};
  int nkt = kchunk >> 6;
  for (int kt = 0; kt < nkt; ++kt) {
    int kb = k0 + (kt << 6);
    {
      int gi = tid & 7;
      #pragma unroll
      for (int i = 0; i < 2; ++i) {
        int row = (tid >> 3) + (i << 6);
        uint4 v = *(const uint4*)&A[(long)(m0 + row) * K + kb + gi * 8];
        *(uint4*)&Ah[row * 64 + ((gi ^ (row & 7)) << 3)] = v;
      }
      int row = tid >> 3;
      long off = (long)(n0 + row) * K + kb + gi * 8;
      int la = row * 64 + ((gi ^ (row & 7)) << 3);
      *(uint4*)&Bh[la] = *(const uint4*)&Bhi[off];
      *(uint4*)&Bl[la] = *(const uint4*)&Blo[off];
    }
    __syncthreads();
    #pragma unroll
    for (int kk = 0; kk < 2; ++kk) {
      bf16x8 af[2], bhf[2], blf[2];
      #pragma unroll
      for (int mi = 0; mi < 2; ++mi) {
        int row = wm * 32 + mi * 16 + lrow;
        af[mi] = *(const bf16x8*)&Ah[row * 64 + ((((kk << 2) + g) ^ (row & 7)) << 3)];
      }
      #pragma unroll
      for (int ni = 0; ni < 2; ++ni) {
        int row = wn * 32 + ni * 16 + lrow;
        int col = (((kk << 2) + g) ^ (row & 7)) << 3;
        bhf[ni] = *(const bf16x8*)&Bh[row * 64 + col];
        blf[ni] = *(const bf16x8*)&Bl[row * 64 + col];
      }
      #pragma unroll
      for (int mi = 0; mi < 2; ++mi)
        #pragma unroll
        for (int ni = 0; ni < 2; ++ni) {
          acc[mi][ni] = __builtin_amdgcn_mfma_f32_16x16x32_bf16(af[mi], bhf[ni], acc[mi][ni], 0, 0, 0);
          acc[mi][ni] = __builtin_amdgcn_mfma_f32_16x16x32_bf16(af[mi], blf[ni], acc[mi][ni], 0, 0, 0);
        }
    }
    __syncthreads();
  }
  int r4 = lane >> 4;
  if (mode == 2) {
    bool xhalf = (n0 < 512);
    ushort* xcb = (ushort*)Cout;
    #pragma unroll
    for (int mi = 0; mi < 2; ++mi)
      #pragma unroll
      for (int ni = 0; ni < 2; ++ni) {
        int n = n0 + wn * 32 + ni * 16 + lrow;
        int mb = m0 + wm * 32 + mi * 16 + r4 * 4;
        int bb = mb >> 10, l = mb & 1023;
        if (xhalf) {
          uint2 o;
          o.x = packbf(acc[mi][ni][0], acc[mi][ni][1]);
          o.y = packbf(acc[mi][ni][2], acc[mi][ni][3]);
          *(uint2*)&xcb[((long)(bb * 512 + n)) * 1024 + l] = o;
        } else {
          #pragma unroll
          for (int r = 0; r < 4; ++r)
            C2[(long)(mb + r) * 512 + (n - 512)] = acc[mi][ni][r];
        }
      }
  } else {
    long zoff = (long)kz * M * N;
    #pragma unroll
    for (int mi = 0; mi < 2; ++mi)
      #pragma unroll
      for (int ni = 0; ni < 2; ++ni) {
        int n = n0 + wn * 32 + ni * 16 + lrow;
        int mb = m0 + wm * 32 + mi * 16 + r4 * 4;
        #pragma unroll
        for (int r = 0; r < 4; ++r)
          Cout[zoff + (long)(mb + r) * N + n] = acc[mi][ni][r];
      }
  }
}

// ---------------- MFMA x_dbl: xdbl[z] (1024,48) = xsT_bf[z] @ xproj[k]^T -----
__global__ __launch_bounds__(256) void mfma_x(
    const ushort* __restrict__ A, const ushort* __restrict__ Bhi,
    const ushort* __restrict__ Blo, float* __restrict__ xdbl)
{
  __shared__ __align__(16) ushort Ah[64 * 64];
  __shared__ __align__(16) ushort Bh[48 * 64];
  __shared__ __align__(16) ushort Bl[48 * 64];
  int tid = threadIdx.x;
  int m0 = blockIdx.x * 64;
  int z = blockIdx.y, k = z & 3;
  const ushort* Az = A + (long)z * 524288;
  const ushort* Bhz = Bhi + (long)k * 24576;
  const ushort* Blz = Blo + (long)k * 24576;
  int lane = tid & 63, wv = tid >> 6;
  int lrow = lane & 15, g = lane >> 4;
  f32x4 acc[3] = {};
  for (int kt = 0; kt < 8; ++kt) {
    int kb = kt << 6;
    #pragma unroll
    for (int i = 0; i < 2; ++i) {
      int idx = i * 256 + tid;
      int row = idx >> 3, gi = idx & 7;
      uint4 v = *(const uint4*)&Az[(long)(m0 + row) * 512 + kb + gi * 8];
      *(uint4*)&Ah[row * 64 + ((gi ^ (row & 7)) << 3)] = v;
      if (idx < 384) {
        long off = (long)row * 512 + kb + gi * 8;
        int la = row * 64 + ((gi ^ (row & 7)) << 3);
        *(uint4*)&Bh[la] = *(const uint4*)&Bhz[off];
        *(uint4*)&Bl[la] = *(const uint4*)&Blz[off];
      }
    }
    __syncthreads();
    #pragma unroll
    for (int kk = 0; kk < 2; ++kk) {
      int arow = wv * 16 + lrow;
      bf16x8 af = *(const bf16x8*)&Ah[arow * 64 + ((((kk << 2) + g) ^ (arow & 7)) << 3)];
      #pragma unroll
      for (int ni = 0; ni < 3; ++ni) {
        int brow = ni * 16 + lrow;
        int col = (((kk << 2) + g) ^ (brow & 7)) << 3;
        bf16x8 bh = *(const bf16x8*)&Bh[brow * 64 + col];
        bf16x8 bl = *(const bf16x8*)&Bl[brow * 64 + col];
        acc[ni] = __builtin_amdgcn_mfma_f32_16x16x32_bf16(af, bh, acc[ni], 0, 0, 0);
        acc[ni] = __builtin_amdgcn_mfma_f32_16x16x32_bf16(af, bl, acc[ni], 0, 0, 0);
      }
    }
    __syncthreads();
  }
  float* Cz = xdbl + (long)z * 49152;
  int r4 = lane >> 4;
  #pragma unroll
  for (int ni = 0; ni < 3; ++ni) {
    int n = ni * 16 + lrow;
    int mb = m0 + wv * 16 + r4 * 4;
    #pragma unroll
    for (int r = 0; r < 4; ++r)
      Cz[(long)(mb + r) * 48 + n] = acc[ni][r];
  }
}

// ---------------- reduce split-K partials: C (=/+=) sum_s P + bias ----------
__global__ __launch_bounds__(256) void reduce_split(const float* __restrict__ P,
    float* __restrict__ C, const float* __restrict__ bias,
    int MN, int N, int S, int accumulate) {
  int i = blockIdx.x * 256 + threadIdx.x;
  if (i * 4 >= MN) return;
  float4 v = make_float4(0.f, 0.f, 0.f, 0.f);
  for (int s = 0; s < S; ++s) {
    float4 p = *(const float4*)(P + (long)s * MN + i * 4);
    v.x += p.x; v.y += p.y; v.z += p.z; v.w += p.w;
  }
  if (bias) {
    float4 bv = *(const float4*)(bias + ((i * 4) & (N - 1)));
    v.x += bv.x; v.y += bv.y; v.z += bv.z; v.w += bv.w;
  }
  if (accumulate) {
    float4 o = *(const float4*)(C + (long)i * 4);
    v.x += o.x; v.y += o.y; v.z += o.z; v.w += o.w;
  }
  *(float4*)(C + (long)i * 4) = v;
}

// ---------------- block reduce helper (256 threads) ----------------
__device__ __forceinline__ float blk_sum(float v, float* sm) {
  #pragma unroll
  for (int o = 32; o > 0; o >>= 1) v += __shfl_down(v, o);
  int wid = threadIdx.x >> 6, lane = threadIdx.x & 63;
  __syncthreads();
  if (lane == 0) sm[wid] = v;
  __syncthreads();
  int nw = blockDim.x >> 6;
  float r = 0.f;
  for (int i = 0; i < nw; ++i) r += sm[i];
  return r;
}

// ------- fused: patch split-K reduce + bias -> t, then LN1 -> u (bf16) -------
__global__ __launch_bounds__(256) void reduce_ln1(const float* __restrict__ P,
    float* __restrict__ t, const float* __restrict__ bias,
    const float* __restrict__ g, const float* __restrict__ b,
    ushort* __restrict__ u) {
  __shared__ float sm[8];
  int m = blockIdx.x, c = threadIdx.x;
  float v = bias[c];
  #pragma unroll
  for (int s = 0; s < 8; ++s) v += P[(long)s * 524288 + m * 256 + c];
  t[(long)m * 256 + c] = v;
  float s1 = blk_sum(v, sm);
  float s2 = blk_sum(v * v, sm);
  float mu = s1 * (1.f / 256.f);
  float var = s2 * (1.f / 256.f) - mu * mu;
  float rs = rsqrtf(var + 1e-5f);
  u[(long)m * 256 + c] = bf16_rn((v - mu) * rs * g[c] + b[c]);
}

// ---------------- depthwise 3x3 + bias + silu (bf16 in/out) ----------------
__global__ __launch_bounds__(256) void dwconv_kernel(const ushort* __restrict__ xc,
    const float* __restrict__ cw, const float* __restrict__ cb, ushort* __restrict__ out) {
  __shared__ float plane[32][33];
  int d = blockIdx.x, b = blockIdx.y;
  long base = ((long)b * 512 + d) * 1024;
  int tid = threadIdx.x;
  uint2 v = *(const uint2*)&xc[base + tid * 4];
  int h0 = (tid * 4) >> 5, w0 = (tid * 4) & 31;
  plane[h0][w0 + 0] = bf2f(v.x & 0xffff); plane[h0][w0 + 1] = bf2f(v.x >> 16);
  plane[h0][w0 + 2] = bf2f(v.y & 0xffff); plane[h0][w0 + 3] = bf2f(v.y >> 16);
  float w9[9];
  #pragma unroll
  for (int i = 0; i < 9; ++i) w9[i] = cw[d * 9 + i];
  float bias = cb[d];
  __syncthreads();
  float o4[4];
  #pragma unroll
  for (int j = 0; j < 4; ++j) {
    int p = tid * 4 + j, h = p >> 5, w = p & 31;
    float acc = 0.f;
    #pragma unroll
    for (int dh = -1; dh <= 1; ++dh) {
      int hy = h + dh;
      if (hy < 0 || hy > 31) continue;
      #pragma unroll
      for (int dw = -1; dw <= 1; ++dw) {
        int wx = w + dw;
        if (wx < 0 || wx > 31) continue;
        acc += w9[(dh + 1) * 3 + (dw + 1)] * plane[hy][wx];
      }
    }
    acc += bias;
    o4[j] = acc / (1.f + __expf(-acc));  // silu
  }
  uint2 o2;
  o2.x = packbf(o4[0], o4[1]);
  o2.y = packbf(o4[2], o4[3]);
  *(uint2*)&out[base + tid * 4] = o2;
}

// --------- build xsT_bf (B,K,L,512) bf16 from xca_bf (B,512,32,32) -----------
__global__ __launch_bounds__(256) void build_xsT(const ushort* __restrict__ xca,
    ushort* __restrict__ xsTb) {
  __shared__ ushort tile[32][34];
  int h = blockIdx.x;
  int d0 = blockIdx.y * 32;
  int z = blockIdx.z;          // z = b*4 + k
  int b = z >> 2, k = z & 3;
  int tid = threadIdx.x;
  int a = tid >> 5, q = tid & 31;
  #pragma unroll
  for (int i = 0; i < 4; ++i) {
    int di = a + i * 8;
    tile[di][q] = xca[((long)(b * 512 + d0 + di)) * 1024 + h * 32 + q];
  }
  __syncthreads();
  #pragma unroll
  for (int i = 0; i < 4; ++i) {
    int w = a + i * 8;
    int r;
    if (k == 0) r = h * 32 + w;
    else if (k == 1) r = w * 32 + h;
    else if (k == 2) r = 1023 - (h * 32 + w);
    else r = 1023 - (w * 32 + h);
    xsTb[((long)z * 1024 + r) * 512 + d0 + q] = tile[q][w];
  }
}

// ------- chunk-parallel selective scan, NC=32, fused dt-projection ----------
// LC=32, 2 l-tiles of 16. Block 128 thr = 64 d x 2 n-halves, h[8] in VGPRs.
// dt computed in-kernel. Phase1 stores hp + dtsum (P recomputed in prefix).
// Grid (8 d-tiles, 32 chunks, 8 z).
template<bool FINAL>
__global__ __launch_bounds__(128) void scan_chunk6(
    const float* __restrict__ xdbl, ushort* xsb,
    const float* __restrict__ dtw, const float* __restrict__ dtb,
    const float* __restrict__ A_log, const float* __restrict__ Ds,
    float* __restrict__ dsum, float* __restrict__ hpb)
{
  __shared__ float sdt[32][64];       // 8KB: dt for whole chunk
  __shared__ float sxv[16][64];       // 4KB
  __shared__ float sy[16][64];        // 4KB; first 2KB aliased as sR during dt-calc
  __shared__ float sBC[32][32];       // 4KB: [l][n]: n<16 B, n>=16 C
  float (*sR)[16] = (float(*)[16])sy; // [32][16] R-slice of xdbl
  int tid = threadIdx.x;
  int dl = tid >> 1, ng = tid & 1;
  int d0 = blockIdx.x * 64;
  int d = d0 + dl;
  int c = blockIdx.y;              // 0..31
  int z = blockIdx.z;
  int k = z & 3;
  long baseD = (long)z * 524288;
  int l0 = c * 32;
  const float* xdz = xdbl + (long)z * 49152 + (long)l0 * 48;
  // stage B/C and R slices of xdbl
  #pragma unroll
  for (int i = 0; i < 2; ++i) {
    int idx = i * 128 + tid;
    int l = idx >> 3, q = idx & 7;
    *(float4*)&sBC[l][q * 4] = *(const float4*)(xdz + l * 48 + 16 + q * 4);
  }
  {
    int l = tid >> 2, q = tid & 3;
    *(float4*)&sR[l][q * 4] = *(const float4*)(xdz + l * 48 + q * 4);
  }
  float a[8], h[8];
  #pragma unroll
  for (int j = 0; j < 8; ++j) {
    a[j] = -__expf(A_log[((long)k * 512 + d) * 16 + ng * 8 + j]);
    h[j] = 0.f;
  }
  float4 wr0 = *(const float4*)(dtw + ((long)k * 512 + d) * 16);
  float4 wr1 = *(const float4*)(dtw + ((long)k * 512 + d) * 16 + 4);
  float4 wr2 = *(const float4*)(dtw + ((long)k * 512 + d) * 16 + 8);
  float4 wr3 = *(const float4*)(dtw + ((long)k * 512 + d) * 16 + 12);
  float dbias = dtb[k * 512 + d];
  int gbase = c * 65536 + z * 8192 + d * 16 + ng * 8;
  float Dv = 0.f;
  if (FINAL) {
    #pragma unroll
    for (int j = 0; j < 8; ++j) h[j] = hpb[gbase + j];   // h_in (prefix in-place)
    Dv = Ds[k * 512 + d];
  }
  __syncthreads();                 // sR ready
  // compute dt for this thread's 16 l rows (ng selects half)
  #pragma unroll
  for (int li = 0; li < 16; ++li) {
    int l = ng * 16 + li;
    const float* rr = &sR[l][0];
    float acc = dbias;
    acc += wr0.x * rr[0];  acc += wr0.y * rr[1];  acc += wr0.z * rr[2];  acc += wr0.w * rr[3];
    acc += wr1.x * rr[4];  acc += wr1.y * rr[5];  acc += wr1.z * rr[6];  acc += wr1.w * rr[7];
    acc += wr2.x * rr[8];  acc += wr2.y * rr[9];  acc += wr2.z * rr[10]; acc += wr2.w * rr[11];
    acc += wr3.x * rr[12]; acc += wr3.y * rr[13]; acc += wr3.z * rr[14]; acc += wr3.w * rr[15];
    sdt[l][dl] = (acc > 20.f) ? acc : __logf(1.f + __expf(acc));
  }
  __syncthreads();                 // sdt ready; sR dead -> sy writable
  int xli = tid >> 3;              // xv staging: 16 rows, 8 bf16/thread
  int xdj = (tid & 7) * 8;
  uint4 rxv = *(const uint4*)&xsb[baseD + (long)(l0 + xli) * 512 + d0 + xdj];
  float dtsum = 0.f;
  for (int t = 0; t < 2; ++t) {
    {
      float4 f0, f1;
      f0.x = bf2f(rxv.x & 0xffff); f0.y = bf2f(rxv.x >> 16);
      f0.z = bf2f(rxv.y & 0xffff); f0.w = bf2f(rxv.y >> 16);
      f1.x = bf2f(rxv.z & 0xffff); f1.y = bf2f(rxv.z >> 16);
      f1.z = bf2f(rxv.w & 0xffff); f1.w = bf2f(rxv.w >> 16);
      *(float4*)&sxv[xli][xdj] = f0;
      *(float4*)&sxv[xli][xdj + 4] = f1;
    }
    __syncthreads();
    if (t == 0)
      rxv = *(const uint4*)&xsb[baseD + (long)(l0 + 16 + xli) * 512 + d0 + xdj];
    #pragma unroll
    for (int li = 0; li < 16; ++li) {
      int lr = t * 16 + li;
      float dt = sdt[lr][dl];
      float xv = sxv[li][dl];
      float w = dt * xv;
      float4 B0 = *(const float4*)&sBC[lr][ng * 8];
      float4 B1 = *(const float4*)&sBC[lr][ng * 8 + 4];
      if (!FINAL) {
        dtsum += dt;
        h[0] = __expf(dt * a[0]) * h[0] + w * B0.x;
        h[1] = __expf(dt * a[1]) * h[1] + w * B0.y;
        h[2] = __expf(dt * a[2]) * h[2] + w * B0.z;
        h[3] = __expf(dt * a[3]) * h[3] + w * B0.w;
        h[4] = __expf(dt * a[4]) * h[4] + w * B1.x;
        h[5] = __expf(dt * a[5]) * h[5] + w * B1.y;
        h[6] = __expf(dt * a[6]) * h[6] + w * B1.z;
        h[7] = __expf(dt * a[7]) * h[7] + w * B1.w;
      } else {
        float4 C0 = *(const float4*)&sBC[lr][16 + ng * 8];
        float4 C1 = *(const float4*)&sBC[lr][16 + ng * 8 + 4];
        float p;
        h[0] = __expf(dt * a[0]) * h[0] + w * B0.x; p  = h[0] * C0.x;
        h[1] = __expf(dt * a[1]) * h[1] + w * B0.y; p += h[1] * C0.y;
        h[2] = __expf(dt * a[2]) * h[2] + w * B0.z; p += h[2] * C0.z;
        h[3] = __expf(dt * a[3]) * h[3] + w * B0.w; p += h[3] * C0.w;
        h[4] = __expf(dt * a[4]) * h[4] + w * B1.x; p += h[4] * C1.x;
        h[5] = __expf(dt * a[5]) * h[5] + w * B1.y; p += h[5] * C1.y;
        h[6] = __expf(dt * a[6]) * h[6] + w * B1.z; p += h[6] * C1.z;
        h[7] = __expf(dt * a[7]) * h[7] + w * B1.w; p += h[7] * C1.w;
        p += __shfl_xor(p, 1);
        if (ng == 0) sy[li][dl] = p + Dv * xv;
      }
    }
    __syncthreads();
    if (FINAL) {
      float4 f0 = *(float4*)&sy[xli][xdj];
      float4 f1 = *(float4*)&sy[xli][xdj + 4];
      uint4 o;
      o.x = packbf(f0.x, f0.y); o.y = packbf(f0.z, f0.w);
      o.z = packbf(f1.x, f1.y); o.w = packbf(f1.z, f1.w);
      *(uint4*)&xsb[baseD + (long)(l0 + t * 16 + xli) * 512 + d0 + xdj] = o;
    }
  }
  if (!FINAL) {
    *(float4*)(hpb + gbase)     = make_float4(h[0], h[1], h[2], h[3]);
    *(float4*)(hpb + gbase + 4) = make_float4(h[4], h[5], h[6], h[7]);
    if (ng == 0) dsum[c * 4096 + z * 512 + d] = dtsum;
  }
}

// prefix across the 32 chunks per (z,d,n); recomputes P=exp(dtsum*a);
// writes h_in in-place over hp
__global__ __launch_bounds__(256) void scan_prefix(const float* __restrict__ dsum,
    const float* __restrict__ A_log, float* __restrict__ hpb) {
  int g = blockIdx.x * 256 + threadIdx.x;   // (z,d,n)
  int z = g >> 13, n = g & 15;
  int d = (g >> 4) & 511;
  int k = z & 3;
  float a = -__expf(A_log[((long)k * 512 + d) * 16 + n]);
  float h = 0.f;
  #pragma unroll
  for (int c = 0; c < 32; ++c) {
    float P = __expf(dsum[c * 4096 + z * 512 + d] * a);
    float hp = hpb[c * 65536 + g];
    hpb[c * 65536 + g] = h;
    h = P * h + hp;
  }
}

// -------- fused: combine 4 directions (bf16) + LN over 512 + silu(z) --------
__global__ __launch_bounds__(256) void combine_ln2gate(const ushort* __restrict__ ys,
    const float* __restrict__ zb, ushort* __restrict__ out,
    const float* __restrict__ g, const float* __restrict__ b) {
  __shared__ float sm[8];
  int m = blockIdx.x, tid = threadIdx.x;
  int bb = m >> 10, l = m & 1023;
  int hh = l >> 5, w = l & 31;
  int lw = w * 32 + hh;
  long b4 = (long)bb * 4;
  uint u0 = *(const uint*)&ys[((b4 + 0) * 1024 + l) * 512 + tid * 2];
  uint u1 = *(const uint*)&ys[((b4 + 2) * 1024 + (1023 - l)) * 512 + tid * 2];
  uint u2 = *(const uint*)&ys[((b4 + 1) * 1024 + lw) * 512 + tid * 2];
  uint u3 = *(const uint*)&ys[((b4 + 3) * 1024 + (1023 - lw)) * 512 + tid * 2];
  float v0 = bf2f(u0 & 0xffff) + bf2f(u1 & 0xffff) + bf2f(u2 & 0xffff) + bf2f(u3 & 0xffff);
  float v1 = bf2f(u0 >> 16) + bf2f(u1 >> 16) + bf2f(u2 >> 16) + bf2f(u3 >> 16);
  float s1 = blk_sum(v0 + v1, sm);
  float s2 = blk_sum(v0 * v0 + v1 * v1, sm);
  float mu = s1 * (1.f / 512.f);
  float var = s2 * (1.f / 512.f) - mu * mu;
  float rs = rsqrtf(var + 1e-5f);
  float2 gg = *(const float2*)(g + tid * 2);
  float2 bbv = *(const float2*)(b + tid * 2);
  float2 zz = *(const float2*)(zb + (long)m * 512 + tid * 2);
  float y0 = ((v0 - mu) * rs * gg.x + bbv.x) * (zz.x / (1.f + __expf(-zz.x)));
  float y1 = ((v1 - mu) * rs * gg.y + bbv.y) * (zz.y / (1.f + __expf(-zz.y)));
  *(uint*)&out[(long)m * 512 + tid * 2] = packbf(y0, y1);
}

// ---------------- pooled head ----------------
__global__ __launch_bounds__(256) void head_partial(const float* __restrict__ t,
    const float* __restrict__ hw, float* __restrict__ part) {
  __shared__ float sm[8];
  int j = blockIdx.x, b = blockIdx.y;
  int c = threadIdx.x;
  float s = 0.f;
  for (int l = j * 64; l < j * 64 + 64; ++l) s += t[((long)b * 1024 + l) * 256 + c];
  s *= hw[c];
  float tot = blk_sum(s, sm);
  if (c == 0) part[b * 16 + j] = tot;
}

__global__ void head_final(const float* __restrict__ part, const float* __restrict__ hb, float* __restrict__ out) {
  int tid = threadIdx.x;
  float v = (tid < 32) ? part[tid] : 0.f;
  #pragma unroll
  for (int o = 1; o < 16; o <<= 1) v += __shfl_xor(v, o);
  if (tid < 32 && (tid & 15) == 0) out[tid >> 4] = v * (1.f / 1024.f) + hb[0];
}

extern "C" void kernel_launch(void* const* d_in, const int* in_sizes, int n_in,
                              void* d_out, int out_size, void* d_ws, size_t ws_size,
                              hipStream_t stream) {
  const float* x       = (const float*)d_in[0];
  const float* patch_w = (const float*)d_in[1];
  const float* patch_b = (const float*)d_in[2];
  const float* ln_g    = (const float*)d_in[3];
  const float* ln_b    = (const float*)d_in[4];
  const float* in_w    = (const float*)d_in[5];
  const float* conv_w  = (const float*)d_in[6];
  const float* conv_b  = (const float*)d_in[7];
  const float* xproj_w = (const float*)d_in[8];
  const float* dt_w    = (const float*)d_in[9];
  const float* dt_b    = (const float*)d_in[10];
  const float* A_log   = (const float*)d_in[11];
  const float* Ds      = (const float*)d_in[12];
  const float* on_g    = (const float*)d_in[13];
  const float* on_b    = (const float*)d_in[14];
  const float* out_w   = (const float*)d_in[15];
  const float* head_w  = (const float*)d_in[16];
  const float* head_b  = (const float*)d_in[17];

  float* ws = (float*)d_ws;
  float* t_buf   = ws;                    // 2048*256
  float* u_buf   = t_buf + 524288;        // 2048*256   (u_bf16 overlay)
  float* xz_buf  = u_buf + 524288;        // pw splits overlay; later z_buf
  float* xc_buf  = xz_buf + 2097152;      // xc_bf overlay (2048*512 us)
  float* xca_buf = xc_buf + 1048576;      // xca_bf overlay; later y_bf overlay
  float* xsT_buf = xca_buf + 1048576;     // A_p overlay (dead after patch mfma)
  float* xdbl_buf= xsT_buf + 4194304;     // 8*1024*48
  float* spl_buf = xdbl_buf + 393216;     // P_patch / P_out overlay (16 MB)
  float* part_buf= spl_buf + 4194304;     // 32
  float* tail    = part_buf + 32;
  // overlays:
  ushort* A_p    = (ushort*)xsT_buf;                // 2048*4096 us
  ushort* pw_hi  = (ushort*)xz_buf;                 // 1048576 us
  ushort* pw_lo  = (ushort*)(xz_buf + 524288);      // 1048576 us
  float*  z_buf  = xz_buf;                          // 2048*512 f (after patch mfma)
  float*  P_patch= spl_buf;                         // 8*524288 f
  float*  P_out  = spl_buf;                         // 4*524288 f
  ushort* u_bf   = (ushort*)u_buf;                  // 2048*256 us
  ushort* xc_bf  = (ushort*)xc_buf;                 // 2048*512 us
  ushort* xca_bf = (ushort*)xca_buf;                // 2*512*1024 us
  ushort* y_bf   = (ushort*)xca_buf;                // 2048*512 us (after build_xsT)
  // tail: weight splits, xsT bf16, scan dtsum/hp
  ushort* iw_hi  = (ushort*)tail;                   // 262144 us
  ushort* iw_lo  = (ushort*)(tail + 131072);
  ushort* ow_hi  = (ushort*)(tail + 262144);        // 131072 us
  ushort* ow_lo  = (ushort*)(tail + 327680);
  ushort* xw_hi  = (ushort*)(tail + 393216);        // 98304 us
  ushort* xw_lo  = (ushort*)(tail + 442368);
  ushort* xsT_bf = (ushort*)(tail + 491520);        // 4194304 us
  float*  dsum_buf = tail + 2588672;                // 131072 f
  float*  hp_buf   = tail + 2719744;                // 2097152 f

  // 0. fused prep: im2col A + all weight hi/lo splits
  prep_kernel<<<8065, 256, 0, stream>>>(x, A_p, patch_w, in_w, out_w, xproj_w,
      pw_hi, pw_lo, iw_hi, iw_lo, ow_hi, ow_lo, xw_hi, xw_lo);
  // 1. patch embed MFMA, split-K=8 -> partials (n-major XCD-local decode)
  mfma_bf<<<512, 512, 0, stream>>>(A_p, pw_hi, pw_lo, P_patch, nullptr,
      2048, 256, 4096, 512, 0, 16, 8);
  // 2. fused reduce + bias -> t, LN1 -> u (bf16)
  reduce_ln1<<<2048, 256, 0, stream>>>(P_patch, t_buf, patch_b, ln_g, ln_b, u_bf);
  // 3. in-proj MFMA fused epilogue: xc (transposed bf16) + z (f32)
  mfma_bf<<<256, 512, 0, stream>>>(u_bf, iw_hi, iw_lo, xc_buf, z_buf,
      2048, 1024, 256, 256, 2, 16, 1);
  // 4. depthwise conv + silu -> xca (bf16)
  dwconv_kernel<<<dim3(512, 2), 256, 0, stream>>>(xc_bf, conv_w, conv_b, xca_bf);
  // 5. build xsT (bf16, 4 directions)
  build_xsT<<<dim3(32, 16, 8), 256, 0, stream>>>(xca_bf, xsT_bf);
  // 6. x_dbl[z] (1024,48) = xsT_bf[z] @ xproj[k]^T (MFMA)
  mfma_x<<<dim3(16, 8), 256, 0, stream>>>(xsT_bf, xw_hi, xw_lo, xdbl_buf);
  // 7. chunk-parallel selective scan (NC=32, fused dt-projection)
  scan_chunk6<false><<<dim3(8, 32, 8), 128, 0, stream>>>(xdbl_buf, xsT_bf,
      dt_w, dt_b, A_log, Ds, dsum_buf, hp_buf);
  scan_prefix<<<256, 256, 0, stream>>>(dsum_buf, A_log, hp_buf);
  scan_chunk6<true><<<dim3(8, 32, 8), 128, 0, stream>>>(xdbl_buf, xsT_bf,
      dt_w, dt_b, A_log, Ds, nullptr, hp_buf);
  // 8. fused combine + LN2 + silu gate -> y_bf16
  combine_ln2gate<<<2048, 256, 0, stream>>>(xsT_bf, z_buf, y_bf, on_g, on_b);
  // 9. t += y @ out_w^T (MFMA split-K=4, n-major decode)
  mfma_bf<<<256, 512, 0, stream>>>(y_bf, ow_hi, ow_lo, P_out, nullptr,
      2048, 256, 512, 128, 0, 16, 4);
  reduce_split<<<512, 256, 0, stream>>>(P_out, t_buf, nullptr, 524288, 256, 4, 1);
  // 10. pooled head
  head_partial<<<dim3(16, 2), 256, 0, stream>>>(t_buf, head_w, part_buf);
  head_final<<<1, 64, 0, stream>>>(part_buf, head_b, (float*)d_out);
}

// Round 11
// 127.778 us; speedup vs baseline: 6.3285x; 1.0429x over previous
//
#include <hip/hip_runtime.h>
#include <math.h>

// VMamba discriminator forward. GEMMs: bf16 MFMA (patch: hi-only weights;
// others: hi/lo split), activations bf16-hi, fp32 accum, XCD-local n-major
// block decode. Scan: chunk-parallel NC=32, states in regs, fused dt-proj,
// dtsum-compressed prefix; xs/ys/xc pipeline bf16. Head folded into reduces.
// B=2, C=256, IMG=128, P=4 -> H=W=32, L=1024, D_INNER=512, N=16, R=16, K=4

typedef __attribute__((ext_vector_type(4))) float f32x4;
typedef __attribute__((ext_vector_type(8))) short bf16x8;

__device__ __forceinline__ ushort bf16_rn(float f) {
  uint u = __float_as_uint(f);
  return (ushort)((u + 0x7fffu + ((u >> 16) & 1u)) >> 16);
}
__device__ __forceinline__ float bf2f(uint us) { return __uint_as_float(us << 16); }
__device__ __forceinline__ uint packbf(float a, float b) {
  return (uint)bf16_rn(a) | ((uint)bf16_rn(b) << 16);
}

// ------ fused prep: im2col (blocks 0..2047) + weight splits (rest) ----------
__global__ __launch_bounds__(256) void prep_kernel(const float* __restrict__ x,
    ushort* __restrict__ Ap,
    const float* __restrict__ pw, const float* __restrict__ iw,
    const float* __restrict__ ow, const float* __restrict__ xw,
    ushort* __restrict__ pwh,
    ushort* __restrict__ iwh, ushort* __restrict__ iwl,
    ushort* __restrict__ owh, ushort* __restrict__ owl,
    ushort* __restrict__ xwh, ushort* __restrict__ xwl) {
  int bid = blockIdx.x;
  int tid = threadIdx.x;
  if (bid < 2048) {
    __shared__ __align__(16) ushort tile[32][136];
    int b = bid >> 10, hh = (bid >> 5) & 31, c0 = (bid & 31) * 8;
    int ci = tid >> 5, ph = (tid >> 3) & 3, w4 = tid & 7;
    const float* src = x + (((long)(b * 256 + c0 + ci) * 128 + 4 * hh + ph) * 128 + 16 * w4);
    #pragma unroll
    for (int j = 0; j < 4; ++j) {
      float4 v = *(const float4*)(src + 4 * j);
      uint2 pk;
      pk.x = packbf(v.x, v.y);
      pk.y = packbf(v.z, v.w);
      *(uint2*)&tile[w4 * 4 + j][ci * 16 + ph * 4] = pk;
    }
    __syncthreads();
    int w = tid >> 3;
    long rowbase = ((long)(b * 1024 + hh * 32 + w)) * 4096 + c0 * 16;
    #pragma unroll
    for (int i = 0; i < 2; ++i) {
      int gr = (tid & 7) + 8 * i;
      *(uint4*)&Ap[rowbase + gr * 8] = *(const uint4*)&tile[w][gr * 8];
    }
  } else {
    int i = (bid - 2048) * 256 + tid;
    if (i < 1048576) {               // patch weights: hi only
      pwh[i] = bf16_rn(pw[i]);
      return;
    }
    const float* src; ushort* hi; ushort* lo; int off;
    if (i < 1310720)      { src = iw; hi = iwh; lo = iwl; off = i - 1048576; }
    else if (i < 1441792) { src = ow; hi = owh; lo = owl; off = i - 1310720; }
    else if (i < 1540096) { src = xw; hi = xwh; lo = xwl; off = i - 1441792; }
    else return;
    float f = src[off];
    ushort h = bf16_rn(f);
    hi[off] = h;
    lo[off] = bf16_rn(f - __uint_as_float(((uint)h) << 16));
  }
}

// ---------------- MFMA NT GEMM (bf16 A, hi[/lo] bf16 B, fp32 out) ------------
// 1D grid, n-major decode: id = n*NBM*NBZ + m*NBZ + z (XCD-local A reuse).
// mode 0: split-K partials. mode 2: in-proj fused epilogue (xc bf16 + z f32).
__global__ __launch_bounds__(512) void mfma_bf(
    const ushort* __restrict__ A, const ushort* __restrict__ Bhi,
    const ushort* __restrict__ Blo, float* __restrict__ Cout, float* __restrict__ C2,
    int M, int N, int K, int kchunk, int mode, int NBM, int NBZ, int uselo)
{
  __shared__ __align__(16) ushort Ah[128 * 64];
  __shared__ __align__(16) ushort Bh[64 * 64];
  __shared__ __align__(16) ushort Bl[64 * 64];
  int tid = threadIdx.x;
  int bid = blockIdx.x;
  int kz = bid % NBZ;
  int n0 = (bid / (NBZ * NBM)) * 64;
  int m0 = ((bid / NBZ) % NBM) * 128;
  int k0 = kz * kchunk;
  int wid = tid >> 6, lane = tid & 63;
  int wm = wid >> 1, wn = wid & 1;
  int lrow = lane & 15, g = lane >> 4;
  f32x4 acc[2][2] = {};
  int nkt = kchunk >> 6;
  for (int kt = 0; kt < nkt; ++kt) {
    int kb = k0 + (kt << 6);
    {
      int gi = tid & 7;
      #pragma unroll
      for (int i = 0; i < 2; ++i) {
        int row = (tid >> 3) + (i << 6);
        uint4 v = *(const uint4*)&A[(long)(m0 + row) * K + kb + gi * 8];
        *(uint4*)&Ah[row * 64 + ((gi ^ (row & 7)) << 3)] = v;
      }
      int row = tid >> 3;
      long off = (long)(n0 + row) * K + kb + gi * 8;
      int la = row * 64 + ((gi ^ (row & 7)) << 3);
      *(uint4*)&Bh[la] = *(const uint4*)&Bhi[off];
      if (uselo) *(uint4*)&Bl[la] = *(const uint4*)&Blo[off];
    }
    __syncthreads();
    #pragma unroll
    for (int kk = 0; kk < 2; ++kk) {
      bf16x8 af[2], bhf[2];
      #pragma unroll
      for (int mi = 0; mi < 2; ++mi) {
        int row = wm * 32 + mi * 16 + lrow;
        af[mi] = *(const bf16x8*)&Ah[row * 64 + ((((kk << 2) + g) ^ (row & 7)) << 3)];
      }
      #pragma unroll
      for (int ni = 0; ni < 2; ++ni) {
        int row = wn * 32 + ni * 16 + lrow;
        int col = (((kk << 2) + g) ^ (row & 7)) << 3;
        bhf[ni] = *(const bf16x8*)&Bh[row * 64 + col];
      }
      #pragma unroll
      for (int mi = 0; mi < 2; ++mi)
        #pragma unroll
        for (int ni = 0; ni < 2; ++ni)
          acc[mi][ni] = __builtin_amdgcn_mfma_f32_16x16x32_bf16(af[mi], bhf[ni], acc[mi][ni], 0, 0, 0);
      if (uselo) {
        #pragma unroll
        for (int ni = 0; ni < 2; ++ni) {
          int row = wn * 32 + ni * 16 + lrow;
          int col = (((kk << 2) + g) ^ (row & 7)) << 3;
          bf16x8 blf = *(const bf16x8*)&Bl[row * 64 + col];
          #pragma unroll
          for (int mi = 0; mi < 2; ++mi)
            acc[mi][ni] = __builtin_amdgcn_mfma_f32_16x16x32_bf16(af[mi], blf, acc[mi][ni], 0, 0, 0);
        }
      }
    }
    __syncthreads();
  }
  int r4 = lane >> 4;
  if (mode == 2) {
    bool xhalf = (n0 < 512);
    ushort* xcb = (ushort*)Cout;
    #pragma unroll
    for (int mi = 0; mi < 2; ++mi)
      #pragma unroll
      for (int ni = 0; ni < 2; ++ni) {
        int n = n0 + wn * 32 + ni * 16 + lrow;
        int mb = m0 + wm * 32 + mi * 16 + r4 * 4;
        int bb = mb >> 10, l = mb & 1023;
        if (xhalf) {
          uint2 o;
          o.x = packbf(acc[mi][ni][0], acc[mi][ni][1]);
          o.y = packbf(acc[mi][ni][2], acc[mi][ni][3]);
          *(uint2*)&xcb[((long)(bb * 512 + n)) * 1024 + l] = o;
        } else {
          #pragma unroll
          for (int r = 0; r < 4; ++r)
            C2[(long)(mb + r) * 512 + (n - 512)] = acc[mi][ni][r];
        }
      }
  } else {
    long zoff = (long)kz * M * N;
    #pragma unroll
    for (int mi = 0; mi < 2; ++mi)
      #pragma unroll
      for (int ni = 0; ni < 2; ++ni) {
        int n = n0 + wn * 32 + ni * 16 + lrow;
        int mb = m0 + wm * 32 + mi * 16 + r4 * 4;
        #pragma unroll
        for (int r = 0; r < 4; ++r)
          Cout[zoff + (long)(mb + r) * N + n] = acc[mi][ni][r];
      }
  }
}

// ---------------- MFMA x_dbl: xdbl[z] (1024,48) = xsT_bf[z] @ xproj[k]^T -----
__global__ __launch_bounds__(256) void mfma_x(
    const ushort* __restrict__ A, const ushort* __restrict__ Bhi,
    const ushort* __restrict__ Blo, float* __restrict__ xdbl)
{
  __shared__ __align__(16) ushort Ah[64 * 64];
  __shared__ __align__(16) ushort Bh[48 * 64];
  __shared__ __align__(16) ushort Bl[48 * 64];
  int tid = threadIdx.x;
  int m0 = blockIdx.x * 64;
  int z = blockIdx.y, k = z & 3;
  const ushort* Az = A + (long)z * 524288;
  const ushort* Bhz = Bhi + (long)k * 24576;
  const ushort* Blz = Blo + (long)k * 24576;
  int lane = tid & 63, wv = tid >> 6;
  int lrow = lane & 15, g = lane >> 4;
  f32x4 acc[3] = {};
  for (int kt = 0; kt < 8; ++kt) {
    int kb = kt << 6;
    #pragma unroll
    for (int i = 0; i < 2; ++i) {
      int idx = i * 256 + tid;
      int row = idx >> 3, gi = idx & 7;
      uint4 v = *(const uint4*)&Az[(long)(m0 + row) * 512 + kb + gi * 8];
      *(uint4*)&Ah[row * 64 + ((gi ^ (row & 7)) << 3)] = v;
      if (idx < 384) {
        long off = (long)row * 512 + kb + gi * 8;
        int la = row * 64 + ((gi ^ (row & 7)) << 3);
        *(uint4*)&Bh[la] = *(const uint4*)&Bhz[off];
        *(uint4*)&Bl[la] = *(const uint4*)&Blz[off];
      }
    }
    __syncthreads();
    #pragma unroll
    for (int kk = 0; kk < 2; ++kk) {
      int arow = wv * 16 + lrow;
      bf16x8 af = *(const bf16x8*)&Ah[arow * 64 + ((((kk << 2) + g) ^ (arow & 7)) << 3)];
      #pragma unroll
      for (int ni = 0; ni < 3; ++ni) {
        int brow = ni * 16 + lrow;
        int col = (((kk << 2) + g) ^ (brow & 7)) << 3;
        bf16x8 bh = *(const bf16x8*)&Bh[brow * 64 + col];
        bf16x8 bl = *(const bf16x8*)&Bl[brow * 64 + col];
        acc[ni] = __builtin_amdgcn_mfma_f32_16x16x32_bf16(af, bh, acc[ni], 0, 0, 0);
        acc[ni] = __builtin_amdgcn_mfma_f32_16x16x32_bf16(af, bl, acc[ni], 0, 0, 0);
      }
    }
    __syncthreads();
  }
  float* Cz = xdbl + (long)z * 49152;
  int r4 = lane >> 4;
  #pragma unroll
  for (int ni = 0; ni < 3; ++ni) {
    int n = ni * 16 + lrow;
    int mb = m0 + wv * 16 + r4 * 4;
    #pragma unroll
    for (int r = 0; r < 4; ++r)
      Cz[(long)(mb + r) * 48 + n] = acc[ni][r];
  }
}

// ---------------- block reduce helper (256 threads) ----------------
__device__ __forceinline__ float blk_sum(float v, float* sm) {
  #pragma unroll
  for (int o = 32; o > 0; o >>= 1) v += __shfl_down(v, o);
  int wid = threadIdx.x >> 6, lane = threadIdx.x & 63;
  __syncthreads();
  if (lane == 0) sm[wid] = v;
  __syncthreads();
  int nw = blockDim.x >> 6;
  float r = 0.f;
  for (int i = 0; i < nw; ++i) r += sm[i];
  return r;
}

// -- fused: patch split-K reduce + bias -> LN1 -> u (bf16); t never stored; --
// -- head partial tpart[m] = sum_c t[m,c]*hw[c] ------------------------------
__global__ __launch_bounds__(256) void reduce_ln1(const float* __restrict__ P,
    const float* __restrict__ bias, const float* __restrict__ g,
    const float* __restrict__ b, ushort* __restrict__ u,
    const float* __restrict__ hw, float* __restrict__ tpart) {
  __shared__ float sm[8];
  int m = blockIdx.x, c = threadIdx.x;
  float v = bias[c];
  #pragma unroll
  for (int s = 0; s < 8; ++s) v += P[(long)s * 524288 + m * 256 + c];
  float s1 = blk_sum(v, sm);
  float s2 = blk_sum(v * v, sm);
  float s3 = blk_sum(v * hw[c], sm);
  if (c == 0) tpart[m] = s3;
  float mu = s1 * (1.f / 256.f);
  float var = s2 * (1.f / 256.f) - mu * mu;
  float rs = rsqrtf(var + 1e-5f);
  u[(long)m * 256 + c] = bf16_rn((v - mu) * rs * g[c] + b[c]);
}

// -- out-proj split-K reduce fused with head dot: spart[bid] = sum ss*hw -----
__global__ __launch_bounds__(256) void reduce_ss(const float* __restrict__ P,
    const float* __restrict__ hw, float* __restrict__ spart) {
  __shared__ float sm[8];
  int bid = blockIdx.x;                       // 512 blocks x 1024 elems
  int i = bid * 1024 + threadIdx.x * 4;       // element; c = i & 255
  float4 v = make_float4(0.f, 0.f, 0.f, 0.f);
  #pragma unroll
  for (int s = 0; s < 4; ++s) {
    float4 p = *(const float4*)(P + (long)s * 524288 + i);
    v.x += p.x; v.y += p.y; v.z += p.z; v.w += p.w;
  }
  float4 w = *(const float4*)(hw + (i & 255));
  float s = v.x * w.x + v.y * w.y + v.z * w.z + v.w * w.w;
  float tot = blk_sum(s, sm);
  if (threadIdx.x == 0) spart[bid] = tot;
}

// ---------------- head final: sum partials per batch ----------------
__global__ __launch_bounds__(256) void head_final(const float* __restrict__ tpart,
    const float* __restrict__ spart, const float* __restrict__ hb,
    float* __restrict__ out) {
  __shared__ float sm[8];
  int b = blockIdx.x, tid = threadIdx.x;
  float s = 0.f;
  #pragma unroll
  for (int j = 0; j < 4; ++j) s += tpart[b * 1024 + tid * 4 + j];
  s += spart[b * 256 + tid];
  float tot = blk_sum(s, sm);
  if (tid == 0) out[b] = tot * (1.f / 1024.f) + hb[0];
}

// ---------------- depthwise 3x3 + bias + silu (bf16 in/out) ----------------
__global__ __launch_bounds__(256) void dwconv_kernel(const ushort* __restrict__ xc,
    const float* __restrict__ cw, const float* __restrict__ cb, ushort* __restrict__ out) {
  __shared__ float plane[32][33];
  int d = blockIdx.x, b = blockIdx.y;
  long base = ((long)b * 512 + d) * 1024;
  int tid = threadIdx.x;
  uint2 v = *(const uint2*)&xc[base + tid * 4];
  int h0 = (tid * 4) >> 5, w0 = (tid * 4) & 31;
  plane[h0][w0 + 0] = bf2f(v.x & 0xffff); plane[h0][w0 + 1] = bf2f(v.x >> 16);
  plane[h0][w0 + 2] = bf2f(v.y & 0xffff); plane[h0][w0 + 3] = bf2f(v.y >> 16);
  float w9[9];
  #pragma unroll
  for (int i = 0; i < 9; ++i) w9[i] = cw[d * 9 + i];
  float bias = cb[d];
  __syncthreads();
  float o4[4];
  #pragma unroll
  for (int j = 0; j < 4; ++j) {
    int p = tid * 4 + j, h = p >> 5, w = p & 31;
    float acc = 0.f;
    #pragma unroll
    for (int dh = -1; dh <= 1; ++dh) {
      int hy = h + dh;
      if (hy < 0 || hy > 31) continue;
      #pragma unroll
      for (int dw = -1; dw <= 1; ++dw) {
        int wx = w + dw;
        if (wx < 0 || wx > 31) continue;
        acc += w9[(dh + 1) * 3 + (dw + 1)] * plane[hy][wx];
      }
    }
    acc += bias;
    o4[j] = acc / (1.f + __expf(-acc));  // silu
  }
  uint2 o2;
  o2.x = packbf(o4[0], o4[1]);
  o2.y = packbf(o4[2], o4[3]);
  *(uint2*)&out[base + tid * 4] = o2;
}

// --------- build xsT_bf (B,K,L,512) bf16 from xca_bf (B,512,32,32) -----------
__global__ __launch_bounds__(256) void build_xsT(const ushort* __restrict__ xca,
    ushort* __restrict__ xsTb) {
  __shared__ ushort tile[32][34];
  int h = blockIdx.x;
  int d0 = blockIdx.y * 32;
  int z = blockIdx.z;          // z = b*4 + k
  int b = z >> 2, k = z & 3;
  int tid = threadIdx.x;
  int a = tid >> 5, q = tid & 31;
  #pragma unroll
  for (int i = 0; i < 4; ++i) {
    int di = a + i * 8;
    tile[di][q] = xca[((long)(b * 512 + d0 + di)) * 1024 + h * 32 + q];
  }
  __syncthreads();
  #pragma unroll
  for (int i = 0; i < 4; ++i) {
    int w = a + i * 8;
    int r;
    if (k == 0) r = h * 32 + w;
    else if (k == 1) r = w * 32 + h;
    else if (k == 2) r = 1023 - (h * 32 + w);
    else r = 1023 - (w * 32 + h);
    xsTb[((long)z * 1024 + r) * 512 + d0 + q] = tile[q][w];
  }
}

// ------- chunk-parallel selective scan, NC=32, fused dt-projection ----------
template<bool FINAL>
__global__ __launch_bounds__(128) void scan_chunk6(
    const float* __restrict__ xdbl, ushort* xsb,
    const float* __restrict__ dtw, const float* __restrict__ dtb,
    const float* __restrict__ A_log, const float* __restrict__ Ds,
    float* __restrict__ dsum, float* __restrict__ hpb)
{
  __shared__ float sdt[32][64];
  __shared__ float sxv[16][64];
  __shared__ float sy[16][64];        // first 2KB aliased as sR during dt-calc
  __shared__ float sBC[32][32];
  float (*sR)[16] = (float(*)[16])sy;
  int tid = threadIdx.x;
  int dl = tid >> 1, ng = tid & 1;
  int d0 = blockIdx.x * 64;
  int d = d0 + dl;
  int c = blockIdx.y;
  int z = blockIdx.z;
  int k = z & 3;
  long baseD = (long)z * 524288;
  int l0 = c * 32;
  const float* xdz = xdbl + (long)z * 49152 + (long)l0 * 48;
  #pragma unroll
  for (int i = 0; i < 2; ++i) {
    int idx = i * 128 + tid;
    int l = idx >> 3, q = idx & 7;
    *(float4*)&sBC[l][q * 4] = *(const float4*)(xdz + l * 48 + 16 + q * 4);
  }
  {
    int l = tid >> 2, q = tid & 3;
    *(float4*)&sR[l][q * 4] = *(const float4*)(xdz + l * 48 + q * 4);
  }
  float a[8], h[8];
  #pragma unroll
  for (int j = 0; j < 8; ++j) {
    a[j] = -__expf(A_log[((long)k * 512 + d) * 16 + ng * 8 + j]);
    h[j] = 0.f;
  }
  float4 wr0 = *(const float4*)(dtw + ((long)k * 512 + d) * 16);
  float4 wr1 = *(const float4*)(dtw + ((long)k * 512 + d) * 16 + 4);
  float4 wr2 = *(const float4*)(dtw + ((long)k * 512 + d) * 16 + 8);
  float4 wr3 = *(const float4*)(dtw + ((long)k * 512 + d) * 16 + 12);
  float dbias = dtb[k * 512 + d];
  int gbase = c * 65536 + z * 8192 + d * 16 + ng * 8;
  float Dv = 0.f;
  if (FINAL) {
    #pragma unroll
    for (int j = 0; j < 8; ++j) h[j] = hpb[gbase + j];
    Dv = Ds[k * 512 + d];
  }
  __syncthreads();
  #pragma unroll
  for (int li = 0; li < 16; ++li) {
    int l = ng * 16 + li;
    const float* rr = &sR[l][0];
    float acc = dbias;
    acc += wr0.x * rr[0];  acc += wr0.y * rr[1];  acc += wr0.z * rr[2];  acc += wr0.w * rr[3];
    acc += wr1.x * rr[4];  acc += wr1.y * rr[5];  acc += wr1.z * rr[6];  acc += wr1.w * rr[7];
    acc += wr2.x * rr[8];  acc += wr2.y * rr[9];  acc += wr2.z * rr[10]; acc += wr2.w * rr[11];
    acc += wr3.x * rr[12]; acc += wr3.y * rr[13]; acc += wr3.z * rr[14]; acc += wr3.w * rr[15];
    sdt[l][dl] = (acc > 20.f) ? acc : __logf(1.f + __expf(acc));
  }
  __syncthreads();
  int xli = tid >> 3;
  int xdj = (tid & 7) * 8;
  uint4 rxv = *(const uint4*)&xsb[baseD + (long)(l0 + xli) * 512 + d0 + xdj];
  float dtsum = 0.f;
  for (int t = 0; t < 2; ++t) {
    {
      float4 f0, f1;
      f0.x = bf2f(rxv.x & 0xffff); f0.y = bf2f(rxv.x >> 16);
      f0.z = bf2f(rxv.y & 0xffff); f0.w = bf2f(rxv.y >> 16);
      f1.x = bf2f(rxv.z & 0xffff); f1.y = bf2f(rxv.z >> 16);
      f1.z = bf2f(rxv.w & 0xffff); f1.w = bf2f(rxv.w >> 16);
      *(float4*)&sxv[xli][xdj] = f0;
      *(float4*)&sxv[xli][xdj + 4] = f1;
    }
    __syncthreads();
    if (t == 0)
      rxv = *(const uint4*)&xsb[baseD + (long)(l0 + 16 + xli) * 512 + d0 + xdj];
    #pragma unroll
    for (int li = 0; li < 16; ++li) {
      int lr = t * 16 + li;
      float dt = sdt[lr][dl];
      float xv = sxv[li][dl];
      float w = dt * xv;
      float4 B0 = *(const float4*)&sBC[lr][ng * 8];
      float4 B1 = *(const float4*)&sBC[lr][ng * 8 + 4];
      if (!FINAL) {
        dtsum += dt;
        h[0] = __expf(dt * a[0]) * h[0] + w * B0.x;
        h[1] = __expf(dt * a[1]) * h[1] + w * B0.y;
        h[2] = __expf(dt * a[2]) * h[2] + w * B0.z;
        h[3] = __expf(dt * a[3]) * h[3] + w * B0.w;
        h[4] = __expf(dt * a[4]) * h[4] + w * B1.x;
        h[5] = __expf(dt * a[5]) * h[5] + w * B1.y;
        h[6] = __expf(dt * a[6]) * h[6] + w * B1.z;
        h[7] = __expf(dt * a[7]) * h[7] + w * B1.w;
      } else {
        float4 C0 = *(const float4*)&sBC[lr][16 + ng * 8];
        float4 C1 = *(const float4*)&sBC[lr][16 + ng * 8 + 4];
        float p;
        h[0] = __expf(dt * a[0]) * h[0] + w * B0.x; p  = h[0] * C0.x;
        h[1] = __expf(dt * a[1]) * h[1] + w * B0.y; p += h[1] * C0.y;
        h[2] = __expf(dt * a[2]) * h[2] + w * B0.z; p += h[2] * C0.z;
        h[3] = __expf(dt * a[3]) * h[3] + w * B0.w; p += h[3] * C0.w;
        h[4] = __expf(dt * a[4]) * h[4] + w * B1.x; p += h[4] * C1.x;
        h[5] = __expf(dt * a[5]) * h[5] + w * B1.y; p += h[5] * C1.y;
        h[6] = __expf(dt * a[6]) * h[6] + w * B1.z; p += h[6] * C1.z;
        h[7] = __expf(dt * a[7]) * h[7] + w * B1.w; p += h[7] * C1.w;
        p += __shfl_xor(p, 1);
        if (ng == 0) sy[li][dl] = p + Dv * xv;
      }
    }
    __syncthreads();
    if (FINAL) {
      float4 f0 = *(float4*)&sy[xli][xdj];
      float4 f1 = *(float4*)&sy[xli][xdj + 4];
      uint4 o;
      o.x = packbf(f0.x, f0.y); o.y = packbf(f0.z, f0.w);
      o.z = packbf(f1.x, f1.y); o.w = packbf(f1.z, f1.w);
      *(uint4*)&xsb[baseD + (long)(l0 + t * 16 + xli) * 512 + d0 + xdj] = o;
    }
  }
  if (!FINAL) {
    *(float4*)(hpb + gbase)     = make_float4(h[0], h[1], h[2], h[3]);
    *(float4*)(hpb + gbase + 4) = make_float4(h[4], h[5], h[6], h[7]);
    if (ng == 0) dsum[c * 4096 + z * 512 + d] = dtsum;
  }
}

// prefix across the 32 chunks per (z,d,n); recomputes P=exp(dtsum*a)
__global__ __launch_bounds__(256) void scan_prefix(const float* __restrict__ dsum,
    const float* __restrict__ A_log, float* __restrict__ hpb) {
  int g = blockIdx.x * 256 + threadIdx.x;   // (z,d,n)
  int z = g >> 13, n = g & 15;
  int d = (g >> 4) & 511;
  int k = z & 3;
  float a = -__expf(A_log[((long)k * 512 + d) * 16 + n]);
  float h = 0.f;
  #pragma unroll
  for (int c = 0; c < 32; ++c) {
    float P = __expf(dsum[c * 4096 + z * 512 + d] * a);
    float hp = hpb[c * 65536 + g];
    hpb[c * 65536 + g] = h;
    h = P * h + hp;
  }
}

// -------- fused: combine 4 directions (bf16) + LN over 512 + silu(z) --------
__global__ __launch_bounds__(256) void combine_ln2gate(const ushort* __restrict__ ys,
    const float* __restrict__ zb, ushort* __restrict__ out,
    const float* __restrict__ g, const float* __restrict__ b) {
  __shared__ float sm[8];
  int m = blockIdx.x, tid = threadIdx.x;
  int bb = m >> 10, l = m & 1023;
  int hh = l >> 5, w = l & 31;
  int lw = w * 32 + hh;
  long b4 = (long)bb * 4;
  uint u0 = *(const uint*)&ys[((b4 + 0) * 1024 + l) * 512 + tid * 2];
  uint u1 = *(const uint*)&ys[((b4 + 2) * 1024 + (1023 - l)) * 512 + tid * 2];
  uint u2 = *(const uint*)&ys[((b4 + 1) * 1024 + lw) * 512 + tid * 2];
  uint u3 = *(const uint*)&ys[((b4 + 3) * 1024 + (1023 - lw)) * 512 + tid * 2];
  float v0 = bf2f(u0 & 0xffff) + bf2f(u1 & 0xffff) + bf2f(u2 & 0xffff) + bf2f(u3 & 0xffff);
  float v1 = bf2f(u0 >> 16) + bf2f(u1 >> 16) + bf2f(u2 >> 16) + bf2f(u3 >> 16);
  float s1 = blk_sum(v0 + v1, sm);
  float s2 = blk_sum(v0 * v0 + v1 * v1, sm);
  float mu = s1 * (1.f / 512.f);
  float var = s2 * (1.f / 512.f) - mu * mu;
  float rs = rsqrtf(var + 1e-5f);
  float2 gg = *(const float2*)(g + tid * 2);
  float2 bbv = *(const float2*)(b + tid * 2);
  float2 zz = *(const float2*)(zb + (long)m * 512 + tid * 2);
  float y0 = ((v0 - mu) * rs * gg.x + bbv.x) * (zz.x / (1.f + __expf(-zz.x)));
  float y1 = ((v1 - mu) * rs * gg.y + bbv.y) * (zz.y / (1.f + __expf(-zz.y)));
  *(uint*)&out[(long)m * 512 + tid * 2] = packbf(y0, y1);
}

extern "C" void kernel_launch(void* const* d_in, const int* in_sizes, int n_in,
                              void* d_out, int out_size, void* d_ws, size_t ws_size,
                              hipStream_t stream) {
  const float* x       = (const float*)d_in[0];
  const float* patch_w = (const float*)d_in[1];
  const float* patch_b = (const float*)d_in[2];
  const float* ln_g    = (const float*)d_in[3];
  const float* ln_b    = (const float*)d_in[4];
  const float* in_w    = (const float*)d_in[5];
  const float* conv_w  = (const float*)d_in[6];
  const float* conv_b  = (const float*)d_in[7];
  const float* xproj_w = (const float*)d_in[8];
  const float* dt_w    = (const float*)d_in[9];
  const float* dt_b    = (const float*)d_in[10];
  const float* A_log   = (const float*)d_in[11];
  const float* Ds      = (const float*)d_in[12];
  const float* on_g    = (const float*)d_in[13];
  const float* on_b    = (const float*)d_in[14];
  const float* out_w   = (const float*)d_in[15];
  const float* head_w  = (const float*)d_in[16];
  const float* head_b  = (const float*)d_in[17];

  float* ws = (float*)d_ws;
  float* t_buf   = ws;                    // tpart(2048) + spart(512)
  float* u_buf   = t_buf + 524288;        // u_bf16 overlay
  float* xz_buf  = u_buf + 524288;        // pw_hi overlay; later z_buf
  float* xc_buf  = xz_buf + 2097152;      // xc_bf overlay
  float* xca_buf = xc_buf + 1048576;      // xca_bf overlay; later y_bf
  float* xsT_buf = xca_buf + 1048576;     // A_p overlay
  float* xdbl_buf= xsT_buf + 4194304;     // 8*1024*48
  float* spl_buf = xdbl_buf + 393216;     // P_patch / P_out overlay
  float* tail    = spl_buf + 4194304;
  // overlays:
  float*  tpart  = t_buf;                           // 2048 f
  float*  spart  = t_buf + 2048;                    // 512 f
  ushort* A_p    = (ushort*)xsT_buf;                // 2048*4096 us
  ushort* pw_hi  = (ushort*)xz_buf;                 // 1048576 us
  float*  z_buf  = xz_buf;                          // 2048*512 f (after patch mfma)
  float*  P_patch= spl_buf;                         // 8*524288 f
  float*  P_out  = spl_buf;                         // 4*524288 f
  ushort* u_bf   = (ushort*)u_buf;
  ushort* xc_bf  = (ushort*)xc_buf;
  ushort* xca_bf = (ushort*)xca_buf;
  ushort* y_bf   = (ushort*)xca_buf;                // after build_xsT
  ushort* iw_hi  = (ushort*)tail;
  ushort* iw_lo  = (ushort*)(tail + 131072);
  ushort* ow_hi  = (ushort*)(tail + 262144);
  ushort* ow_lo  = (ushort*)(tail + 327680);
  ushort* xw_hi  = (ushort*)(tail + 393216);
  ushort* xw_lo  = (ushort*)(tail + 442368);
  ushort* xsT_bf = (ushort*)(tail + 491520);        // 4194304 us
  float*  dsum_buf = tail + 2588672;                // 131072 f
  float*  hp_buf   = tail + 2719744;                // 2097152 f

  // 0. fused prep: im2col A + weight splits (patch hi-only)
  prep_kernel<<<8065, 256, 0, stream>>>(x, A_p, patch_w, in_w, out_w, xproj_w,
      pw_hi, iw_hi, iw_lo, ow_hi, ow_lo, xw_hi, xw_lo);
  // 1. patch embed MFMA (hi-only), split-K=8 -> partials
  mfma_bf<<<512, 512, 0, stream>>>(A_p, pw_hi, nullptr, P_patch, nullptr,
      2048, 256, 4096, 512, 0, 16, 8, 0);
  // 2. fused reduce + bias + LN1 -> u (bf16); tpart head partial; t not stored
  reduce_ln1<<<2048, 256, 0, stream>>>(P_patch, patch_b, ln_g, ln_b, u_bf,
      head_w, tpart);
  // 3. in-proj MFMA fused epilogue: xc (transposed bf16) + z (f32)
  mfma_bf<<<256, 512, 0, stream>>>(u_bf, iw_hi, iw_lo, xc_buf, z_buf,
      2048, 1024, 256, 256, 2, 16, 1, 1);
  // 4. depthwise conv + silu -> xca (bf16)
  dwconv_kernel<<<dim3(512, 2), 256, 0, stream>>>(xc_bf, conv_w, conv_b, xca_bf);
  // 5. build xsT (bf16, 4 directions)
  build_xsT<<<dim3(32, 16, 8), 256, 0, stream>>>(xca_bf, xsT_bf);
  // 6. x_dbl[z] (1024,48) = xsT_bf[z] @ xproj[k]^T (MFMA)
  mfma_x<<<dim3(16, 8), 256, 0, stream>>>(xsT_bf, xw_hi, xw_lo, xdbl_buf);
  // 7. chunk-parallel selective scan (NC=32, fused dt-projection)
  scan_chunk6<false><<<dim3(8, 32, 8), 128, 0, stream>>>(xdbl_buf, xsT_bf,
      dt_w, dt_b, A_log, Ds, dsum_buf, hp_buf);
  scan_prefix<<<256, 256, 0, stream>>>(dsum_buf, A_log, hp_buf);
  scan_chunk6<true><<<dim3(8, 32, 8), 128, 0, stream>>>(xdbl_buf, xsT_bf,
      dt_w, dt_b, A_log, Ds, nullptr, hp_buf);
  // 8. fused combine + LN2 + silu gate -> y_bf16
  combine_ln2gate<<<2048, 256, 0, stream>>>(xsT_bf, z_buf, y_bf, on_g, on_b);
  // 9. ss = y @ out_w^T (MFMA split-K=4) -> partials; head dot fused in reduce
  mfma_bf<<<256, 512, 0, stream>>>(y_bf, ow_hi, ow_lo, P_out, nullptr,
      2048, 256, 512, 128, 0, 16, 4, 1);
  reduce_ss<<<512, 256, 0, stream>>>(P_out, head_w, spart);
  // 10. head final
  head_final<<<2, 256, 0, stream>>>(tpart, spart, head_b, (float*)d_out);
}